// Round 1
// baseline (2403.946 us; speedup 1.0000x reference)
//
#include <hip/hip_runtime.h>

#define N_NODES 50000
#define N_EDGES 800000
#define F_IN 128
#define HIDDEN 128
#define N_CLASSES 40

// ---------------------------------------------------------------------------
// Kernel 1: layer-1 scatter-add. 32 threads per edge, each handles 4 floats.
// Also accumulates degree (one lane per edge).
__global__ __launch_bounds__(256) void k_scatter1(
    const float* __restrict__ x, const int* __restrict__ src,
    const int* __restrict__ dst, float* __restrict__ agg,
    float* __restrict__ deg) {
  int idx = blockIdx.x * 256 + threadIdx.x;
  int e = idx >> 5;
  if (e >= N_EDGES) return;
  int c = (idx & 31) << 2;
  int s = src[e], d = dst[e];
  const float4 v = *(const float4*)(x + (size_t)s * F_IN + c);
  float* a = agg + (size_t)d * F_IN + c;
  atomicAdd(a + 0, v.x);
  atomicAdd(a + 1, v.y);
  atomicAdd(a + 2, v.z);
  atomicAdd(a + 3, v.w);
  if ((idx & 31) == 0) atomicAdd(deg + d, 1.0f);
}

// ---------------------------------------------------------------------------
// Kernel 2: deg -> 1/max(deg,1)
__global__ void k_invdeg(float* __restrict__ deg) {
  int i = blockIdx.x * blockDim.x + threadIdx.x;
  if (i < N_NODES) deg[i] = 1.0f / fmaxf(deg[i], 1.0f);
}

// ---------------------------------------------------------------------------
// Kernel 3: h = relu((agg*invdeg) @ W1_l + x @ W1_r + b1)
// Block: 256 threads, 32 rows x 128 cols per block, 16 outputs/thread.
// LDS: 2x(32x128) W tiles + 2x(32x33) input tiles = ~40.7 KB.
__global__ __launch_bounds__(256) void k_layer1(
    const float* __restrict__ agg, const float* __restrict__ invdeg,
    const float* __restrict__ x, const float* __restrict__ Wl,
    const float* __restrict__ Wr, const float* __restrict__ b,
    float* __restrict__ h) {
  __shared__ float sWl[32][128];
  __shared__ float sWr[32][128];
  __shared__ float sa[32][33];
  __shared__ float sx[32][33];
  int row0 = blockIdx.x * 32;
  int col = threadIdx.x & 127;
  int rh = threadIdx.x >> 7;  // 0/1
  float acc[16];
#pragma unroll
  for (int i = 0; i < 16; i++) acc[i] = 0.f;

  for (int k0 = 0; k0 < F_IN; k0 += 32) {
    for (int i = threadIdx.x; i < 32 * 128; i += 256) {
      int kk = i >> 7, cc = i & 127;
      sWl[kk][cc] = Wl[(size_t)(k0 + kk) * HIDDEN + cc];
      sWr[kk][cc] = Wr[(size_t)(k0 + kk) * HIDDEN + cc];
    }
    for (int i = threadIdx.x; i < 32 * 32; i += 256) {
      int rr = i >> 5, kk = i & 31;
      int row = row0 + rr;
      float av = 0.f, xv = 0.f;
      if (row < N_NODES) {
        av = agg[(size_t)row * F_IN + k0 + kk] * invdeg[row];
        xv = x[(size_t)row * F_IN + k0 + kk];
      }
      sa[rr][kk] = av;
      sx[rr][kk] = xv;
    }
    __syncthreads();
#pragma unroll
    for (int kk = 0; kk < 32; kk++) {
      float wl = sWl[kk][col];
      float wr = sWr[kk][col];
#pragma unroll
      for (int r = 0; r < 16; r++) {
        int rr = 2 * r + rh;
        acc[r] += sa[rr][kk] * wl + sx[rr][kk] * wr;
      }
    }
    __syncthreads();
  }
  float bias = b[col];
#pragma unroll
  for (int r = 0; r < 16; r++) {
    int row = row0 + 2 * r + rh;
    if (row < N_NODES) h[(size_t)row * HIDDEN + col] = fmaxf(acc[r] + bias, 0.f);
  }
}

// ---------------------------------------------------------------------------
// Kernel 4: p = h @ W2_l ; q = h @ W2_r + b2   (project BEFORE aggregating —
// shrinks layer-2 scatter traffic from 128 to 40 dims)
// 64 threads per row (cols 0..39 active).
__global__ __launch_bounds__(256) void k_pq(
    const float* __restrict__ h, const float* __restrict__ W2l,
    const float* __restrict__ W2r, const float* __restrict__ b2,
    float* __restrict__ p, float* __restrict__ q) {
  int t = blockIdx.x * 256 + threadIdx.x;
  int row = t >> 6;
  int col = t & 63;
  if (row >= N_NODES || col >= N_CLASSES) return;
  const float* hr = h + (size_t)row * HIDDEN;
  float accl = 0.f, accr = 0.f;
#pragma unroll 8
  for (int k = 0; k < HIDDEN; k++) {
    float hv = hr[k];
    accl += hv * W2l[k * N_CLASSES + col];
    accr += hv * W2r[k * N_CLASSES + col];
  }
  p[(size_t)row * N_CLASSES + col] = accl;
  q[(size_t)row * N_CLASSES + col] = accr + b2[col];
}

// ---------------------------------------------------------------------------
// Kernel 5: layer-2 scatter-add of projected features into d_out.
// 10 threads per edge, each handles 4 floats.
__global__ __launch_bounds__(256) void k_scatter2(
    const float* __restrict__ p, const int* __restrict__ src,
    const int* __restrict__ dst, float* __restrict__ out) {
  int idx = blockIdx.x * 256 + threadIdx.x;
  int e = idx / 10;
  if (e >= N_EDGES) return;
  int c = (idx - e * 10) << 2;
  int s = src[e], d = dst[e];
  const float4 v = *(const float4*)(p + (size_t)s * N_CLASSES + c);
  float* o = out + (size_t)d * N_CLASSES + c;
  atomicAdd(o + 0, v.x);
  atomicAdd(o + 1, v.y);
  atomicAdd(o + 2, v.z);
  atomicAdd(o + 3, v.w);
}

// ---------------------------------------------------------------------------
// Kernel 6: out = log_softmax(relu(out*invdeg + q)), in place. 1 thread/row.
__global__ __launch_bounds__(256) void k_final(
    float* __restrict__ out, const float* __restrict__ q,
    const float* __restrict__ invdeg) {
  int row = blockIdx.x * 256 + threadIdx.x;
  if (row >= N_NODES) return;
  float inv = invdeg[row];
  const float* qr = q + (size_t)row * N_CLASSES;
  float* orow = out + (size_t)row * N_CLASSES;
  float v[N_CLASSES];
  float m = 0.f;  // relu output >= 0, and there are 40 values, so max >= 0
#pragma unroll
  for (int c = 0; c < N_CLASSES; c++) {
    float o = fmaxf(orow[c] * inv + qr[c], 0.f);
    v[c] = o;
    m = fmaxf(m, o);
  }
  float s = 0.f;
#pragma unroll
  for (int c = 0; c < N_CLASSES; c++) s += __expf(v[c] - m);
  float lse = __logf(s) + m;
#pragma unroll
  for (int c = 0; c < N_CLASSES; c++) orow[c] = v[c] - lse;
}

// ---------------------------------------------------------------------------
extern "C" void kernel_launch(void* const* d_in, const int* in_sizes, int n_in,
                              void* d_out, int out_size, void* d_ws,
                              size_t ws_size, hipStream_t stream) {
  const float* x   = (const float*)d_in[0];
  const int*   ei  = (const int*)d_in[1];
  const int*   src = ei;            // edge_index[0]
  const int*   dst = ei + N_EDGES;  // edge_index[1]
  const float* W1l = (const float*)d_in[2];
  const float* W1r = (const float*)d_in[3];
  const float* b1  = (const float*)d_in[4];
  const float* W2l = (const float*)d_in[5];
  const float* W2r = (const float*)d_in[6];
  const float* b2  = (const float*)d_in[7];
  float* out = (float*)d_out;

  // workspace layout (floats):
  //   [0, N)                       deg -> invdeg
  //   [N, N + N*128)               agg1, later reused as p (N*40) + q (N*40)
  //   [N + N*128, N + 2*N*128)     h
  float* deg = (float*)d_ws;
  float* agg = deg + N_NODES;
  float* h   = agg + (size_t)N_NODES * F_IN;
  float* p   = agg;  // reuse after k_layer1 consumed agg
  float* q   = agg + (size_t)N_NODES * N_CLASSES;

  hipMemsetAsync(d_ws, 0, (size_t)(N_NODES + (size_t)N_NODES * F_IN) * sizeof(float), stream);
  hipMemsetAsync(d_out, 0, (size_t)N_NODES * N_CLASSES * sizeof(float), stream);

  k_scatter1<<<(N_EDGES * 32) / 256, 256, 0, stream>>>(x, src, dst, agg, deg);
  k_invdeg<<<(N_NODES + 255) / 256, 256, 0, stream>>>(deg);
  k_layer1<<<(N_NODES + 31) / 32, 256, 0, stream>>>(agg, deg, x, W1l, W1r, b1, h);
  k_pq<<<(N_NODES * 64) / 256, 256, 0, stream>>>(h, W2l, W2r, b2, p, q);
  k_scatter2<<<(N_EDGES * 10 + 255) / 256, 256, 0, stream>>>(p, src, dst, out);
  k_final<<<(N_NODES + 255) / 256, 256, 0, stream>>>(out, q, deg);
}

// Round 2
// 951.044 us; speedup vs baseline: 2.5277x; 2.5277x over previous
//
#include <hip/hip_runtime.h>

#define N_NODES 50000
#define N_EDGES 800000
#define F_IN 128
#define HIDDEN 128
#define N_CLASSES 40

// workspace element offsets (floats/ints, 4B each); agg/p 16B-aligned
#define OFF_RS     0         // int[N+1] rowstart
#define OFF_CUR    50004     // int[N]   counts -> cursor
#define OFF_INVDEG 100004    // float[N]
#define OFF_SRCS   150004    // int[E]   CSR-ordered src ids
#define OFF_AGG    950004    // float[N*128], reused in-place as h
#define OFF_P      7350004   // float[N*40]
#define OFF_Q      9350004   // float[N*40]
// total 11,350,004 elems = 45.4 MB

// ---------------------------------------------------------------------------
// CSR build step 1: per-dst degree count (int atomics only)
__global__ __launch_bounds__(256) void k_count(const int* __restrict__ dst,
                                               int* __restrict__ cur) {
  int e = blockIdx.x * 256 + threadIdx.x;
  if (e < N_EDGES) atomicAdd(&cur[dst[e]], 1);
}

// ---------------------------------------------------------------------------
// CSR build step 2: single-block exclusive scan over 50k counts.
// Writes rowstart (rs), cursor init (cur), and invdeg.
__global__ __launch_bounds__(1024) void k_scan(int* __restrict__ rs,
                                               int* __restrict__ cur,
                                               float* __restrict__ invdeg) {
  __shared__ int sd[1024];
  int t = threadIdx.x;
  const int CH = (N_NODES + 1023) / 1024;  // 49
  int beg = t * CH;
  int end = beg + CH;
  if (beg > N_NODES) beg = N_NODES;
  if (end > N_NODES) end = N_NODES;
  int sum = 0;
  for (int i = beg; i < end; i++) sum += cur[i];
  sd[t] = sum;
  __syncthreads();
  // Hillis-Steele inclusive scan over 1024 partials
  for (int off = 1; off < 1024; off <<= 1) {
    int add = (t >= off) ? sd[t - off] : 0;
    __syncthreads();
    sd[t] += add;
    __syncthreads();
  }
  int run = sd[t] - sum;  // exclusive prefix for my chunk
  for (int i = beg; i < end; i++) {
    int c = cur[i];
    rs[i] = run;
    cur[i] = run;  // cursor for fill phase
    invdeg[i] = 1.0f / (float)(c > 1 ? c : 1);
    run += c;
  }
  if (t == 0) rs[N_NODES] = N_EDGES;
}

// ---------------------------------------------------------------------------
// CSR build step 3: bucket-fill src ids (int atomics only)
__global__ __launch_bounds__(256) void k_fill(const int* __restrict__ src,
                                              const int* __restrict__ dst,
                                              int* __restrict__ cur,
                                              int* __restrict__ srcs) {
  int e = blockIdx.x * 256 + threadIdx.x;
  if (e < N_EDGES) {
    int pos = atomicAdd(&cur[dst[e]], 1);
    srcs[pos] = src[e];
  }
}

// ---------------------------------------------------------------------------
// Layer-1 aggregation by GATHER (no float atomics). 128 threads per node,
// 2 nodes per block. Coalesced row reads of x; mean folded in.
__global__ __launch_bounds__(256) void k_gather1(
    const float* __restrict__ x, const int* __restrict__ rs,
    const int* __restrict__ srcs, const float* __restrict__ invdeg,
    float* __restrict__ agg) {
  int node = blockIdx.x * 2 + (threadIdx.x >> 7);
  int col = threadIdx.x & 127;
  if (node >= N_NODES) return;
  int beg = rs[node], end = rs[node + 1];
  float acc = 0.f;
  for (int i = beg; i < end; i++) {
    int s = srcs[i];  // same addr across wave -> broadcast load
    acc += x[(size_t)s * F_IN + col];
  }
  agg[(size_t)node * F_IN + col] = acc * invdeg[node];
}

// ---------------------------------------------------------------------------
// h = relu(agg @ W1_l + x @ W1_r + b1), written IN PLACE over agg.
// Safe: each block reads only its own 32 rows of agg (all k-chunks) before
// writing them; no other block touches those rows.
__global__ __launch_bounds__(256) void k_layer1(
    float* __restrict__ agg, const float* __restrict__ x,
    const float* __restrict__ Wl, const float* __restrict__ Wr,
    const float* __restrict__ b) {
  __shared__ float sWl[32][128];
  __shared__ float sWr[32][128];
  __shared__ float sa[32][33];
  __shared__ float sx[32][33];
  int row0 = blockIdx.x * 32;
  int col = threadIdx.x & 127;
  int rh = threadIdx.x >> 7;  // 0/1
  float acc[16];
#pragma unroll
  for (int i = 0; i < 16; i++) acc[i] = 0.f;

  for (int k0 = 0; k0 < F_IN; k0 += 32) {
    for (int i = threadIdx.x; i < 32 * 128; i += 256) {
      int kk = i >> 7, cc = i & 127;
      sWl[kk][cc] = Wl[(size_t)(k0 + kk) * HIDDEN + cc];
      sWr[kk][cc] = Wr[(size_t)(k0 + kk) * HIDDEN + cc];
    }
    for (int i = threadIdx.x; i < 32 * 32; i += 256) {
      int rr = i >> 5, kk = i & 31;
      int row = row0 + rr;
      float av = 0.f, xv = 0.f;
      if (row < N_NODES) {
        av = agg[(size_t)row * F_IN + k0 + kk];
        xv = x[(size_t)row * F_IN + k0 + kk];
      }
      sa[rr][kk] = av;
      sx[rr][kk] = xv;
    }
    __syncthreads();
#pragma unroll
    for (int kk = 0; kk < 32; kk++) {
      float wl = sWl[kk][col];
      float wr = sWr[kk][col];
#pragma unroll
      for (int r = 0; r < 16; r++) {
        int rr = 2 * r + rh;
        acc[r] += sa[rr][kk] * wl + sx[rr][kk] * wr;
      }
    }
    __syncthreads();
  }
  float bias = b[col];
#pragma unroll
  for (int r = 0; r < 16; r++) {
    int row = row0 + 2 * r + rh;
    if (row < N_NODES)
      agg[(size_t)row * HIDDEN + col] = fmaxf(acc[r] + bias, 0.f);
  }
}

// ---------------------------------------------------------------------------
// p = h @ W2_l ; q = h @ W2_r + b2  (project before layer-2 aggregation)
__global__ __launch_bounds__(256) void k_pq(
    const float* __restrict__ h, const float* __restrict__ W2l,
    const float* __restrict__ W2r, const float* __restrict__ b2,
    float* __restrict__ p, float* __restrict__ q) {
  int t = blockIdx.x * 256 + threadIdx.x;
  int row = t >> 6;
  int col = t & 63;
  if (row >= N_NODES || col >= N_CLASSES) return;
  const float* hr = h + (size_t)row * HIDDEN;
  float accl = 0.f, accr = 0.f;
#pragma unroll 8
  for (int k = 0; k < HIDDEN; k++) {
    float hv = hr[k];
    accl += hv * W2l[k * N_CLASSES + col];
    accr += hv * W2r[k * N_CLASSES + col];
  }
  p[(size_t)row * N_CLASSES + col] = accl;
  q[(size_t)row * N_CLASSES + col] = accr + b2[col];
}

// ---------------------------------------------------------------------------
// Fused: layer-2 gather-mean + root + ReLU + log_softmax. One wave per node
// (lanes 0..39 active), shuffle reductions for max / sum.
__global__ __launch_bounds__(256) void k_final(
    const float* __restrict__ p, const float* __restrict__ q,
    const int* __restrict__ rs, const int* __restrict__ srcs,
    const float* __restrict__ invdeg, float* __restrict__ out) {
  int node = blockIdx.x * 4 + (threadIdx.x >> 6);
  int lane = threadIdx.x & 63;
  if (node >= N_NODES) return;
  bool active = lane < N_CLASSES;
  int beg = rs[node], end = rs[node + 1];
  float acc = 0.f;
  for (int i = beg; i < end; i++) {
    int s = srcs[i];
    if (active) acc += p[(size_t)s * N_CLASSES + lane];
  }
  float v = active
                ? fmaxf(acc * invdeg[node] + q[(size_t)node * N_CLASSES + lane], 0.f)
                : -1e30f;
  float m = v;
#pragma unroll
  for (int off = 32; off; off >>= 1) m = fmaxf(m, __shfl_xor(m, off, 64));
  float ex = active ? __expf(v - m) : 0.f;
  float ssum = ex;
#pragma unroll
  for (int off = 32; off; off >>= 1) ssum += __shfl_xor(ssum, off, 64);
  float lse = __logf(ssum) + m;
  if (active) out[(size_t)node * N_CLASSES + lane] = v - lse;
}

// ---------------------------------------------------------------------------
extern "C" void kernel_launch(void* const* d_in, const int* in_sizes, int n_in,
                              void* d_out, int out_size, void* d_ws,
                              size_t ws_size, hipStream_t stream) {
  const float* x   = (const float*)d_in[0];
  const int*   ei  = (const int*)d_in[1];
  const int*   src = ei;            // edge_index[0]
  const int*   dst = ei + N_EDGES;  // edge_index[1]
  const float* W1l = (const float*)d_in[2];
  const float* W1r = (const float*)d_in[3];
  const float* b1  = (const float*)d_in[4];
  const float* W2l = (const float*)d_in[5];
  const float* W2r = (const float*)d_in[6];
  const float* b2  = (const float*)d_in[7];
  float* out = (float*)d_out;

  float* wsf    = (float*)d_ws;
  int*   rs     = (int*)wsf + OFF_RS;
  int*   cur    = (int*)wsf + OFF_CUR;
  float* invdeg = wsf + OFF_INVDEG;
  int*   srcs   = (int*)wsf + OFF_SRCS;
  float* agg    = wsf + OFF_AGG;  // later holds h in place
  float* p      = wsf + OFF_P;
  float* q      = wsf + OFF_Q;

  hipMemsetAsync(cur, 0, N_NODES * sizeof(int), stream);

  k_count<<<(N_EDGES + 255) / 256, 256, 0, stream>>>(dst, cur);
  k_scan<<<1, 1024, 0, stream>>>(rs, cur, invdeg);
  k_fill<<<(N_EDGES + 255) / 256, 256, 0, stream>>>(src, dst, cur, srcs);
  k_gather1<<<(N_NODES + 1) / 2, 256, 0, stream>>>(x, rs, srcs, invdeg, agg);
  k_layer1<<<(N_NODES + 31) / 32, 256, 0, stream>>>(agg, x, W1l, W1r, b1);
  k_pq<<<(N_NODES * 64 + 255) / 256, 256, 0, stream>>>(agg, W2l, W2r, b2, p, q);
  k_final<<<(N_NODES + 3) / 4, 256, 0, stream>>>(p, q, rs, srcs, invdeg, out);
}

// Round 4
// 591.547 us; speedup vs baseline: 4.0638x; 1.6077x over previous
//
#include <hip/hip_runtime.h>

#define N_NODES 50000
#define N_EDGES 800000
#define F_IN 128
#define HIDDEN 128
#define N_CLASSES 40

// workspace element offsets (4B units)
#define OFF_RS     0          // int[N+1]
#define OFF_CUR    50004      // int[N]
#define OFF_INVDEG 100004     // float[N]
#define OFF_SRCS   150004     // int[E]
#define OFF_AB     950004     // ushort[N*256] bf16 A = [agg | x]; dead after k_l1
#define OFF_P      950004     // float[N*40]  (overlays dead Ab)
#define OFF_Q      2950004    // float[N*40]  (overlays dead Ab)
#define OFF_HB     7350004    // ushort[N*128] = 3,200,000 float-units -> ends 10,550,004
#define OFF_WT1    10550004   // ushort[128*256] = 16,384 float-units -> ends 10,566,388
#define OFF_WT2    10566388   // ushort[80*128]  = 5,120 float-units  -> ends 10,571,508
// total 10,571,508 float-units = 42.3 MB (R1 proved >= 45.4 MB available)

typedef short bf16x8 __attribute__((ext_vector_type(8)));
typedef float f32x4 __attribute__((ext_vector_type(4)));

static __device__ __forceinline__ unsigned short f2bf(float f) {
  unsigned int u = __builtin_bit_cast(unsigned int, f);
  u = (u + 0x7fffu + ((u >> 16) & 1u)) >> 16;  // RNE; inputs are finite
  return (unsigned short)u;
}

// ---------------------------------------------------------------------------
// CSR build: count, scan, fill (int atomics only)
__global__ __launch_bounds__(256) void k_count(const int* __restrict__ dst,
                                               int* __restrict__ cur) {
  int e = blockIdx.x * 256 + threadIdx.x;
  if (e < N_EDGES) atomicAdd(&cur[dst[e]], 1);
}

__global__ __launch_bounds__(1024) void k_scan(int* __restrict__ rs,
                                               int* __restrict__ cur,
                                               float* __restrict__ invdeg) {
  __shared__ int sd[1024];
  int t = threadIdx.x;
  const int CH = (N_NODES + 1023) / 1024;  // 49
  int beg = t * CH, end = beg + CH;
  if (beg > N_NODES) beg = N_NODES;
  if (end > N_NODES) end = N_NODES;
  int sum = 0;
  for (int i = beg; i < end; i++) sum += cur[i];
  sd[t] = sum;
  __syncthreads();
  for (int off = 1; off < 1024; off <<= 1) {
    int add = (t >= off) ? sd[t - off] : 0;
    __syncthreads();
    sd[t] += add;
    __syncthreads();
  }
  int run = sd[t] - sum;
  for (int i = beg; i < end; i++) {
    int c = cur[i];
    rs[i] = run;
    cur[i] = run;
    invdeg[i] = 1.0f / (float)(c > 1 ? c : 1);
    run += c;
  }
  if (t == 0) rs[N_NODES] = N_EDGES;
}

__global__ __launch_bounds__(256) void k_fill(const int* __restrict__ src,
                                              const int* __restrict__ dst,
                                              int* __restrict__ cur,
                                              int* __restrict__ srcs) {
  int e = blockIdx.x * 256 + threadIdx.x;
  if (e < N_EDGES) {
    int pos = atomicAdd(&cur[dst[e]], 1);
    srcs[pos] = src[e];
  }
}

// ---------------------------------------------------------------------------
// Weight prep: fp32 -> bf16, transposed to [n][k] so B-fragments are
// contiguous 16B loads. Wt1: [128][256] (W1l|W1r over k). Wt2: [80][128]
// (W2l|W2r over n).
__global__ __launch_bounds__(256) void k_prep_w(
    const float* __restrict__ W1l, const float* __restrict__ W1r,
    const float* __restrict__ W2l, const float* __restrict__ W2r,
    unsigned short* __restrict__ Wt1, unsigned short* __restrict__ Wt2) {
  int idx = blockIdx.x * 256 + threadIdx.x;
  if (idx < 128 * 256) {
    int n = idx >> 8, k = idx & 255;
    float v = (k < 128) ? W1l[(size_t)k * 128 + n]
                        : W1r[(size_t)(k - 128) * 128 + n];
    Wt1[(size_t)n * 256 + k] = f2bf(v);
  } else if (idx < 128 * 256 + 80 * 128) {
    int j = idx - 128 * 256;
    int n = j >> 7, k = j & 127;
    float v = (n < 40) ? W2l[(size_t)k * 40 + n]
                       : W2r[(size_t)k * 40 + (n - 40)];
    Wt2[(size_t)n * 128 + k] = f2bf(v);
  }
}

// x fp32 -> bf16 into Ab[:, 128:256]
__global__ __launch_bounds__(256) void k_castx(const float* __restrict__ x,
                                               unsigned short* __restrict__ Ab) {
  int idx = blockIdx.x * 256 + threadIdx.x;  // one per 4 elems
  if (idx >= N_NODES * 32) return;
  int row = idx >> 5, c4 = (idx & 31) << 2;
  const float4 v = *(const float4*)(x + (size_t)row * F_IN + c4);
  ushort4 o;
  o.x = f2bf(v.x); o.y = f2bf(v.y); o.z = f2bf(v.z); o.w = f2bf(v.w);
  *(ushort4*)(Ab + (size_t)row * 256 + 128 + c4) = o;
}

// ---------------------------------------------------------------------------
// Layer-1 mean-aggregation by gather (no float atomics), bf16 out into
// Ab[:, 0:128]. 128 threads per node, 2 nodes per block.
__global__ __launch_bounds__(256) void k_gather1(
    const float* __restrict__ x, const int* __restrict__ rs,
    const int* __restrict__ srcs, const float* __restrict__ invdeg,
    unsigned short* __restrict__ Ab) {
  int node = blockIdx.x * 2 + (threadIdx.x >> 7);
  int col = threadIdx.x & 127;
  if (node >= N_NODES) return;
  int beg = rs[node], end = rs[node + 1];
  float acc = 0.f;
  for (int i = beg; i < end; i++) {
    int s = srcs[i];  // uniform across group -> broadcast
    acc += x[(size_t)s * F_IN + col];
  }
  Ab[(size_t)node * 256 + col] = f2bf(acc * invdeg[node]);
}

// ---------------------------------------------------------------------------
// h = relu([agg|x] @ [W1l;W1r] + b1)  — register-only bf16 MFMA GEMM.
// Block = 4 waves x 16 rows = 64 rows, full N=128 (8 n-tiles), K=256.
// A-frags and B-frags are direct 16B global loads (A has no intra-block
// reuse; W is 64KB L2-resident). h written as bf16.
__global__ __launch_bounds__(256) void k_l1(
    const unsigned short* __restrict__ Ab, const unsigned short* __restrict__ Wt1,
    const float* __restrict__ b1, unsigned short* __restrict__ hb) {
  int w = threadIdx.x >> 6, lane = threadIdx.x & 63;
  int r = lane & 15, quad = lane >> 4;
  int row0 = blockIdx.x * 64 + w * 16;
  int arow = row0 + r;
  if (arow >= N_NODES) arow = N_NODES - 1;  // clamp load, guard store
  const unsigned short* Ap = Ab + (size_t)arow * 256 + quad * 8;
  const unsigned short* Bp = Wt1 + (size_t)r * 256 + quad * 8;
  f32x4 acc[8];
#pragma unroll
  for (int n = 0; n < 8; n++) acc[n] = (f32x4){0.f, 0.f, 0.f, 0.f};
#pragma unroll
  for (int k0 = 0; k0 < 256; k0 += 32) {
    bf16x8 af = *(const bf16x8*)(Ap + k0);
#pragma unroll
    for (int n = 0; n < 8; n++) {
      bf16x8 bv = *(const bf16x8*)(Bp + (size_t)n * 16 * 256 + k0);
      acc[n] = __builtin_amdgcn_mfma_f32_16x16x32_bf16(af, bv, acc[n], 0, 0, 0);
    }
  }
  int crow0 = row0 + quad * 4;
#pragma unroll
  for (int n = 0; n < 8; n++) {
    int col = n * 16 + r;
    float bias = b1[col];
#pragma unroll
    for (int reg = 0; reg < 4; reg++) {
      int row = crow0 + reg;
      if (row < N_NODES)
        hb[(size_t)row * HIDDEN + col] = f2bf(fmaxf(acc[n][reg] + bias, 0.f));
    }
  }
}

// ---------------------------------------------------------------------------
// [p|q] = h @ [W2l|W2r] (+ b2 on q)  — same register-only MFMA structure,
// N=80 (5 n-tiles), K=128. p,q fp32.
__global__ __launch_bounds__(256) void k_pq(
    const unsigned short* __restrict__ hb, const unsigned short* __restrict__ Wt2,
    const float* __restrict__ b2, float* __restrict__ p, float* __restrict__ q) {
  int w = threadIdx.x >> 6, lane = threadIdx.x & 63;
  int r = lane & 15, quad = lane >> 4;
  int row0 = blockIdx.x * 64 + w * 16;
  int arow = row0 + r;
  if (arow >= N_NODES) arow = N_NODES - 1;
  const unsigned short* Ap = hb + (size_t)arow * HIDDEN + quad * 8;
  const unsigned short* Bp = Wt2 + (size_t)r * 128 + quad * 8;
  f32x4 acc[5];
#pragma unroll
  for (int n = 0; n < 5; n++) acc[n] = (f32x4){0.f, 0.f, 0.f, 0.f};
#pragma unroll
  for (int k0 = 0; k0 < 128; k0 += 32) {
    bf16x8 af = *(const bf16x8*)(Ap + k0);
#pragma unroll
    for (int n = 0; n < 5; n++) {
      bf16x8 bv = *(const bf16x8*)(Bp + (size_t)n * 16 * 128 + k0);
      acc[n] = __builtin_amdgcn_mfma_f32_16x16x32_bf16(af, bv, acc[n], 0, 0, 0);
    }
  }
  int crow0 = row0 + quad * 4;
#pragma unroll
  for (int n = 0; n < 5; n++) {
    int col = n * 16 + r;
#pragma unroll
    for (int reg = 0; reg < 4; reg++) {
      int row = crow0 + reg;
      if (row < N_NODES) {
        float v = acc[n][reg];
        if (col < N_CLASSES)
          p[(size_t)row * N_CLASSES + col] = v;
        else
          q[(size_t)row * N_CLASSES + (col - N_CLASSES)] = v + b2[col - N_CLASSES];
      }
    }
  }
}

// ---------------------------------------------------------------------------
// Fused: layer-2 gather-mean + root + ReLU + log_softmax. One wave per node.
__global__ __launch_bounds__(256) void k_final(
    const float* __restrict__ p, const float* __restrict__ q,
    const int* __restrict__ rs, const int* __restrict__ srcs,
    const float* __restrict__ invdeg, float* __restrict__ out) {
  int node = blockIdx.x * 4 + (threadIdx.x >> 6);
  int lane = threadIdx.x & 63;
  if (node >= N_NODES) return;
  bool active = lane < N_CLASSES;
  int beg = rs[node], end = rs[node + 1];
  float acc = 0.f;
  for (int i = beg; i < end; i++) {
    int s = srcs[i];
    if (active) acc += p[(size_t)s * N_CLASSES + lane];
  }
  float v = active
                ? fmaxf(acc * invdeg[node] + q[(size_t)node * N_CLASSES + lane], 0.f)
                : -1e30f;
  float m = v;
#pragma unroll
  for (int off = 32; off; off >>= 1) m = fmaxf(m, __shfl_xor(m, off, 64));
  float ex = active ? __expf(v - m) : 0.f;
  float ssum = ex;
#pragma unroll
  for (int off = 32; off; off >>= 1) ssum += __shfl_xor(ssum, off, 64);
  float lse = __logf(ssum) + m;
  if (active) out[(size_t)node * N_CLASSES + lane] = v - lse;
}

// ---------------------------------------------------------------------------
extern "C" void kernel_launch(void* const* d_in, const int* in_sizes, int n_in,
                              void* d_out, int out_size, void* d_ws,
                              size_t ws_size, hipStream_t stream) {
  const float* x   = (const float*)d_in[0];
  const int*   ei  = (const int*)d_in[1];
  const int*   src = ei;
  const int*   dst = ei + N_EDGES;
  const float* W1l = (const float*)d_in[2];
  const float* W1r = (const float*)d_in[3];
  const float* b1  = (const float*)d_in[4];
  const float* W2l = (const float*)d_in[5];
  const float* W2r = (const float*)d_in[6];
  const float* b2  = (const float*)d_in[7];
  float* out = (float*)d_out;

  float* wsf = (float*)d_ws;
  int*   rs     = (int*)wsf + OFF_RS;
  int*   cur    = (int*)wsf + OFF_CUR;
  float* invdeg = wsf + OFF_INVDEG;
  int*   srcs   = (int*)wsf + OFF_SRCS;
  unsigned short* Ab  = (unsigned short*)(wsf + OFF_AB);
  unsigned short* hb  = (unsigned short*)(wsf + OFF_HB);
  unsigned short* Wt1 = (unsigned short*)(wsf + OFF_WT1);
  unsigned short* Wt2 = (unsigned short*)(wsf + OFF_WT2);
  float* p = wsf + OFF_P;  // overlays Ab (dead after k_l1)
  float* q = wsf + OFF_Q;

  hipMemsetAsync(cur, 0, N_NODES * sizeof(int), stream);

  k_count<<<(N_EDGES + 255) / 256, 256, 0, stream>>>(dst, cur);
  k_scan<<<1, 1024, 0, stream>>>(rs, cur, invdeg);
  k_fill<<<(N_EDGES + 255) / 256, 256, 0, stream>>>(src, dst, cur, srcs);
  k_prep_w<<<(128 * 256 + 80 * 128 + 255) / 256, 256, 0, stream>>>(
      W1l, W1r, W2l, W2r, Wt1, Wt2);
  k_castx<<<(N_NODES * 32 + 255) / 256, 256, 0, stream>>>(x, Ab);
  k_gather1<<<(N_NODES + 1) / 2, 256, 0, stream>>>(x, rs, srcs, invdeg, Ab);
  k_l1<<<(N_NODES + 63) / 64, 256, 0, stream>>>(Ab, Wt1, b1, hb);
  k_pq<<<(N_NODES + 63) / 64, 256, 0, stream>>>(hb, Wt2, b2, p, q);
  k_final<<<(N_NODES + 3) / 4, 256, 0, stream>>>(p, q, rs, srcs, invdeg, out);
}

// Round 5
// 443.968 us; speedup vs baseline: 5.4147x; 1.3324x over previous
//
#include <hip/hip_runtime.h>

#define N_NODES 50000
#define N_EDGES 800000
#define F_IN 128
#define HIDDEN 128
#define N_CLASSES 40

// workspace element offsets (4B units)
#define OFF_RS     0          // int[N+1]
#define OFF_CUR    50004      // int[N]
#define OFF_INVDEG 100004     // float[N]
#define OFF_SRCS   150004     // int[E]
#define OFF_AB     950004     // ushort[N*256] bf16 A = [agg | x]; dead after k_l1
#define OFF_PB     950004     // ushort[N*64] bf16 p, stride 64 (overlays dead Ab)
#define OFF_Q      2950004    // float[N*40]
#define OFF_HB     7350004    // ushort[N*128] -> ends 10,550,004
#define OFF_WT1    10550004   // ushort[128*256] -> ends 10,566,388
#define OFF_WT2    10566388   // ushort[80*128]  -> ends 10,571,508
// total 10,571,508 float-units = 42.3 MB

typedef short bf16x8 __attribute__((ext_vector_type(8)));
typedef float f32x4 __attribute__((ext_vector_type(4)));
typedef unsigned short u16x8 __attribute__((ext_vector_type(8)));
typedef unsigned short u16x4 __attribute__((ext_vector_type(4)));

static __device__ __forceinline__ unsigned short f2bf(float f) {
  unsigned int u = __builtin_bit_cast(unsigned int, f);
  u = (u + 0x7fffu + ((u >> 16) & 1u)) >> 16;  // RNE; inputs are finite
  return (unsigned short)u;
}
static __device__ __forceinline__ float bf2f(unsigned short s) {
  unsigned int u = ((unsigned int)s) << 16;
  return __builtin_bit_cast(float, u);
}

// ---------------------------------------------------------------------------
// CSR build: count, scan, fill (int atomics only)
__global__ __launch_bounds__(256) void k_count(const int* __restrict__ dst,
                                               int* __restrict__ cur) {
  int e = blockIdx.x * 256 + threadIdx.x;
  if (e < N_EDGES) atomicAdd(&cur[dst[e]], 1);
}

__global__ __launch_bounds__(1024) void k_scan(int* __restrict__ rs,
                                               int* __restrict__ cur,
                                               float* __restrict__ invdeg) {
  __shared__ int sd[1024];
  int t = threadIdx.x;
  const int CH = (N_NODES + 1023) / 1024;  // 49
  int beg = t * CH, end = beg + CH;
  if (beg > N_NODES) beg = N_NODES;
  if (end > N_NODES) end = N_NODES;
  int sum = 0;
  for (int i = beg; i < end; i++) sum += cur[i];
  sd[t] = sum;
  __syncthreads();
  for (int off = 1; off < 1024; off <<= 1) {
    int add = (t >= off) ? sd[t - off] : 0;
    __syncthreads();
    sd[t] += add;
    __syncthreads();
  }
  int run = sd[t] - sum;
  for (int i = beg; i < end; i++) {
    int c = cur[i];
    rs[i] = run;
    cur[i] = run;
    invdeg[i] = 1.0f / (float)(c > 1 ? c : 1);
    run += c;
  }
  if (t == 0) rs[N_NODES] = N_EDGES;
}

__global__ __launch_bounds__(256) void k_fill(const int* __restrict__ src,
                                              const int* __restrict__ dst,
                                              int* __restrict__ cur,
                                              int* __restrict__ srcs) {
  int e = blockIdx.x * 256 + threadIdx.x;
  if (e < N_EDGES) {
    int pos = atomicAdd(&cur[dst[e]], 1);
    srcs[pos] = src[e];
  }
}

// ---------------------------------------------------------------------------
// Weight prep: fp32 -> bf16, transposed to [n][k].
__global__ __launch_bounds__(256) void k_prep_w(
    const float* __restrict__ W1l, const float* __restrict__ W1r,
    const float* __restrict__ W2l, const float* __restrict__ W2r,
    unsigned short* __restrict__ Wt1, unsigned short* __restrict__ Wt2) {
  int idx = blockIdx.x * 256 + threadIdx.x;
  if (idx < 128 * 256) {
    int n = idx >> 8, k = idx & 255;
    float v = (k < 128) ? W1l[(size_t)k * 128 + n]
                        : W1r[(size_t)(k - 128) * 128 + n];
    Wt1[(size_t)n * 256 + k] = f2bf(v);
  } else if (idx < 128 * 256 + 80 * 128) {
    int j = idx - 128 * 256;
    int n = j >> 7, k = j & 127;
    float v = (n < 40) ? W2l[(size_t)k * 40 + n]
                       : W2r[(size_t)k * 40 + (n - 40)];
    Wt2[(size_t)n * 128 + k] = f2bf(v);
  }
}

// x fp32 -> bf16 into Ab[:, 128:256]
__global__ __launch_bounds__(256) void k_castx(const float* __restrict__ x,
                                               unsigned short* __restrict__ Ab) {
  int idx = blockIdx.x * 256 + threadIdx.x;  // one per 4 elems
  if (idx >= N_NODES * 32) return;
  int row = idx >> 5, c4 = (idx & 31) << 2;
  const float4 v = *(const float4*)(x + (size_t)row * F_IN + c4);
  ushort4 o;
  o.x = f2bf(v.x); o.y = f2bf(v.y); o.z = f2bf(v.z); o.w = f2bf(v.w);
  *(ushort4*)(Ab + (size_t)row * 256 + 128 + c4) = o;
}

// ---------------------------------------------------------------------------
// Layer-1 mean-aggregation: wave per node, 4 edge-slots x 16 lanes x 16B.
// Gathers bf16 x rows (256B) from Ab[:,128:256]; one wave-load covers 4
// edges. Slot partials reduced by shfl_xor; bf16 agg into Ab[:,0:128].
__global__ __launch_bounds__(256) void k_gather1(
    const int* __restrict__ rs, const int* __restrict__ srcs,
    const float* __restrict__ invdeg, unsigned short* __restrict__ Ab) {
  int node = blockIdx.x * 4 + (threadIdx.x >> 6);
  int lane = threadIdx.x & 63;
  int slot = lane >> 4, li = lane & 15;
  if (node >= N_NODES) return;
  int beg = rs[node], end = rs[node + 1];
  float acc[8];
#pragma unroll
  for (int j = 0; j < 8; j++) acc[j] = 0.f;
  for (int i = beg + slot; i < end; i += 4) {
    int s = srcs[i];
    u16x8 v = *(const u16x8*)(Ab + (size_t)s * 256 + 128 + li * 8);
#pragma unroll
    for (int j = 0; j < 8; j++) acc[j] += bf2f(v[j]);
  }
#pragma unroll
  for (int off = 16; off <= 32; off <<= 1)
#pragma unroll
    for (int j = 0; j < 8; j++) acc[j] += __shfl_xor(acc[j], off, 64);
  if (slot == 0) {
    float inv = invdeg[node];
    u16x8 o;
#pragma unroll
    for (int j = 0; j < 8; j++) o[j] = f2bf(acc[j] * inv);
    *(u16x8*)(Ab + (size_t)node * 256 + li * 8) = o;
  }
}

// ---------------------------------------------------------------------------
// h = relu([agg|x] @ [W1l;W1r] + b1)  — register-only bf16 MFMA GEMM.
__global__ __launch_bounds__(256) void k_l1(
    const unsigned short* __restrict__ Ab, const unsigned short* __restrict__ Wt1,
    const float* __restrict__ b1, unsigned short* __restrict__ hb) {
  int w = threadIdx.x >> 6, lane = threadIdx.x & 63;
  int r = lane & 15, quad = lane >> 4;
  int row0 = blockIdx.x * 64 + w * 16;
  int arow = row0 + r;
  if (arow >= N_NODES) arow = N_NODES - 1;  // clamp load, guard store
  const unsigned short* Ap = Ab + (size_t)arow * 256 + quad * 8;
  const unsigned short* Bp = Wt1 + (size_t)r * 256 + quad * 8;
  f32x4 acc[8];
#pragma unroll
  for (int n = 0; n < 8; n++) acc[n] = (f32x4){0.f, 0.f, 0.f, 0.f};
#pragma unroll
  for (int k0 = 0; k0 < 256; k0 += 32) {
    bf16x8 af = *(const bf16x8*)(Ap + k0);
#pragma unroll
    for (int n = 0; n < 8; n++) {
      bf16x8 bv = *(const bf16x8*)(Bp + (size_t)n * 16 * 256 + k0);
      acc[n] = __builtin_amdgcn_mfma_f32_16x16x32_bf16(af, bv, acc[n], 0, 0, 0);
    }
  }
  int crow0 = row0 + quad * 4;
#pragma unroll
  for (int n = 0; n < 8; n++) {
    int col = n * 16 + r;
    float bias = b1[col];
#pragma unroll
    for (int reg = 0; reg < 4; reg++) {
      int row = crow0 + reg;
      if (row < N_NODES)
        hb[(size_t)row * HIDDEN + col] = f2bf(fmaxf(acc[n][reg] + bias, 0.f));
    }
  }
}

// ---------------------------------------------------------------------------
// [p|q] = h @ [W2l|W2r] (+ b2 on q). p stored bf16, row stride 64 (padded);
// q fp32 [N,40].
__global__ __launch_bounds__(256) void k_pq(
    const unsigned short* __restrict__ hb, const unsigned short* __restrict__ Wt2,
    const float* __restrict__ b2, unsigned short* __restrict__ pb,
    float* __restrict__ q) {
  int w = threadIdx.x >> 6, lane = threadIdx.x & 63;
  int r = lane & 15, quad = lane >> 4;
  int row0 = blockIdx.x * 64 + w * 16;
  int arow = row0 + r;
  if (arow >= N_NODES) arow = N_NODES - 1;
  const unsigned short* Ap = hb + (size_t)arow * HIDDEN + quad * 8;
  const unsigned short* Bp = Wt2 + (size_t)r * 128 + quad * 8;
  f32x4 acc[5];
#pragma unroll
  for (int n = 0; n < 5; n++) acc[n] = (f32x4){0.f, 0.f, 0.f, 0.f};
#pragma unroll
  for (int k0 = 0; k0 < 128; k0 += 32) {
    bf16x8 af = *(const bf16x8*)(Ap + k0);
#pragma unroll
    for (int n = 0; n < 5; n++) {
      bf16x8 bv = *(const bf16x8*)(Bp + (size_t)n * 16 * 128 + k0);
      acc[n] = __builtin_amdgcn_mfma_f32_16x16x32_bf16(af, bv, acc[n], 0, 0, 0);
    }
  }
  int crow0 = row0 + quad * 4;
#pragma unroll
  for (int n = 0; n < 5; n++) {
    int col = n * 16 + r;
#pragma unroll
    for (int reg = 0; reg < 4; reg++) {
      int row = crow0 + reg;
      if (row < N_NODES) {
        float v = acc[n][reg];
        if (col < N_CLASSES)
          pb[(size_t)row * 64 + col] = f2bf(v);
        else
          q[(size_t)row * N_CLASSES + (col - N_CLASSES)] = v + b2[col - N_CLASSES];
      }
    }
  }
}

// ---------------------------------------------------------------------------
// Fused: layer-2 gather-mean (bf16 p, stride 64) + root + ReLU + log_softmax.
// Wave per node, 4 edge-slots x 16 lanes x 8B; shuffle reductions.
// Note: pb cols 40..63 hold poison (tiny finite bf16 values) — accumulated
// into cols >= 40 partials and discarded before softmax.
__global__ __launch_bounds__(256) void k_final(
    const unsigned short* __restrict__ pb, const float* __restrict__ q,
    const int* __restrict__ rs, const int* __restrict__ srcs,
    const float* __restrict__ invdeg, float* __restrict__ out) {
  int node = blockIdx.x * 4 + (threadIdx.x >> 6);
  int lane = threadIdx.x & 63;
  int slot = lane >> 4, li = lane & 15;
  if (node >= N_NODES) return;
  int beg = rs[node], end = rs[node + 1];
  float acc[4];
#pragma unroll
  for (int j = 0; j < 4; j++) acc[j] = 0.f;
  for (int i = beg + slot; i < end; i += 4) {
    int s = srcs[i];
    u16x4 v = *(const u16x4*)(pb + (size_t)s * 64 + li * 4);
#pragma unroll
    for (int j = 0; j < 4; j++) acc[j] += bf2f(v[j]);
  }
#pragma unroll
  for (int off = 16; off <= 32; off <<= 1)
#pragma unroll
    for (int j = 0; j < 4; j++) acc[j] += __shfl_xor(acc[j], off, 64);
  // all lanes now hold the full slot-sum (butterfly). cols = li*4 + j,
  // valid iff li < 10 (cols 0..39).
  float inv = invdeg[node];
  bool valid = li < 10;
  float4 qv = valid ? *(const float4*)(q + (size_t)node * N_CLASSES + li * 4)
                    : make_float4(0.f, 0.f, 0.f, 0.f);
  float v0 = valid ? fmaxf(acc[0] * inv + qv.x, 0.f) : -1e30f;
  float v1 = valid ? fmaxf(acc[1] * inv + qv.y, 0.f) : -1e30f;
  float v2 = valid ? fmaxf(acc[2] * inv + qv.z, 0.f) : -1e30f;
  float v3 = valid ? fmaxf(acc[3] * inv + qv.w, 0.f) : -1e30f;
  float m = fmaxf(fmaxf(v0, v1), fmaxf(v2, v3));
#pragma unroll
  for (int off = 1; off <= 8; off <<= 1) m = fmaxf(m, __shfl_xor(m, off, 16));
  float ssum = valid ? (__expf(v0 - m) + __expf(v1 - m) +
                        __expf(v2 - m) + __expf(v3 - m))
                     : 0.f;
#pragma unroll
  for (int off = 1; off <= 8; off <<= 1) ssum += __shfl_xor(ssum, off, 16);
  float lse = __logf(ssum) + m;
  if (slot == 0 && valid) {
    float4 o = make_float4(v0 - lse, v1 - lse, v2 - lse, v3 - lse);
    *(float4*)(out + (size_t)node * N_CLASSES + li * 4) = o;
  }
}

// ---------------------------------------------------------------------------
extern "C" void kernel_launch(void* const* d_in, const int* in_sizes, int n_in,
                              void* d_out, int out_size, void* d_ws,
                              size_t ws_size, hipStream_t stream) {
  const float* x   = (const float*)d_in[0];
  const int*   ei  = (const int*)d_in[1];
  const int*   src = ei;
  const int*   dst = ei + N_EDGES;
  const float* W1l = (const float*)d_in[2];
  const float* W1r = (const float*)d_in[3];
  const float* b1  = (const float*)d_in[4];
  const float* W2l = (const float*)d_in[5];
  const float* W2r = (const float*)d_in[6];
  const float* b2  = (const float*)d_in[7];
  float* out = (float*)d_out;

  float* wsf = (float*)d_ws;
  int*   rs     = (int*)wsf + OFF_RS;
  int*   cur    = (int*)wsf + OFF_CUR;
  float* invdeg = wsf + OFF_INVDEG;
  int*   srcs   = (int*)wsf + OFF_SRCS;
  unsigned short* Ab  = (unsigned short*)(wsf + OFF_AB);
  unsigned short* pb  = (unsigned short*)(wsf + OFF_PB);  // overlays dead Ab
  unsigned short* hb  = (unsigned short*)(wsf + OFF_HB);
  unsigned short* Wt1 = (unsigned short*)(wsf + OFF_WT1);
  unsigned short* Wt2 = (unsigned short*)(wsf + OFF_WT2);
  float* q = wsf + OFF_Q;

  hipMemsetAsync(cur, 0, N_NODES * sizeof(int), stream);

  k_count<<<(N_EDGES + 255) / 256, 256, 0, stream>>>(dst, cur);
  k_scan<<<1, 1024, 0, stream>>>(rs, cur, invdeg);
  k_fill<<<(N_EDGES + 255) / 256, 256, 0, stream>>>(src, dst, cur, srcs);
  k_prep_w<<<(128 * 256 + 80 * 128 + 255) / 256, 256, 0, stream>>>(
      W1l, W1r, W2l, W2r, Wt1, Wt2);
  k_castx<<<(N_NODES * 32 + 255) / 256, 256, 0, stream>>>(x, Ab);
  k_gather1<<<(N_NODES + 3) / 4, 256, 0, stream>>>(rs, srcs, invdeg, Ab);
  k_l1<<<(N_NODES + 63) / 64, 256, 0, stream>>>(Ab, Wt1, b1, hb);
  k_pq<<<(N_NODES + 63) / 64, 256, 0, stream>>>(hb, Wt2, b2, pb, q);
  k_final<<<(N_NODES + 3) / 4, 256, 0, stream>>>(pb, q, rs, srcs, invdeg, out);
}

// Round 6
// 315.511 us; speedup vs baseline: 7.6192x; 1.4071x over previous
//
#include <hip/hip_runtime.h>

#define N_NODES 50000
#define N_EDGES 800000
#define F_IN 128
#define HIDDEN 128
#define N_CLASSES 40

#define SCAN_NB 196  // ceil(50000/256)

// workspace element offsets (4B units)
#define OFF_RS     0          // int[N+1]
#define OFF_CUR    50004      // int[N]
#define OFF_INVDEG 100004     // float[N]
#define OFF_SRCS   150004     // int[E]
#define OFF_AB     950004     // ushort[N*256] bf16 A = [agg | x]; dead after k_l1
#define OFF_PB     950004     // ushort[N*64] bf16 p, stride 64 (overlays dead Ab)
#define OFF_Q      2950004    // float[N*40]
#define OFF_HB     7350004    // ushort[N*128] -> ends 10,550,004
#define OFF_WT1    10550004   // ushort[128*256] -> ends 10,566,388
#define OFF_WT2    10566388   // ushort[80*128]  -> ends 10,571,508
#define OFF_PART   10571508   // int[196] scan partials -> ends 10,571,704
// total 10,571,704 float-units = 42.3 MB

typedef short bf16x8 __attribute__((ext_vector_type(8)));
typedef float f32x4 __attribute__((ext_vector_type(4)));
typedef unsigned short u16x8 __attribute__((ext_vector_type(8)));
typedef unsigned short u16x4 __attribute__((ext_vector_type(4)));

static __device__ __forceinline__ unsigned short f2bf(float f) {
  unsigned int u = __builtin_bit_cast(unsigned int, f);
  u = (u + 0x7fffu + ((u >> 16) & 1u)) >> 16;  // RNE; inputs are finite
  return (unsigned short)u;
}
static __device__ __forceinline__ float bf2f(unsigned short s) {
  unsigned int u = ((unsigned int)s) << 16;
  return __builtin_bit_cast(float, u);
}

// ---------------------------------------------------------------------------
// CSR build step 1: per-dst degree count (int atomics only)
__global__ __launch_bounds__(256) void k_count(const int* __restrict__ dst,
                                               int* __restrict__ cur) {
  int e = blockIdx.x * 256 + threadIdx.x;
  if (e < N_EDGES) atomicAdd(&cur[dst[e]], 1);
}

// ---------------------------------------------------------------------------
// Parallel scan phase A: per-block sums of 256-element chunks.
__global__ __launch_bounds__(256) void k_scanA(const int* __restrict__ cur,
                                               int* __restrict__ part) {
  int i = blockIdx.x * 256 + threadIdx.x;
  int v = (i < N_NODES) ? cur[i] : 0;
#pragma unroll
  for (int off = 32; off; off >>= 1) v += __shfl_xor(v, off, 64);
  __shared__ int sd[4];
  if ((threadIdx.x & 63) == 0) sd[threadIdx.x >> 6] = v;
  __syncthreads();
  if (threadIdx.x == 0) part[blockIdx.x] = sd[0] + sd[1] + sd[2] + sd[3];
}

// Phase B: single small block scans the 196 partials (exclusive, in place).
__global__ __launch_bounds__(256) void k_scanB(int* __restrict__ part,
                                               int* __restrict__ rs) {
  __shared__ int sd[256];
  int t = threadIdx.x;
  int v = (t < SCAN_NB) ? part[t] : 0;
  sd[t] = v;
  __syncthreads();
  for (int off = 1; off < 256; off <<= 1) {
    int add = (t >= off) ? sd[t - off] : 0;
    __syncthreads();
    sd[t] += add;
    __syncthreads();
  }
  if (t < SCAN_NB) part[t] = sd[t] - v;  // exclusive prefix of block sums
  if (t == 0) rs[N_NODES] = N_EDGES;
}

// Phase C: block-local exclusive scan + block offset -> rs/cursor/invdeg.
__global__ __launch_bounds__(256) void k_scanC(const int* __restrict__ part,
                                               int* __restrict__ cur,
                                               int* __restrict__ rs,
                                               float* __restrict__ invdeg) {
  __shared__ int sd[256];
  int t = threadIdx.x;
  int i = blockIdx.x * 256 + t;
  int c = (i < N_NODES) ? cur[i] : 0;
  sd[t] = c;
  __syncthreads();
  for (int off = 1; off < 256; off <<= 1) {
    int add = (t >= off) ? sd[t - off] : 0;
    __syncthreads();
    sd[t] += add;
    __syncthreads();
  }
  int excl = sd[t] - c + part[blockIdx.x];
  if (i < N_NODES) {
    rs[i] = excl;
    cur[i] = excl;  // cursor for fill phase
    invdeg[i] = 1.0f / (float)(c > 1 ? c : 1);
  }
}

// ---------------------------------------------------------------------------
// CSR build step 3: bucket-fill src ids (int atomics only)
__global__ __launch_bounds__(256) void k_fill(const int* __restrict__ src,
                                              const int* __restrict__ dst,
                                              int* __restrict__ cur,
                                              int* __restrict__ srcs) {
  int e = blockIdx.x * 256 + threadIdx.x;
  if (e < N_EDGES) {
    int pos = atomicAdd(&cur[dst[e]], 1);
    srcs[pos] = src[e];
  }
}

// ---------------------------------------------------------------------------
// Fused prep: x fp32->bf16 into Ab[:,128:256], plus bf16 transposed weights.
__global__ __launch_bounds__(256) void k_prep(
    const float* __restrict__ x, const float* __restrict__ W1l,
    const float* __restrict__ W1r, const float* __restrict__ W2l,
    const float* __restrict__ W2r, unsigned short* __restrict__ Ab,
    unsigned short* __restrict__ Wt1, unsigned short* __restrict__ Wt2) {
  int idx = blockIdx.x * 256 + threadIdx.x;
  if (idx < N_NODES * 32) {  // castx: one thread per 4 elems
    int row = idx >> 5, c4 = (idx & 31) << 2;
    const float4 v = *(const float4*)(x + (size_t)row * F_IN + c4);
    ushort4 o;
    o.x = f2bf(v.x); o.y = f2bf(v.y); o.z = f2bf(v.z); o.w = f2bf(v.w);
    *(ushort4*)(Ab + (size_t)row * 256 + 128 + c4) = o;
    return;
  }
  idx -= N_NODES * 32;
  if (idx < 128 * 256) {
    int n = idx >> 8, k = idx & 255;
    float v = (k < 128) ? W1l[(size_t)k * 128 + n]
                        : W1r[(size_t)(k - 128) * 128 + n];
    Wt1[(size_t)n * 256 + k] = f2bf(v);
  } else if (idx < 128 * 256 + 80 * 128) {
    int j = idx - 128 * 256;
    int n = j >> 7, k = j & 127;
    float v = (n < 40) ? W2l[(size_t)k * 40 + n]
                       : W2r[(size_t)k * 40 + (n - 40)];
    Wt2[(size_t)n * 128 + k] = f2bf(v);
  }
}

// ---------------------------------------------------------------------------
// Layer-1 mean-aggregation: wave per node, 4 edge-slots x 16 lanes x 16B.
__global__ __launch_bounds__(256) void k_gather1(
    const int* __restrict__ rs, const int* __restrict__ srcs,
    const float* __restrict__ invdeg, unsigned short* __restrict__ Ab) {
  int node = blockIdx.x * 4 + (threadIdx.x >> 6);
  int lane = threadIdx.x & 63;
  int slot = lane >> 4, li = lane & 15;
  if (node >= N_NODES) return;
  int beg = rs[node], end = rs[node + 1];
  float acc[8];
#pragma unroll
  for (int j = 0; j < 8; j++) acc[j] = 0.f;
  for (int i = beg + slot; i < end; i += 4) {
    int s = srcs[i];
    u16x8 v = *(const u16x8*)(Ab + (size_t)s * 256 + 128 + li * 8);
#pragma unroll
    for (int j = 0; j < 8; j++) acc[j] += bf2f(v[j]);
  }
#pragma unroll
  for (int off = 16; off <= 32; off <<= 1)
#pragma unroll
    for (int j = 0; j < 8; j++) acc[j] += __shfl_xor(acc[j], off, 64);
  if (slot == 0) {
    float inv = invdeg[node];
    u16x8 o;
#pragma unroll
    for (int j = 0; j < 8; j++) o[j] = f2bf(acc[j] * inv);
    *(u16x8*)(Ab + (size_t)node * 256 + li * 8) = o;
  }
}

// ---------------------------------------------------------------------------
// h = relu([agg|x] @ [W1l;W1r] + b1)  — register-only bf16 MFMA GEMM.
__global__ __launch_bounds__(256) void k_l1(
    const unsigned short* __restrict__ Ab, const unsigned short* __restrict__ Wt1,
    const float* __restrict__ b1, unsigned short* __restrict__ hb) {
  int w = threadIdx.x >> 6, lane = threadIdx.x & 63;
  int r = lane & 15, quad = lane >> 4;
  int row0 = blockIdx.x * 64 + w * 16;
  int arow = row0 + r;
  if (arow >= N_NODES) arow = N_NODES - 1;  // clamp load, guard store
  const unsigned short* Ap = Ab + (size_t)arow * 256 + quad * 8;
  const unsigned short* Bp = Wt1 + (size_t)r * 256 + quad * 8;
  f32x4 acc[8];
#pragma unroll
  for (int n = 0; n < 8; n++) acc[n] = (f32x4){0.f, 0.f, 0.f, 0.f};
#pragma unroll
  for (int k0 = 0; k0 < 256; k0 += 32) {
    bf16x8 af = *(const bf16x8*)(Ap + k0);
#pragma unroll
    for (int n = 0; n < 8; n++) {
      bf16x8 bv = *(const bf16x8*)(Bp + (size_t)n * 16 * 256 + k0);
      acc[n] = __builtin_amdgcn_mfma_f32_16x16x32_bf16(af, bv, acc[n], 0, 0, 0);
    }
  }
  int crow0 = row0 + quad * 4;
#pragma unroll
  for (int n = 0; n < 8; n++) {
    int col = n * 16 + r;
    float bias = b1[col];
#pragma unroll
    for (int reg = 0; reg < 4; reg++) {
      int row = crow0 + reg;
      if (row < N_NODES)
        hb[(size_t)row * HIDDEN + col] = f2bf(fmaxf(acc[n][reg] + bias, 0.f));
    }
  }
}

// ---------------------------------------------------------------------------
// [p|q] = h @ [W2l|W2r] (+ b2 on q). p bf16 stride 64; q fp32 [N,40].
__global__ __launch_bounds__(256) void k_pq(
    const unsigned short* __restrict__ hb, const unsigned short* __restrict__ Wt2,
    const float* __restrict__ b2, unsigned short* __restrict__ pb,
    float* __restrict__ q) {
  int w = threadIdx.x >> 6, lane = threadIdx.x & 63;
  int r = lane & 15, quad = lane >> 4;
  int row0 = blockIdx.x * 64 + w * 16;
  int arow = row0 + r;
  if (arow >= N_NODES) arow = N_NODES - 1;
  const unsigned short* Ap = hb + (size_t)arow * HIDDEN + quad * 8;
  const unsigned short* Bp = Wt2 + (size_t)r * 128 + quad * 8;
  f32x4 acc[5];
#pragma unroll
  for (int n = 0; n < 5; n++) acc[n] = (f32x4){0.f, 0.f, 0.f, 0.f};
#pragma unroll
  for (int k0 = 0; k0 < 128; k0 += 32) {
    bf16x8 af = *(const bf16x8*)(Ap + k0);
#pragma unroll
    for (int n = 0; n < 5; n++) {
      bf16x8 bv = *(const bf16x8*)(Bp + (size_t)n * 16 * 128 + k0);
      acc[n] = __builtin_amdgcn_mfma_f32_16x16x32_bf16(af, bv, acc[n], 0, 0, 0);
    }
  }
  int crow0 = row0 + quad * 4;
#pragma unroll
  for (int n = 0; n < 5; n++) {
    int col = n * 16 + r;
#pragma unroll
    for (int reg = 0; reg < 4; reg++) {
      int row = crow0 + reg;
      if (row < N_NODES) {
        float v = acc[n][reg];
        if (col < N_CLASSES)
          pb[(size_t)row * 64 + col] = f2bf(v);
        else
          q[(size_t)row * N_CLASSES + (col - N_CLASSES)] = v + b2[col - N_CLASSES];
      }
    }
  }
}

// ---------------------------------------------------------------------------
// Fused: layer-2 gather-mean (bf16 p, stride 64) + root + ReLU + log_softmax.
__global__ __launch_bounds__(256) void k_final(
    const unsigned short* __restrict__ pb, const float* __restrict__ q,
    const int* __restrict__ rs, const int* __restrict__ srcs,
    const float* __restrict__ invdeg, float* __restrict__ out) {
  int node = blockIdx.x * 4 + (threadIdx.x >> 6);
  int lane = threadIdx.x & 63;
  int slot = lane >> 4, li = lane & 15;
  if (node >= N_NODES) return;
  int beg = rs[node], end = rs[node + 1];
  float acc[4];
#pragma unroll
  for (int j = 0; j < 4; j++) acc[j] = 0.f;
  for (int i = beg + slot; i < end; i += 4) {
    int s = srcs[i];
    u16x4 v = *(const u16x4*)(pb + (size_t)s * 64 + li * 4);
#pragma unroll
    for (int j = 0; j < 4; j++) acc[j] += bf2f(v[j]);
  }
#pragma unroll
  for (int off = 16; off <= 32; off <<= 1)
#pragma unroll
    for (int j = 0; j < 4; j++) acc[j] += __shfl_xor(acc[j], off, 64);
  float inv = invdeg[node];
  bool valid = li < 10;
  float4 qv = valid ? *(const float4*)(q + (size_t)node * N_CLASSES + li * 4)
                    : make_float4(0.f, 0.f, 0.f, 0.f);
  float v0 = valid ? fmaxf(acc[0] * inv + qv.x, 0.f) : -1e30f;
  float v1 = valid ? fmaxf(acc[1] * inv + qv.y, 0.f) : -1e30f;
  float v2 = valid ? fmaxf(acc[2] * inv + qv.z, 0.f) : -1e30f;
  float v3 = valid ? fmaxf(acc[3] * inv + qv.w, 0.f) : -1e30f;
  float m = fmaxf(fmaxf(v0, v1), fmaxf(v2, v3));
#pragma unroll
  for (int off = 1; off <= 8; off <<= 1) m = fmaxf(m, __shfl_xor(m, off, 16));
  float ssum = valid ? (__expf(v0 - m) + __expf(v1 - m) +
                        __expf(v2 - m) + __expf(v3 - m))
                     : 0.f;
#pragma unroll
  for (int off = 1; off <= 8; off <<= 1) ssum += __shfl_xor(ssum, off, 16);
  float lse = __logf(ssum) + m;
  if (slot == 0 && valid) {
    float4 o = make_float4(v0 - lse, v1 - lse, v2 - lse, v3 - lse);
    *(float4*)(out + (size_t)node * N_CLASSES + li * 4) = o;
  }
}

// ---------------------------------------------------------------------------
extern "C" void kernel_launch(void* const* d_in, const int* in_sizes, int n_in,
                              void* d_out, int out_size, void* d_ws,
                              size_t ws_size, hipStream_t stream) {
  const float* x   = (const float*)d_in[0];
  const int*   ei  = (const int*)d_in[1];
  const int*   src = ei;
  const int*   dst = ei + N_EDGES;
  const float* W1l = (const float*)d_in[2];
  const float* W1r = (const float*)d_in[3];
  const float* b1  = (const float*)d_in[4];
  const float* W2l = (const float*)d_in[5];
  const float* W2r = (const float*)d_in[6];
  const float* b2  = (const float*)d_in[7];
  float* out = (float*)d_out;

  float* wsf = (float*)d_ws;
  int*   rs     = (int*)wsf + OFF_RS;
  int*   cur    = (int*)wsf + OFF_CUR;
  float* invdeg = wsf + OFF_INVDEG;
  int*   srcs   = (int*)wsf + OFF_SRCS;
  unsigned short* Ab  = (unsigned short*)(wsf + OFF_AB);
  unsigned short* pb  = (unsigned short*)(wsf + OFF_PB);  // overlays dead Ab
  unsigned short* hb  = (unsigned short*)(wsf + OFF_HB);
  unsigned short* Wt1 = (unsigned short*)(wsf + OFF_WT1);
  unsigned short* Wt2 = (unsigned short*)(wsf + OFF_WT2);
  int*   part   = (int*)wsf + OFF_PART;
  float* q = wsf + OFF_Q;

  hipMemsetAsync(cur, 0, N_NODES * sizeof(int), stream);

  k_count<<<(N_EDGES + 255) / 256, 256, 0, stream>>>(dst, cur);
  k_scanA<<<SCAN_NB, 256, 0, stream>>>(cur, part);
  k_scanB<<<1, 256, 0, stream>>>(part, rs);
  k_scanC<<<SCAN_NB, 256, 0, stream>>>(part, cur, rs, invdeg);
  k_fill<<<(N_EDGES + 255) / 256, 256, 0, stream>>>(src, dst, cur, srcs);
  k_prep<<<(N_NODES * 32 + 128 * 256 + 80 * 128 + 255) / 256, 256, 0, stream>>>(
      x, W1l, W1r, W2l, W2r, Ab, Wt1, Wt2);
  k_gather1<<<(N_NODES + 3) / 4, 256, 0, stream>>>(rs, srcs, invdeg, Ab);
  k_l1<<<(N_NODES + 63) / 64, 256, 0, stream>>>(Ab, Wt1, b1, hb);
  k_pq<<<(N_NODES + 63) / 64, 256, 0, stream>>>(hb, Wt2, b2, pb, q);
  k_final<<<(N_NODES + 3) / 4, 256, 0, stream>>>(pb, q, rs, srcs, invdeg, out);
}

// Round 7
// 250.952 us; speedup vs baseline: 9.5793x; 1.2573x over previous
//
#include <hip/hip_runtime.h>

#define N_NODES 50000
#define N_EDGES 800000
#define F_IN 128
#define HIDDEN 128
#define N_CLASSES 40

#define NBUCKET 196      // ceil(50000/256) buckets of 256 nodes
#define BUCKET_CAP 8192  // per-bucket capacity (mean fill 4096, sd ~64)
#define BINA_CHUNK 4096
#define BINA_NBLK 196    // ceil(800000/4096)
#define PREP_ITEMS (N_NODES * 32 + 128 * 256 + 80 * 128)  // 1,643,008
#define PREP_NBLK (PREP_ITEMS / 256)                       // 6418 (exact)

// workspace element offsets (4B units)
#define OFF_RS     0          // int[N+1]
#define OFF_BCNT   50004      // int[196] global bucket counts
#define OFF_INVDEG 100004     // float[N]
#define OFF_SRCS   150004     // int[E] -> ends 950,004
#define OFF_AB     950004     // ushort[N*256] bf16 [agg|x]; spans ->7,350,004
#define OFF_PB     950004     // ushort[N*64] bf16 p (overlays dead Ab, ->2,550,004)
#define OFF_Q      2950004    // float[N*40] (inside dead-Ab span, after PB end)
#define OFF_BINS   7350004    // int[196*8192] bucketed edges (dead before hb live)
#define OFF_HB     7350004    // ushort[N*128] -> ends 10,550,004 (overlays dead bins)
#define OFF_WT1    10550004   // ushort[128*256] -> ends 10,566,388
#define OFF_WT2    10566388   // ushort[80*128]  -> ends 10,571,508
// total 10,571,508 float-units = 42.3 MB (proven available)

typedef short bf16x8 __attribute__((ext_vector_type(8)));
typedef float f32x4 __attribute__((ext_vector_type(4)));
typedef unsigned short u16x8 __attribute__((ext_vector_type(8)));
typedef unsigned short u16x4 __attribute__((ext_vector_type(4)));

static __device__ __forceinline__ unsigned short f2bf(float f) {
  unsigned int u = __builtin_bit_cast(unsigned int, f);
  u = (u + 0x7fffu + ((u >> 16) & 1u)) >> 16;  // RNE; inputs are finite
  return (unsigned short)u;
}
static __device__ __forceinline__ float bf2f(unsigned short s) {
  unsigned int u = ((unsigned int)s) << 16;
  return __builtin_bit_cast(float, u);
}

// ---------------------------------------------------------------------------
// Fused: bucket-sort phase A (blocks 0..195) + weight/x prep (blocks 196+).
// binA: per-block LDS counting sort of 4096 edges into 196 dst-buckets;
// per-bucket global ranges claimed via one atomicAdd return per bucket;
// writes are CONTIGUOUS per bucket-group (no masked-write amplification).
__global__ __launch_bounds__(256) void k_binA_prep(
    const int* __restrict__ src, const int* __restrict__ dst,
    int* __restrict__ bcnt, int* __restrict__ bins,
    const float* __restrict__ x, const float* __restrict__ W1l,
    const float* __restrict__ W1r, const float* __restrict__ W2l,
    const float* __restrict__ W2r, unsigned short* __restrict__ Ab,
    unsigned short* __restrict__ Wt1, unsigned short* __restrict__ Wt2) {
  if (blockIdx.x >= BINA_NBLK) {
    // ---- prep path (independent of CSR build) ----
    int idx = (blockIdx.x - BINA_NBLK) * 256 + threadIdx.x;
    if (idx < N_NODES * 32) {  // x fp32 -> bf16, one thread per 4 elems
      int row = idx >> 5, c4 = (idx & 31) << 2;
      const float4 v = *(const float4*)(x + (size_t)row * F_IN + c4);
      ushort4 o;
      o.x = f2bf(v.x); o.y = f2bf(v.y); o.z = f2bf(v.z); o.w = f2bf(v.w);
      *(ushort4*)(Ab + (size_t)row * 256 + 128 + c4) = o;
      return;
    }
    idx -= N_NODES * 32;
    if (idx < 128 * 256) {
      int n = idx >> 8, k = idx & 255;
      float v = (k < 128) ? W1l[(size_t)k * 128 + n]
                          : W1r[(size_t)(k - 128) * 128 + n];
      Wt1[(size_t)n * 256 + k] = f2bf(v);
    } else if (idx < 128 * 256 + 80 * 128) {
      int j = idx - 128 * 256;
      int n = j >> 7, k = j & 127;
      float v = (n < 40) ? W2l[(size_t)k * 40 + n]
                         : W2r[(size_t)k * 40 + (n - 40)];
      Wt2[(size_t)n * 128 + k] = f2bf(v);
    }
    return;
  }
  // ---- binA path ----
  __shared__ int cnt[NBUCKET];
  __shared__ int excl[NBUCKET];
  __shared__ int cursor[NBUCKET];
  __shared__ int bbase[NBUCKET];
  __shared__ int sc[256];
  __shared__ int stage[BINA_CHUNK];
  __shared__ unsigned char bkt[BINA_CHUNK];
  int t = threadIdx.x;
  int e0 = blockIdx.x * BINA_CHUNK;
  int ne = N_EDGES - e0;
  if (ne > BINA_CHUNK) ne = BINA_CHUNK;
  if (t < NBUCKET) cnt[t] = 0;
  __syncthreads();
  for (int i = t; i < ne; i += 256) atomicAdd(&cnt[dst[e0 + i] >> 8], 1);
  __syncthreads();
  int v = (t < NBUCKET) ? cnt[t] : 0;
  sc[t] = v;
  __syncthreads();
  for (int off = 1; off < 256; off <<= 1) {  // Hillis inclusive scan
    int add = (t >= off) ? sc[t - off] : 0;
    __syncthreads();
    sc[t] += add;
    __syncthreads();
  }
  if (t < NBUCKET) {
    int ex = sc[t] - v;
    excl[t] = ex;
    cursor[t] = ex;
    bbase[t] = atomicAdd(&bcnt[t], v);  // claim contiguous range in bucket t
  }
  __syncthreads();
  for (int i = t; i < ne; i += 256) {
    int d = dst[e0 + i];
    int s = src[e0 + i];
    int b = d >> 8;
    int pos = atomicAdd(&cursor[b], 1);
    stage[pos] = ((d & 255) << 16) | s;  // src < 65536 fits 16 bits
    bkt[pos] = (unsigned char)b;
  }
  __syncthreads();
  for (int i = t; i < ne; i += 256) {
    int b = bkt[i];
    bins[(size_t)b * BUCKET_CAP + bbase[b] + (i - excl[b])] = stage[i];
  }
}

// ---------------------------------------------------------------------------
// Bucket-sort phase B: one block per bucket (256 nodes). Builds final CSR:
// rs / invdeg / srcs. Scattered srcs writes confined to one block's 16KB
// region -> fully merged in its XCD L2 (no amplification).
__global__ __launch_bounds__(256) void k_binB(
    const int* __restrict__ bcnt, const int* __restrict__ bins,
    int* __restrict__ rs, int* __restrict__ srcs,
    float* __restrict__ invdeg) {
  __shared__ int sc[256];
  __shared__ int hist[256];
  __shared__ int cursor[256];
  int b = blockIdx.x;
  int t = threadIdx.x;
  // base = sum(bcnt[0..b-1])
  sc[t] = (t < NBUCKET && t < b) ? bcnt[t] : 0;
  __syncthreads();
  for (int off = 128; off; off >>= 1) {
    if (t < off) sc[t] += sc[t + off];
    __syncthreads();
  }
  int base = sc[0];
  int cnt = bcnt[b];
  const int* bb = bins + (size_t)b * BUCKET_CAP;
  hist[t] = 0;
  __syncthreads();
  for (int i = t; i < cnt; i += 256) atomicAdd(&hist[bb[i] >> 16], 1);
  __syncthreads();
  int c = hist[t];
  sc[t] = c;
  __syncthreads();
  for (int off = 1; off < 256; off <<= 1) {  // Hillis inclusive scan
    int add = (t >= off) ? sc[t - off] : 0;
    __syncthreads();
    sc[t] += add;
    __syncthreads();
  }
  int lexcl = sc[t] - c;
  int node = b * 256 + t;
  if (node < N_NODES) {
    rs[node] = base + lexcl;
    invdeg[node] = 1.0f / (float)(c > 1 ? c : 1);
  }
  if (b == 0 && t == 0) rs[N_NODES] = N_EDGES;
  cursor[t] = lexcl;
  __syncthreads();
  for (int i = t; i < cnt; i += 256) {
    int v = bb[i];
    int pos = atomicAdd(&cursor[v >> 16], 1);
    srcs[base + pos] = v & 0xFFFF;
  }
}

// ---------------------------------------------------------------------------
// Layer-1 mean-aggregation: wave per node, 4 edge-slots x 16 lanes x 16B.
__global__ __launch_bounds__(256) void k_gather1(
    const int* __restrict__ rs, const int* __restrict__ srcs,
    const float* __restrict__ invdeg, unsigned short* __restrict__ Ab) {
  int node = blockIdx.x * 4 + (threadIdx.x >> 6);
  int lane = threadIdx.x & 63;
  int slot = lane >> 4, li = lane & 15;
  if (node >= N_NODES) return;
  int beg = rs[node], end = rs[node + 1];
  float acc[8];
#pragma unroll
  for (int j = 0; j < 8; j++) acc[j] = 0.f;
  for (int i = beg + slot; i < end; i += 4) {
    int s = srcs[i];
    u16x8 v = *(const u16x8*)(Ab + (size_t)s * 256 + 128 + li * 8);
#pragma unroll
    for (int j = 0; j < 8; j++) acc[j] += bf2f(v[j]);
  }
#pragma unroll
  for (int off = 16; off <= 32; off <<= 1)
#pragma unroll
    for (int j = 0; j < 8; j++) acc[j] += __shfl_xor(acc[j], off, 64);
  if (slot == 0) {
    float inv = invdeg[node];
    u16x8 o;
#pragma unroll
    for (int j = 0; j < 8; j++) o[j] = f2bf(acc[j] * inv);
    *(u16x8*)(Ab + (size_t)node * 256 + li * 8) = o;
  }
}

// ---------------------------------------------------------------------------
// h = relu([agg|x] @ [W1l;W1r] + b1)  — register-only bf16 MFMA GEMM.
__global__ __launch_bounds__(256) void k_l1(
    const unsigned short* __restrict__ Ab, const unsigned short* __restrict__ Wt1,
    const float* __restrict__ b1, unsigned short* __restrict__ hb) {
  int w = threadIdx.x >> 6, lane = threadIdx.x & 63;
  int r = lane & 15, quad = lane >> 4;
  int row0 = blockIdx.x * 64 + w * 16;
  int arow = row0 + r;
  if (arow >= N_NODES) arow = N_NODES - 1;  // clamp load, guard store
  const unsigned short* Ap = Ab + (size_t)arow * 256 + quad * 8;
  const unsigned short* Bp = Wt1 + (size_t)r * 256 + quad * 8;
  f32x4 acc[8];
#pragma unroll
  for (int n = 0; n < 8; n++) acc[n] = (f32x4){0.f, 0.f, 0.f, 0.f};
#pragma unroll
  for (int k0 = 0; k0 < 256; k0 += 32) {
    bf16x8 af = *(const bf16x8*)(Ap + k0);
#pragma unroll
    for (int n = 0; n < 8; n++) {
      bf16x8 bv = *(const bf16x8*)(Bp + (size_t)n * 16 * 256 + k0);
      acc[n] = __builtin_amdgcn_mfma_f32_16x16x32_bf16(af, bv, acc[n], 0, 0, 0);
    }
  }
  int crow0 = row0 + quad * 4;
#pragma unroll
  for (int n = 0; n < 8; n++) {
    int col = n * 16 + r;
    float bias = b1[col];
#pragma unroll
    for (int reg = 0; reg < 4; reg++) {
      int row = crow0 + reg;
      if (row < N_NODES)
        hb[(size_t)row * HIDDEN + col] = f2bf(fmaxf(acc[n][reg] + bias, 0.f));
    }
  }
}

// ---------------------------------------------------------------------------
// [p|q] = h @ [W2l|W2r] (+ b2 on q). p bf16 stride 64; q fp32 [N,40].
__global__ __launch_bounds__(256) void k_pq(
    const unsigned short* __restrict__ hb, const unsigned short* __restrict__ Wt2,
    const float* __restrict__ b2, unsigned short* __restrict__ pb,
    float* __restrict__ q) {
  int w = threadIdx.x >> 6, lane = threadIdx.x & 63;
  int r = lane & 15, quad = lane >> 4;
  int row0 = blockIdx.x * 64 + w * 16;
  int arow = row0 + r;
  if (arow >= N_NODES) arow = N_NODES - 1;
  const unsigned short* Ap = hb + (size_t)arow * HIDDEN + quad * 8;
  const unsigned short* Bp = Wt2 + (size_t)r * 128 + quad * 8;
  f32x4 acc[5];
#pragma unroll
  for (int n = 0; n < 5; n++) acc[n] = (f32x4){0.f, 0.f, 0.f, 0.f};
#pragma unroll
  for (int k0 = 0; k0 < 128; k0 += 32) {
    bf16x8 af = *(const bf16x8*)(Ap + k0);
#pragma unroll
    for (int n = 0; n < 5; n++) {
      bf16x8 bv = *(const bf16x8*)(Bp + (size_t)n * 16 * 128 + k0);
      acc[n] = __builtin_amdgcn_mfma_f32_16x16x32_bf16(af, bv, acc[n], 0, 0, 0);
    }
  }
  int crow0 = row0 + quad * 4;
#pragma unroll
  for (int n = 0; n < 5; n++) {
    int col = n * 16 + r;
#pragma unroll
    for (int reg = 0; reg < 4; reg++) {
      int row = crow0 + reg;
      if (row < N_NODES) {
        float v = acc[n][reg];
        if (col < N_CLASSES)
          pb[(size_t)row * 64 + col] = f2bf(v);
        else
          q[(size_t)row * N_CLASSES + (col - N_CLASSES)] = v + b2[col - N_CLASSES];
      }
    }
  }
}

// ---------------------------------------------------------------------------
// Fused: layer-2 gather-mean (bf16 p, stride 64) + root + ReLU + log_softmax.
__global__ __launch_bounds__(256) void k_final(
    const unsigned short* __restrict__ pb, const float* __restrict__ q,
    const int* __restrict__ rs, const int* __restrict__ srcs,
    const float* __restrict__ invdeg, float* __restrict__ out) {
  int node = blockIdx.x * 4 + (threadIdx.x >> 6);
  int lane = threadIdx.x & 63;
  int slot = lane >> 4, li = lane & 15;
  if (node >= N_NODES) return;
  int beg = rs[node], end = rs[node + 1];
  float acc[4];
#pragma unroll
  for (int j = 0; j < 4; j++) acc[j] = 0.f;
  for (int i = beg + slot; i < end; i += 4) {
    int s = srcs[i];
    u16x4 v = *(const u16x4*)(pb + (size_t)s * 64 + li * 4);
#pragma unroll
    for (int j = 0; j < 4; j++) acc[j] += bf2f(v[j]);
  }
#pragma unroll
  for (int off = 16; off <= 32; off <<= 1)
#pragma unroll
    for (int j = 0; j < 4; j++) acc[j] += __shfl_xor(acc[j], off, 64);
  float inv = invdeg[node];
  bool valid = li < 10;
  float4 qv = valid ? *(const float4*)(q + (size_t)node * N_CLASSES + li * 4)
                    : make_float4(0.f, 0.f, 0.f, 0.f);
  float v0 = valid ? fmaxf(acc[0] * inv + qv.x, 0.f) : -1e30f;
  float v1 = valid ? fmaxf(acc[1] * inv + qv.y, 0.f) : -1e30f;
  float v2 = valid ? fmaxf(acc[2] * inv + qv.z, 0.f) : -1e30f;
  float v3 = valid ? fmaxf(acc[3] * inv + qv.w, 0.f) : -1e30f;
  float m = fmaxf(fmaxf(v0, v1), fmaxf(v2, v3));
#pragma unroll
  for (int off = 1; off <= 8; off <<= 1) m = fmaxf(m, __shfl_xor(m, off, 16));
  float ssum = valid ? (__expf(v0 - m) + __expf(v1 - m) +
                        __expf(v2 - m) + __expf(v3 - m))
                     : 0.f;
#pragma unroll
  for (int off = 1; off <= 8; off <<= 1) ssum += __shfl_xor(ssum, off, 16);
  float lse = __logf(ssum) + m;
  if (slot == 0 && valid) {
    float4 o = make_float4(v0 - lse, v1 - lse, v2 - lse, v3 - lse);
    *(float4*)(out + (size_t)node * N_CLASSES + li * 4) = o;
  }
}

// ---------------------------------------------------------------------------
extern "C" void kernel_launch(void* const* d_in, const int* in_sizes, int n_in,
                              void* d_out, int out_size, void* d_ws,
                              size_t ws_size, hipStream_t stream) {
  const float* x   = (const float*)d_in[0];
  const int*   ei  = (const int*)d_in[1];
  const int*   src = ei;
  const int*   dst = ei + N_EDGES;
  const float* W1l = (const float*)d_in[2];
  const float* W1r = (const float*)d_in[3];
  const float* b1  = (const float*)d_in[4];
  const float* W2l = (const float*)d_in[5];
  const float* W2r = (const float*)d_in[6];
  const float* b2  = (const float*)d_in[7];
  float* out = (float*)d_out;

  float* wsf = (float*)d_ws;
  int*   rs     = (int*)wsf + OFF_RS;
  int*   bcnt   = (int*)wsf + OFF_BCNT;
  float* invdeg = wsf + OFF_INVDEG;
  int*   srcs   = (int*)wsf + OFF_SRCS;
  unsigned short* Ab  = (unsigned short*)(wsf + OFF_AB);
  unsigned short* pb  = (unsigned short*)(wsf + OFF_PB);
  unsigned short* hb  = (unsigned short*)(wsf + OFF_HB);
  unsigned short* Wt1 = (unsigned short*)(wsf + OFF_WT1);
  unsigned short* Wt2 = (unsigned short*)(wsf + OFF_WT2);
  int*   bins   = (int*)wsf + OFF_BINS;
  float* q = wsf + OFF_Q;

  hipMemsetAsync(bcnt, 0, NBUCKET * sizeof(int), stream);

  k_binA_prep<<<BINA_NBLK + PREP_NBLK, 256, 0, stream>>>(
      src, dst, bcnt, bins, x, W1l, W1r, W2l, W2r, Ab, Wt1, Wt2);
  k_binB<<<NBUCKET, 256, 0, stream>>>(bcnt, bins, rs, srcs, invdeg);
  k_gather1<<<(N_NODES + 3) / 4, 256, 0, stream>>>(rs, srcs, invdeg, Ab);
  k_l1<<<(N_NODES + 63) / 64, 256, 0, stream>>>(Ab, Wt1, b1, hb);
  k_pq<<<(N_NODES + 63) / 64, 256, 0, stream>>>(hb, Wt2, b2, pb, q);
  k_final<<<(N_NODES + 3) / 4, 256, 0, stream>>>(pb, q, rs, srcs, invdeg, out);
}

// Round 8
// 240.621 us; speedup vs baseline: 9.9906x; 1.0429x over previous
//
#include <hip/hip_runtime.h>

#define N_NODES 50000
#define N_EDGES 800000
#define F_IN 128
#define HIDDEN 128
#define N_CLASSES 40

#define NBUCKET 196      // ceil(50000/256) buckets of 256 nodes
#define BUCKET_CAP 8192  // per-bucket capacity (mean fill 4096, sd ~64)
#define BINA_CHUNK 4096
#define BINA_NBLK 196    // ceil(800000/4096)
#define PREP_ITEMS (N_NODES * 32 + 128 * 256 + 80 * 128)  // 1,643,008
#define PREP_NBLK (PREP_ITEMS / 256)                       // 6418 (exact)

// workspace element offsets (4B units)
#define OFF_RS     0          // int[N+1]
#define OFF_BCNT   50004      // int[196] global bucket counts
#define OFF_INVDEG 100004     // float[N]
#define OFF_SRCS   150004     // int[E] -> ends 950,004
#define OFF_AB     950004     // ushort[N*256] bf16 [agg|x]; spans ->7,350,004
#define OFF_PB     950004     // ushort[N*40] bf16 p stride 40 (overlays dead Ab, ->1,950,004)
#define OFF_Q      2950004    // float[N*40] (inside dead-Ab span, after PB end)
#define OFF_BINS   7350004    // int[196*8192] bucketed edges (dead before hb live)
#define OFF_HB     7350004    // ushort[N*128] -> ends 10,550,004 (overlays dead bins)
#define OFF_WT1    10550004   // ushort[128*256] -> ends 10,566,388
#define OFF_WT2    10566388   // ushort[80*128]  -> ends 10,571,508
// total 10,571,508 float-units = 42.3 MB (proven available)

typedef short bf16x8 __attribute__((ext_vector_type(8)));
typedef float f32x4 __attribute__((ext_vector_type(4)));
typedef unsigned short u16x8 __attribute__((ext_vector_type(8)));

static __device__ __forceinline__ unsigned short f2bf(float f) {
  unsigned int u = __builtin_bit_cast(unsigned int, f);
  u = (u + 0x7fffu + ((u >> 16) & 1u)) >> 16;  // RNE; inputs are finite
  return (unsigned short)u;
}
static __device__ __forceinline__ float bf2f(unsigned short s) {
  unsigned int u = ((unsigned int)s) << 16;
  return __builtin_bit_cast(float, u);
}

// ---------------------------------------------------------------------------
// Fused: bucket-sort phase A (blocks 0..195) + weight/x prep (blocks 196+).
__global__ __launch_bounds__(256) void k_binA_prep(
    const int* __restrict__ src, const int* __restrict__ dst,
    int* __restrict__ bcnt, int* __restrict__ bins,
    const float* __restrict__ x, const float* __restrict__ W1l,
    const float* __restrict__ W1r, const float* __restrict__ W2l,
    const float* __restrict__ W2r, unsigned short* __restrict__ Ab,
    unsigned short* __restrict__ Wt1, unsigned short* __restrict__ Wt2) {
  if (blockIdx.x >= BINA_NBLK) {
    // ---- prep path (independent of CSR build) ----
    int idx = (blockIdx.x - BINA_NBLK) * 256 + threadIdx.x;
    if (idx < N_NODES * 32) {  // x fp32 -> bf16, one thread per 4 elems
      int row = idx >> 5, c4 = (idx & 31) << 2;
      const float4 v = *(const float4*)(x + (size_t)row * F_IN + c4);
      ushort4 o;
      o.x = f2bf(v.x); o.y = f2bf(v.y); o.z = f2bf(v.z); o.w = f2bf(v.w);
      *(ushort4*)(Ab + (size_t)row * 256 + 128 + c4) = o;
      return;
    }
    idx -= N_NODES * 32;
    if (idx < 128 * 256) {
      int n = idx >> 8, k = idx & 255;
      float v = (k < 128) ? W1l[(size_t)k * 128 + n]
                          : W1r[(size_t)(k - 128) * 128 + n];
      Wt1[(size_t)n * 256 + k] = f2bf(v);
    } else if (idx < 128 * 256 + 80 * 128) {
      int j = idx - 128 * 256;
      int n = j >> 7, k = j & 127;
      float v = (n < 40) ? W2l[(size_t)k * 40 + n]
                         : W2r[(size_t)k * 40 + (n - 40)];
      Wt2[(size_t)n * 128 + k] = f2bf(v);
    }
    return;
  }
  // ---- binA path: LDS counting sort of 4096 edges into 196 dst-buckets ----
  __shared__ int cnt[NBUCKET];
  __shared__ int excl[NBUCKET];
  __shared__ int cursor[NBUCKET];
  __shared__ int bbase[NBUCKET];
  __shared__ int sc[256];
  __shared__ int stage[BINA_CHUNK];
  __shared__ unsigned char bkt[BINA_CHUNK];
  int t = threadIdx.x;
  int e0 = blockIdx.x * BINA_CHUNK;
  int ne = N_EDGES - e0;
  if (ne > BINA_CHUNK) ne = BINA_CHUNK;
  if (t < NBUCKET) cnt[t] = 0;
  __syncthreads();
  for (int i = t; i < ne; i += 256) atomicAdd(&cnt[dst[e0 + i] >> 8], 1);
  __syncthreads();
  int v = (t < NBUCKET) ? cnt[t] : 0;
  sc[t] = v;
  __syncthreads();
  for (int off = 1; off < 256; off <<= 1) {  // Hillis inclusive scan
    int add = (t >= off) ? sc[t - off] : 0;
    __syncthreads();
    sc[t] += add;
    __syncthreads();
  }
  if (t < NBUCKET) {
    int ex = sc[t] - v;
    excl[t] = ex;
    cursor[t] = ex;
    bbase[t] = atomicAdd(&bcnt[t], v);  // claim contiguous range in bucket t
  }
  __syncthreads();
  for (int i = t; i < ne; i += 256) {
    int d = dst[e0 + i];
    int s = src[e0 + i];
    int b = d >> 8;
    int pos = atomicAdd(&cursor[b], 1);
    stage[pos] = ((d & 255) << 16) | s;  // src < 65536 fits 16 bits
    bkt[pos] = (unsigned char)b;
  }
  __syncthreads();
  for (int i = t; i < ne; i += 256) {
    int b = bkt[i];
    bins[(size_t)b * BUCKET_CAP + bbase[b] + (i - excl[b])] = stage[i];
  }
}

// ---------------------------------------------------------------------------
// Bucket-sort phase B: one block per bucket (256 nodes). Builds final CSR.
__global__ __launch_bounds__(256) void k_binB(
    const int* __restrict__ bcnt, const int* __restrict__ bins,
    int* __restrict__ rs, int* __restrict__ srcs,
    float* __restrict__ invdeg) {
  __shared__ int sc[256];
  __shared__ int hist[256];
  __shared__ int cursor[256];
  int b = blockIdx.x;
  int t = threadIdx.x;
  sc[t] = (t < NBUCKET && t < b) ? bcnt[t] : 0;
  __syncthreads();
  for (int off = 128; off; off >>= 1) {
    if (t < off) sc[t] += sc[t + off];
    __syncthreads();
  }
  int base = sc[0];
  int cnt = bcnt[b];
  const int* bb = bins + (size_t)b * BUCKET_CAP;
  hist[t] = 0;
  __syncthreads();
  for (int i = t; i < cnt; i += 256) atomicAdd(&hist[bb[i] >> 16], 1);
  __syncthreads();
  int c = hist[t];
  sc[t] = c;
  __syncthreads();
  for (int off = 1; off < 256; off <<= 1) {
    int add = (t >= off) ? sc[t - off] : 0;
    __syncthreads();
    sc[t] += add;
    __syncthreads();
  }
  int lexcl = sc[t] - c;
  int node = b * 256 + t;
  if (node < N_NODES) {
    rs[node] = base + lexcl;
    invdeg[node] = 1.0f / (float)(c > 1 ? c : 1);
  }
  if (b == 0 && t == 0) rs[N_NODES] = N_EDGES;
  cursor[t] = lexcl;
  __syncthreads();
  for (int i = t; i < cnt; i += 256) {
    int v = bb[i];
    int pos = atomicAdd(&cursor[v >> 16], 1);
    srcs[base + pos] = v & 0xFFFF;
  }
}

// ---------------------------------------------------------------------------
// Layer-1 mean-aggregation: wave per node, 8 edge-slots x 8 lanes x 2x16B.
// 16 cache lines outstanding per wave (2x the R7 MLP).
__global__ __launch_bounds__(256) void k_gather1(
    const int* __restrict__ rs, const int* __restrict__ srcs,
    const float* __restrict__ invdeg, unsigned short* __restrict__ Ab) {
  int node = blockIdx.x * 4 + (threadIdx.x >> 6);
  int lane = threadIdx.x & 63;
  int slot = lane >> 3, li = lane & 7;
  if (node >= N_NODES) return;
  int beg = rs[node], end = rs[node + 1];
  float acc[16];
#pragma unroll
  for (int j = 0; j < 16; j++) acc[j] = 0.f;
  for (int i = beg + slot; i < end; i += 8) {
    int s = srcs[i];
    const unsigned short* rp = Ab + (size_t)s * 256 + 128 + li * 8;
    u16x8 v0 = *(const u16x8*)rp;
    u16x8 v1 = *(const u16x8*)(rp + 64);
#pragma unroll
    for (int j = 0; j < 8; j++) {
      acc[j] += bf2f(v0[j]);
      acc[8 + j] += bf2f(v1[j]);
    }
  }
#pragma unroll
  for (int off = 8; off <= 32; off <<= 1)
#pragma unroll
    for (int j = 0; j < 16; j++) acc[j] += __shfl_xor(acc[j], off, 64);
  if (slot == 0) {  // lanes 0..7 cover cols li*8 and 64+li*8
    float inv = invdeg[node];
    u16x8 o0, o1;
#pragma unroll
    for (int j = 0; j < 8; j++) {
      o0[j] = f2bf(acc[j] * inv);
      o1[j] = f2bf(acc[8 + j] * inv);
    }
    *(u16x8*)(Ab + (size_t)node * 256 + li * 8) = o0;
    *(u16x8*)(Ab + (size_t)node * 256 + 64 + li * 8) = o1;
  }
}

// ---------------------------------------------------------------------------
// h = relu([agg|x] @ [W1l;W1r] + b1)  — register-only bf16 MFMA GEMM.
__global__ __launch_bounds__(256) void k_l1(
    const unsigned short* __restrict__ Ab, const unsigned short* __restrict__ Wt1,
    const float* __restrict__ b1, unsigned short* __restrict__ hb) {
  int w = threadIdx.x >> 6, lane = threadIdx.x & 63;
  int r = lane & 15, quad = lane >> 4;
  int row0 = blockIdx.x * 64 + w * 16;
  int arow = row0 + r;
  if (arow >= N_NODES) arow = N_NODES - 1;  // clamp load, guard store
  const unsigned short* Ap = Ab + (size_t)arow * 256 + quad * 8;
  const unsigned short* Bp = Wt1 + (size_t)r * 256 + quad * 8;
  f32x4 acc[8];
#pragma unroll
  for (int n = 0; n < 8; n++) acc[n] = (f32x4){0.f, 0.f, 0.f, 0.f};
#pragma unroll
  for (int k0 = 0; k0 < 256; k0 += 32) {
    bf16x8 af = *(const bf16x8*)(Ap + k0);
#pragma unroll
    for (int n = 0; n < 8; n++) {
      bf16x8 bv = *(const bf16x8*)(Bp + (size_t)n * 16 * 256 + k0);
      acc[n] = __builtin_amdgcn_mfma_f32_16x16x32_bf16(af, bv, acc[n], 0, 0, 0);
    }
  }
  int crow0 = row0 + quad * 4;
#pragma unroll
  for (int n = 0; n < 8; n++) {
    int col = n * 16 + r;
    float bias = b1[col];
#pragma unroll
    for (int reg = 0; reg < 4; reg++) {
      int row = crow0 + reg;
      if (row < N_NODES)
        hb[(size_t)row * HIDDEN + col] = f2bf(fmaxf(acc[n][reg] + bias, 0.f));
    }
  }
}

// ---------------------------------------------------------------------------
// [p|q] = h @ [W2l|W2r] (+ b2 on q). p bf16 stride 40 (compact); q fp32 [N,40].
__global__ __launch_bounds__(256) void k_pq(
    const unsigned short* __restrict__ hb, const unsigned short* __restrict__ Wt2,
    const float* __restrict__ b2, unsigned short* __restrict__ pb,
    float* __restrict__ q) {
  int w = threadIdx.x >> 6, lane = threadIdx.x & 63;
  int r = lane & 15, quad = lane >> 4;
  int row0 = blockIdx.x * 64 + w * 16;
  int arow = row0 + r;
  if (arow >= N_NODES) arow = N_NODES - 1;
  const unsigned short* Ap = hb + (size_t)arow * HIDDEN + quad * 8;
  const unsigned short* Bp = Wt2 + (size_t)r * 128 + quad * 8;
  f32x4 acc[5];
#pragma unroll
  for (int n = 0; n < 5; n++) acc[n] = (f32x4){0.f, 0.f, 0.f, 0.f};
#pragma unroll
  for (int k0 = 0; k0 < 128; k0 += 32) {
    bf16x8 af = *(const bf16x8*)(Ap + k0);
#pragma unroll
    for (int n = 0; n < 5; n++) {
      bf16x8 bv = *(const bf16x8*)(Bp + (size_t)n * 16 * 128 + k0);
      acc[n] = __builtin_amdgcn_mfma_f32_16x16x32_bf16(af, bv, acc[n], 0, 0, 0);
    }
  }
  int crow0 = row0 + quad * 4;
#pragma unroll
  for (int n = 0; n < 5; n++) {
    int col = n * 16 + r;
#pragma unroll
    for (int reg = 0; reg < 4; reg++) {
      int row = crow0 + reg;
      if (row < N_NODES) {
        float v = acc[n][reg];
        if (col < N_CLASSES)
          pb[(size_t)row * 40 + col] = f2bf(v);
        else
          q[(size_t)row * N_CLASSES + (col - N_CLASSES)] = v + b2[col - N_CLASSES];
      }
    }
  }
}

// ---------------------------------------------------------------------------
// Fused: layer-2 gather-mean (bf16 p, stride 40) + root + ReLU + log_softmax.
// Wave per node, 8 edge-slots x (5 active lanes x 16B = 80B/edge).
__global__ __launch_bounds__(256) void k_final(
    const unsigned short* __restrict__ pb, const float* __restrict__ q,
    const int* __restrict__ rs, const int* __restrict__ srcs,
    const float* __restrict__ invdeg, float* __restrict__ out) {
  int node = blockIdx.x * 4 + (threadIdx.x >> 6);
  int lane = threadIdx.x & 63;
  int slot = lane >> 3, li = lane & 7;
  if (node >= N_NODES) return;
  bool valid = li < 5;  // lane li covers cols li*8..li*8+7 (<40)
  int beg = rs[node], end = rs[node + 1];
  float acc[8];
#pragma unroll
  for (int j = 0; j < 8; j++) acc[j] = 0.f;
  for (int i = beg + slot; i < end; i += 8) {
    int s = srcs[i];
    if (valid) {
      u16x8 v = *(const u16x8*)(pb + (size_t)s * 40 + li * 8);
#pragma unroll
      for (int j = 0; j < 8; j++) acc[j] += bf2f(v[j]);
    }
  }
#pragma unroll
  for (int off = 8; off <= 32; off <<= 1)
#pragma unroll
    for (int j = 0; j < 8; j++) acc[j] += __shfl_xor(acc[j], off, 64);
  float inv = invdeg[node];
  float v[8];
  float m = -1e30f;
  if (valid) {
    const float* qr = q + (size_t)node * N_CLASSES + li * 8;
    float4 q0 = *(const float4*)qr;
    float4 q1 = *(const float4*)(qr + 4);
    v[0] = fmaxf(acc[0] * inv + q0.x, 0.f);
    v[1] = fmaxf(acc[1] * inv + q0.y, 0.f);
    v[2] = fmaxf(acc[2] * inv + q0.z, 0.f);
    v[3] = fmaxf(acc[3] * inv + q0.w, 0.f);
    v[4] = fmaxf(acc[4] * inv + q1.x, 0.f);
    v[5] = fmaxf(acc[5] * inv + q1.y, 0.f);
    v[6] = fmaxf(acc[6] * inv + q1.z, 0.f);
    v[7] = fmaxf(acc[7] * inv + q1.w, 0.f);
#pragma unroll
    for (int j = 0; j < 8; j++) m = fmaxf(m, v[j]);
  }
#pragma unroll
  for (int off = 1; off <= 4; off <<= 1) m = fmaxf(m, __shfl_xor(m, off, 8));
  float ssum = 0.f;
  if (valid) {
#pragma unroll
    for (int j = 0; j < 8; j++) ssum += __expf(v[j] - m);
  }
#pragma unroll
  for (int off = 1; off <= 4; off <<= 1) ssum += __shfl_xor(ssum, off, 8);
  float lse = __logf(ssum) + m;
  if (slot == 0 && valid) {
    float* orow = out + (size_t)node * N_CLASSES + li * 8;
    *(float4*)orow = make_float4(v[0] - lse, v[1] - lse, v[2] - lse, v[3] - lse);
    *(float4*)(orow + 4) =
        make_float4(v[4] - lse, v[5] - lse, v[6] - lse, v[7] - lse);
  }
}

// ---------------------------------------------------------------------------
extern "C" void kernel_launch(void* const* d_in, const int* in_sizes, int n_in,
                              void* d_out, int out_size, void* d_ws,
                              size_t ws_size, hipStream_t stream) {
  const float* x   = (const float*)d_in[0];
  const int*   ei  = (const int*)d_in[1];
  const int*   src = ei;
  const int*   dst = ei + N_EDGES;
  const float* W1l = (const float*)d_in[2];
  const float* W1r = (const float*)d_in[3];
  const float* b1  = (const float*)d_in[4];
  const float* W2l = (const float*)d_in[5];
  const float* W2r = (const float*)d_in[6];
  const float* b2  = (const float*)d_in[7];
  float* out = (float*)d_out;

  float* wsf = (float*)d_ws;
  int*   rs     = (int*)wsf + OFF_RS;
  int*   bcnt   = (int*)wsf + OFF_BCNT;
  float* invdeg = wsf + OFF_INVDEG;
  int*   srcs   = (int*)wsf + OFF_SRCS;
  unsigned short* Ab  = (unsigned short*)(wsf + OFF_AB);
  unsigned short* pb  = (unsigned short*)(wsf + OFF_PB);
  unsigned short* hb  = (unsigned short*)(wsf + OFF_HB);
  unsigned short* Wt1 = (unsigned short*)(wsf + OFF_WT1);
  unsigned short* Wt2 = (unsigned short*)(wsf + OFF_WT2);
  int*   bins   = (int*)wsf + OFF_BINS;
  float* q = wsf + OFF_Q;

  hipMemsetAsync(bcnt, 0, NBUCKET * sizeof(int), stream);

  k_binA_prep<<<BINA_NBLK + PREP_NBLK, 256, 0, stream>>>(
      src, dst, bcnt, bins, x, W1l, W1r, W2l, W2r, Ab, Wt1, Wt2);
  k_binB<<<NBUCKET, 256, 0, stream>>>(bcnt, bins, rs, srcs, invdeg);
  k_gather1<<<(N_NODES + 3) / 4, 256, 0, stream>>>(rs, srcs, invdeg, Ab);
  k_l1<<<(N_NODES + 63) / 64, 256, 0, stream>>>(Ab, Wt1, b1, hb);
  k_pq<<<(N_NODES + 63) / 64, 256, 0, stream>>>(hb, Wt2, b2, pb, q);
  k_final<<<(N_NODES + 3) / 4, 256, 0, stream>>>(pb, q, rs, srcs, invdeg, out);
}

// Round 9
// 233.371 us; speedup vs baseline: 10.3010x; 1.0311x over previous
//
#include <hip/hip_runtime.h>

#define N_NODES 50000
#define N_EDGES 800000
#define F_IN 128
#define HIDDEN 128
#define N_CLASSES 40

#define NBUCKET 391      // buckets of 128 nodes (dst>>7); 391*128 = 50048
#define BUCKET_CAP 4096  // per-bucket capacity (mean fill 2048, sd ~45)
#define BINA_CHUNK 2048
#define BINA_NBLK 391    // ceil(800000/2048)
#define PREP_ITEMS (N_NODES * 32 + 128 * 256 + 80 * 128)  // 1,643,008
#define PREP_NBLK (PREP_ITEMS / 256)                       // 6418 (exact)

// workspace element offsets (4B units)
#define OFF_RS     0          // int[N+1]
#define OFF_BCNT   50004      // int[391] global bucket counts
#define OFF_INVDEG 100004     // float[N]
#define OFF_SRCS   150004     // int[E] -> ends 950,004
#define OFF_AB     950004     // ushort[N*256] bf16 [agg|x]; spans ->7,350,004
#define OFF_PB     950004     // ushort[N*40] bf16 p stride 40 (overlays dead Ab)
#define OFF_Q      2950004    // float[N*40] (inside dead-Ab span, after PB end)
#define OFF_BINS   7350004    // int[391*4096] = 1,601,536 -> ends 8,951,540
#define OFF_WT1    10550004   // ushort[128*256] -> ends 10,566,388
#define OFF_WT2    10566388   // ushort[80*128]  -> ends 10,571,508
// total 10,571,508 float-units = 42.3 MB (proven available)

typedef short bf16x8 __attribute__((ext_vector_type(8)));
typedef float f32x4 __attribute__((ext_vector_type(4)));
typedef unsigned short u16x8 __attribute__((ext_vector_type(8)));

static __device__ __forceinline__ unsigned short f2bf(float f) {
  unsigned int u = __builtin_bit_cast(unsigned int, f);
  u = (u + 0x7fffu + ((u >> 16) & 1u)) >> 16;  // RNE; inputs are finite
  return (unsigned short)u;
}
static __device__ __forceinline__ float bf2f(unsigned short s) {
  unsigned int u = ((unsigned int)s) << 16;
  return __builtin_bit_cast(float, u);
}

// ---------------------------------------------------------------------------
// Fused: bucket-sort phase A (blocks 0..390) + weight/x prep (blocks 391+).
__global__ __launch_bounds__(256) void k_binA_prep(
    const int* __restrict__ src, const int* __restrict__ dst,
    int* __restrict__ bcnt, int* __restrict__ bins,
    const float* __restrict__ x, const float* __restrict__ W1l,
    const float* __restrict__ W1r, const float* __restrict__ W2l,
    const float* __restrict__ W2r, unsigned short* __restrict__ Ab,
    unsigned short* __restrict__ Wt1, unsigned short* __restrict__ Wt2) {
  if (blockIdx.x >= BINA_NBLK) {
    // ---- prep path (independent of CSR build) ----
    int idx = (blockIdx.x - BINA_NBLK) * 256 + threadIdx.x;
    if (idx < N_NODES * 32) {  // x fp32 -> bf16, one thread per 4 elems
      int row = idx >> 5, c4 = (idx & 31) << 2;
      const float4 v = *(const float4*)(x + (size_t)row * F_IN + c4);
      ushort4 o;
      o.x = f2bf(v.x); o.y = f2bf(v.y); o.z = f2bf(v.z); o.w = f2bf(v.w);
      *(ushort4*)(Ab + (size_t)row * 256 + 128 + c4) = o;
      return;
    }
    idx -= N_NODES * 32;
    if (idx < 128 * 256) {
      int n = idx >> 8, k = idx & 255;
      float v = (k < 128) ? W1l[(size_t)k * 128 + n]
                          : W1r[(size_t)(k - 128) * 128 + n];
      Wt1[(size_t)n * 256 + k] = f2bf(v);
    } else if (idx < 128 * 256 + 80 * 128) {
      int j = idx - 128 * 256;
      int n = j >> 7, k = j & 127;
      float v = (n < 40) ? W2l[(size_t)k * 40 + n]
                         : W2r[(size_t)k * 40 + (n - 40)];
      Wt2[(size_t)n * 128 + k] = f2bf(v);
    }
    return;
  }
  // ---- binA path: LDS counting sort of 2048 edges into 391 dst-buckets ----
  __shared__ int cnt[NBUCKET];
  __shared__ int excl[NBUCKET];
  __shared__ int cursor[NBUCKET];
  __shared__ int bbase[NBUCKET];
  __shared__ int sc[256];
  __shared__ int stage[BINA_CHUNK];
  __shared__ unsigned short bkt[BINA_CHUNK];
  int t = threadIdx.x;
  int e0 = blockIdx.x * BINA_CHUNK;
  int ne = N_EDGES - e0;
  if (ne > BINA_CHUNK) ne = BINA_CHUNK;
  for (int i = t; i < NBUCKET; i += 256) cnt[i] = 0;
  __syncthreads();
  for (int i = t; i < ne; i += 256) atomicAdd(&cnt[dst[e0 + i] >> 7], 1);
  __syncthreads();
  // exclusive scan over 391 with 256 threads: pair-sum then Hillis
  int a = (2 * t < NBUCKET) ? cnt[2 * t] : 0;
  int b2_ = (2 * t + 1 < NBUCKET) ? cnt[2 * t + 1] : 0;
  int s = a + b2_;
  sc[t] = s;
  __syncthreads();
  for (int off = 1; off < 256; off <<= 1) {
    int add = (t >= off) ? sc[t - off] : 0;
    __syncthreads();
    sc[t] += add;
    __syncthreads();
  }
  int pbase = sc[t] - s;  // exclusive prefix of my pair
  if (2 * t < NBUCKET) { excl[2 * t] = pbase; cursor[2 * t] = pbase; }
  if (2 * t + 1 < NBUCKET) {
    excl[2 * t + 1] = pbase + a;
    cursor[2 * t + 1] = pbase + a;
  }
  for (int i = t; i < NBUCKET; i += 256)
    bbase[i] = atomicAdd(&bcnt[i], cnt[i]);  // claim contiguous global range
  __syncthreads();
  for (int i = t; i < ne; i += 256) {
    int d = dst[e0 + i];
    int sv = src[e0 + i];
    int b = d >> 7;
    int pos = atomicAdd(&cursor[b], 1);
    stage[pos] = ((d & 127) << 16) | sv;  // src < 65536 fits 16 bits
    bkt[pos] = (unsigned short)b;
  }
  __syncthreads();
  for (int i = t; i < ne; i += 256) {
    int b = bkt[i];
    bins[(size_t)b * BUCKET_CAP + bbase[b] + (i - excl[b])] = stage[i];
  }
}

// ---------------------------------------------------------------------------
// Bucket-sort phase B: one block per bucket (128 nodes). Builds final CSR.
__global__ __launch_bounds__(256) void k_binB(
    const int* __restrict__ bcnt, const int* __restrict__ bins,
    int* __restrict__ rs, int* __restrict__ srcs,
    float* __restrict__ invdeg) {
  __shared__ int sc[256];
  __shared__ int hist[128];
  __shared__ int cursor[128];
  int b = blockIdx.x;
  int t = threadIdx.x;
  // base = sum(bcnt[0..b-1]); each thread covers t and t+256
  int v = 0;
  if (t < b) v += bcnt[t];
  if (t + 256 < b) v += bcnt[t + 256];
  sc[t] = v;
  __syncthreads();
  for (int off = 128; off; off >>= 1) {
    if (t < off) sc[t] += sc[t + off];
    __syncthreads();
  }
  int base = sc[0];
  int cnt = bcnt[b];
  const int* bb = bins + (size_t)b * BUCKET_CAP;
  if (t < 128) hist[t] = 0;
  __syncthreads();
  for (int i = t; i < cnt; i += 256) atomicAdd(&hist[bb[i] >> 16], 1);
  __syncthreads();
  int c = (t < 128) ? hist[t] : 0;
  sc[t] = c;
  __syncthreads();
  for (int off = 1; off < 128; off <<= 1) {
    int add = (t >= off) ? sc[t - off] : 0;
    __syncthreads();
    sc[t] += add;
    __syncthreads();
  }
  int lexcl = sc[t] - c;
  int node = b * 128 + t;
  if (t < 128 && node < N_NODES) {
    rs[node] = base + lexcl;
    invdeg[node] = 1.0f / (float)(c > 1 ? c : 1);
  }
  if (b == 0 && t == 0) rs[N_NODES] = N_EDGES;
  if (t < 128) cursor[t] = lexcl;
  __syncthreads();
  for (int i = t; i < cnt; i += 256) {
    int v2 = bb[i];
    int pos = atomicAdd(&cursor[v2 >> 16], 1);
    srcs[base + pos] = v2 & 0xFFFF;
  }
}

// ---------------------------------------------------------------------------
// Layer-1 mean-aggregation: wave per node, 8 edge-slots x 8 lanes x 2x16B.
__global__ __launch_bounds__(256) void k_gather1(
    const int* __restrict__ rs, const int* __restrict__ srcs,
    const float* __restrict__ invdeg, unsigned short* __restrict__ Ab) {
  int node = blockIdx.x * 4 + (threadIdx.x >> 6);
  int lane = threadIdx.x & 63;
  int slot = lane >> 3, li = lane & 7;
  if (node >= N_NODES) return;
  int beg = rs[node], end = rs[node + 1];
  float acc[16];
#pragma unroll
  for (int j = 0; j < 16; j++) acc[j] = 0.f;
  for (int i = beg + slot; i < end; i += 8) {
    int s = srcs[i];
    const unsigned short* rp = Ab + (size_t)s * 256 + 128 + li * 8;
    u16x8 v0 = *(const u16x8*)rp;
    u16x8 v1 = *(const u16x8*)(rp + 64);
#pragma unroll
    for (int j = 0; j < 8; j++) {
      acc[j] += bf2f(v0[j]);
      acc[8 + j] += bf2f(v1[j]);
    }
  }
#pragma unroll
  for (int off = 8; off <= 32; off <<= 1)
#pragma unroll
    for (int j = 0; j < 16; j++) acc[j] += __shfl_xor(acc[j], off, 64);
  if (slot == 0) {  // lanes 0..7 cover cols li*8 and 64+li*8
    float inv = invdeg[node];
    u16x8 o0, o1;
#pragma unroll
    for (int j = 0; j < 8; j++) {
      o0[j] = f2bf(acc[j] * inv);
      o1[j] = f2bf(acc[8 + j] * inv);
    }
    *(u16x8*)(Ab + (size_t)node * 256 + li * 8) = o0;
    *(u16x8*)(Ab + (size_t)node * 256 + 64 + li * 8) = o1;
  }
}

// ---------------------------------------------------------------------------
// Fused MLP: h = relu([agg|x] @ [W1l;W1r] + b1) (registers -> LDS, never
// global), then [p|q] = h @ [W2l|W2r] (+ b2 on q). Each wave consumes exactly
// the 16 h-rows it produces. LDS stride 132: ds_write_b16 2-way aliased
// (free), ds_read_b64 2-way aliased (free), 8B-aligned for all rows.
__global__ __launch_bounds__(256) void k_mlp(
    const unsigned short* __restrict__ Ab, const unsigned short* __restrict__ Wt1,
    const unsigned short* __restrict__ Wt2, const float* __restrict__ b1,
    const float* __restrict__ b2, unsigned short* __restrict__ pb,
    float* __restrict__ q) {
  __shared__ unsigned short hs[64 * 132];  // 16.5 KB
  int w = threadIdx.x >> 6, lane = threadIdx.x & 63;
  int r = lane & 15, quad = lane >> 4;
  int row0 = blockIdx.x * 64 + w * 16;
  int arow = row0 + r;
  if (arow >= N_NODES) arow = N_NODES - 1;  // clamp load, guard store
  const unsigned short* Ap = Ab + (size_t)arow * 256 + quad * 8;
  const unsigned short* Bp = Wt1 + (size_t)r * 256 + quad * 8;
  f32x4 acc[8];
#pragma unroll
  for (int n = 0; n < 8; n++) acc[n] = (f32x4){0.f, 0.f, 0.f, 0.f};
#pragma unroll
  for (int k0 = 0; k0 < 256; k0 += 32) {
    bf16x8 af = *(const bf16x8*)(Ap + k0);
#pragma unroll
    for (int n = 0; n < 8; n++) {
      bf16x8 bv = *(const bf16x8*)(Bp + (size_t)n * 16 * 256 + k0);
      acc[n] = __builtin_amdgcn_mfma_f32_16x16x32_bf16(af, bv, acc[n], 0, 0, 0);
    }
  }
  // h (bias + relu + bf16) -> LDS
  int lrow0 = w * 16 + quad * 4;
#pragma unroll
  for (int n = 0; n < 8; n++) {
    int col = n * 16 + r;
    float bias = b1[col];
#pragma unroll
    for (int reg = 0; reg < 4; reg++)
      hs[(lrow0 + reg) * 132 + col] = f2bf(fmaxf(acc[n][reg] + bias, 0.f));
  }
  __syncthreads();
  // phase 2: [p|q] = h @ Wt2
  int lr = w * 16 + r;
  const unsigned short* Bp2 = Wt2 + (size_t)r * 128 + quad * 8;
  f32x4 acc2[5];
#pragma unroll
  for (int n = 0; n < 5; n++) acc2[n] = (f32x4){0.f, 0.f, 0.f, 0.f};
#pragma unroll
  for (int k0 = 0; k0 < 128; k0 += 32) {
    const unsigned short* hp = &hs[lr * 132 + k0 + quad * 8];
    ushort4 h0 = *(const ushort4*)hp;        // 8B-aligned ds_read_b64
    ushort4 h1 = *(const ushort4*)(hp + 4);
    bf16x8 af;
    af[0] = (short)h0.x; af[1] = (short)h0.y; af[2] = (short)h0.z; af[3] = (short)h0.w;
    af[4] = (short)h1.x; af[5] = (short)h1.y; af[6] = (short)h1.z; af[7] = (short)h1.w;
#pragma unroll
    for (int n = 0; n < 5; n++) {
      bf16x8 bv = *(const bf16x8*)(Bp2 + (size_t)n * 16 * 128 + k0);
      acc2[n] = __builtin_amdgcn_mfma_f32_16x16x32_bf16(af, bv, acc2[n], 0, 0, 0);
    }
  }
  int crow0 = row0 + quad * 4;
#pragma unroll
  for (int n = 0; n < 5; n++) {
    int col = n * 16 + r;
#pragma unroll
    for (int reg = 0; reg < 4; reg++) {
      int row = crow0 + reg;
      if (row < N_NODES) {
        float v = acc2[n][reg];
        if (col < N_CLASSES)
          pb[(size_t)row * 40 + col] = f2bf(v);
        else
          q[(size_t)row * N_CLASSES + (col - N_CLASSES)] = v + b2[col - N_CLASSES];
      }
    }
  }
}

// ---------------------------------------------------------------------------
// Fused: layer-2 gather-mean (bf16 p, stride 40) + root + ReLU + log_softmax.
// Wave per node, 8 edge-slots x (5 active lanes x 16B = 80B/edge).
__global__ __launch_bounds__(256) void k_final(
    const unsigned short* __restrict__ pb, const float* __restrict__ q,
    const int* __restrict__ rs, const int* __restrict__ srcs,
    const float* __restrict__ invdeg, float* __restrict__ out) {
  int node = blockIdx.x * 4 + (threadIdx.x >> 6);
  int lane = threadIdx.x & 63;
  int slot = lane >> 3, li = lane & 7;
  if (node >= N_NODES) return;
  bool valid = li < 5;  // lane li covers cols li*8..li*8+7 (<40)
  int beg = rs[node], end = rs[node + 1];
  float acc[8];
#pragma unroll
  for (int j = 0; j < 8; j++) acc[j] = 0.f;
  for (int i = beg + slot; i < end; i += 8) {
    int s = srcs[i];
    if (valid) {
      u16x8 v = *(const u16x8*)(pb + (size_t)s * 40 + li * 8);
#pragma unroll
      for (int j = 0; j < 8; j++) acc[j] += bf2f(v[j]);
    }
  }
#pragma unroll
  for (int off = 8; off <= 32; off <<= 1)
#pragma unroll
    for (int j = 0; j < 8; j++) acc[j] += __shfl_xor(acc[j], off, 64);
  float inv = invdeg[node];
  float v[8];
  float m = -1e30f;
  if (valid) {
    const float* qr = q + (size_t)node * N_CLASSES + li * 8;
    float4 q0 = *(const float4*)qr;
    float4 q1 = *(const float4*)(qr + 4);
    v[0] = fmaxf(acc[0] * inv + q0.x, 0.f);
    v[1] = fmaxf(acc[1] * inv + q0.y, 0.f);
    v[2] = fmaxf(acc[2] * inv + q0.z, 0.f);
    v[3] = fmaxf(acc[3] * inv + q0.w, 0.f);
    v[4] = fmaxf(acc[4] * inv + q1.x, 0.f);
    v[5] = fmaxf(acc[5] * inv + q1.y, 0.f);
    v[6] = fmaxf(acc[6] * inv + q1.z, 0.f);
    v[7] = fmaxf(acc[7] * inv + q1.w, 0.f);
#pragma unroll
    for (int j = 0; j < 8; j++) m = fmaxf(m, v[j]);
  }
#pragma unroll
  for (int off = 1; off <= 4; off <<= 1) m = fmaxf(m, __shfl_xor(m, off, 8));
  float ssum = 0.f;
  if (valid) {
#pragma unroll
    for (int j = 0; j < 8; j++) ssum += __expf(v[j] - m);
  }
#pragma unroll
  for (int off = 1; off <= 4; off <<= 1) ssum += __shfl_xor(ssum, off, 8);
  float lse = __logf(ssum) + m;
  if (slot == 0 && valid) {
    float* orow = out + (size_t)node * N_CLASSES + li * 8;
    *(float4*)orow = make_float4(v[0] - lse, v[1] - lse, v[2] - lse, v[3] - lse);
    *(float4*)(orow + 4) =
        make_float4(v[4] - lse, v[5] - lse, v[6] - lse, v[7] - lse);
  }
}

// ---------------------------------------------------------------------------
extern "C" void kernel_launch(void* const* d_in, const int* in_sizes, int n_in,
                              void* d_out, int out_size, void* d_ws,
                              size_t ws_size, hipStream_t stream) {
  const float* x   = (const float*)d_in[0];
  const int*   ei  = (const int*)d_in[1];
  const int*   src = ei;
  const int*   dst = ei + N_EDGES;
  const float* W1l = (const float*)d_in[2];
  const float* W1r = (const float*)d_in[3];
  const float* b1  = (const float*)d_in[4];
  const float* W2l = (const float*)d_in[5];
  const float* W2r = (const float*)d_in[6];
  const float* b2  = (const float*)d_in[7];
  float* out = (float*)d_out;

  float* wsf = (float*)d_ws;
  int*   rs     = (int*)wsf + OFF_RS;
  int*   bcnt   = (int*)wsf + OFF_BCNT;
  float* invdeg = wsf + OFF_INVDEG;
  int*   srcs   = (int*)wsf + OFF_SRCS;
  unsigned short* Ab  = (unsigned short*)(wsf + OFF_AB);
  unsigned short* pb  = (unsigned short*)(wsf + OFF_PB);
  unsigned short* Wt1 = (unsigned short*)(wsf + OFF_WT1);
  unsigned short* Wt2 = (unsigned short*)(wsf + OFF_WT2);
  int*   bins   = (int*)wsf + OFF_BINS;
  float* q = wsf + OFF_Q;

  hipMemsetAsync(bcnt, 0, NBUCKET * sizeof(int), stream);

  k_binA_prep<<<BINA_NBLK + PREP_NBLK, 256, 0, stream>>>(
      src, dst, bcnt, bins, x, W1l, W1r, W2l, W2r, Ab, Wt1, Wt2);
  k_binB<<<NBUCKET, 256, 0, stream>>>(bcnt, bins, rs, srcs, invdeg);
  k_gather1<<<(N_NODES + 3) / 4, 256, 0, stream>>>(rs, srcs, invdeg, Ab);
  k_mlp<<<(N_NODES + 63) / 64, 256, 0, stream>>>(Ab, Wt1, Wt2, b1, b2, pb, q);
  k_final<<<(N_NODES + 3) / 4, 256, 0, stream>>>(pb, q, rs, srcs, invdeg, out);
}

// Round 11
// 223.219 us; speedup vs baseline: 10.7695x; 1.0455x over previous
//
#include <hip/hip_runtime.h>

#define N_NODES 50000
#define N_EDGES 800000
#define F_IN 128
#define HIDDEN 128
#define N_CLASSES 40

#define NBUCKET 391      // buckets of 128 nodes (dst>>7); 391*128 = 50048
#define BUCKET_CAP 4096  // per-bucket capacity (mean fill 2048, sd ~45)
#define BINA_CHUNK 2048
#define BINA_NBLK 391    // ceil(800000/2048)
#define PREP_ITEMS (N_NODES * 32 + 128 * 256 + 80 * 128)  // 1,643,008
#define PREP_NBLK (PREP_ITEMS / 256)                       // 6418 (exact)

// workspace element offsets (4B units)
// RACE FIX (R10 post-mortem): pb/q previously overlaid live Ab — k_mlp wrote
// them while other co-resident blocks still read Ab (R9 passed on timing luck
// only). pb/q now live in the dead bins region, disjoint from Ab.
#define OFF_RS     0          // int[N+1]
#define OFF_BCNT   50004      // int[391] global bucket counts
#define OFF_INVDEG 100004     // float[N]
#define OFF_SRCS   150004     // int[E] -> ends 950,004
#define OFF_AB     950004     // ushort[N*256] bf16 [agg|x] -> ends 7,350,004; LIVE through k_mlp
#define OFF_BINS   7350004    // int[391*4096] = 1,601,536 -> ends 8,951,540; dead after k_binB
#define OFF_PB     7350004    // ushort[N*40] bf16 p (overlays dead bins) -> ends 8,350,004
#define OFF_Q      8350004    // float[N*40] (overlays dead bins tail) -> ends 10,350,004
#define OFF_WT1    10550004   // ushort[128*256] -> ends 10,566,388
#define OFF_WT2    10566388   // ushort[80*128]  -> ends 10,571,508
// total 10,571,508 float-units = 42.3 MB (proven available)

typedef short bf16x8 __attribute__((ext_vector_type(8)));
typedef float f32x4 __attribute__((ext_vector_type(4)));
typedef unsigned short u16x8 __attribute__((ext_vector_type(8)));

static __device__ __forceinline__ unsigned short f2bf(float f) {
  unsigned int u = __builtin_bit_cast(unsigned int, f);
  u = (u + 0x7fffu + ((u >> 16) & 1u)) >> 16;  // RNE; inputs are finite
  return (unsigned short)u;
}
static __device__ __forceinline__ float bf2f(unsigned short s) {
  unsigned int u = ((unsigned int)s) << 16;
  return __builtin_bit_cast(float, u);
}

// ---------------------------------------------------------------------------
// Fused: bucket-sort phase A (blocks 0..390) + weight/x prep (blocks 391+).
__global__ __launch_bounds__(256) void k_binA_prep(
    const int* __restrict__ src, const int* __restrict__ dst,
    int* __restrict__ bcnt, int* __restrict__ bins,
    const float* __restrict__ x, const float* __restrict__ W1l,
    const float* __restrict__ W1r, const float* __restrict__ W2l,
    const float* __restrict__ W2r, unsigned short* __restrict__ Ab,
    unsigned short* __restrict__ Wt1, unsigned short* __restrict__ Wt2) {
  if (blockIdx.x >= BINA_NBLK) {
    // ---- prep path (independent of CSR build) ----
    int idx = (blockIdx.x - BINA_NBLK) * 256 + threadIdx.x;
    if (idx < N_NODES * 32) {  // x fp32 -> bf16, one thread per 4 elems
      int row = idx >> 5, c4 = (idx & 31) << 2;
      const float4 v = *(const float4*)(x + (size_t)row * F_IN + c4);
      ushort4 o;
      o.x = f2bf(v.x); o.y = f2bf(v.y); o.z = f2bf(v.z); o.w = f2bf(v.w);
      *(ushort4*)(Ab + (size_t)row * 256 + 128 + c4) = o;
      return;
    }
    idx -= N_NODES * 32;
    if (idx < 128 * 256) {
      int n = idx >> 8, k = idx & 255;
      float v = (k < 128) ? W1l[(size_t)k * 128 + n]
                          : W1r[(size_t)(k - 128) * 128 + n];
      Wt1[(size_t)n * 256 + k] = f2bf(v);
    } else if (idx < 128 * 256 + 80 * 128) {
      int j = idx - 128 * 256;
      int n = j >> 7, k = j & 127;
      float v = (n < 40) ? W2l[(size_t)k * 40 + n]
                         : W2r[(size_t)k * 40 + (n - 40)];
      Wt2[(size_t)n * 128 + k] = f2bf(v);
    }
    return;
  }
  // ---- binA path: LDS counting sort of 2048 edges into 391 dst-buckets ----
  __shared__ int cnt[NBUCKET];
  __shared__ int excl[NBUCKET];
  __shared__ int cursor[NBUCKET];
  __shared__ int bbase[NBUCKET];
  __shared__ int sc[256];
  __shared__ int stage[BINA_CHUNK];
  __shared__ unsigned short bkt[BINA_CHUNK];
  int t = threadIdx.x;
  int e0 = blockIdx.x * BINA_CHUNK;
  int ne = N_EDGES - e0;
  if (ne > BINA_CHUNK) ne = BINA_CHUNK;
  for (int i = t; i < NBUCKET; i += 256) cnt[i] = 0;
  __syncthreads();
  for (int i = t; i < ne; i += 256) atomicAdd(&cnt[dst[e0 + i] >> 7], 1);
  __syncthreads();
  // exclusive scan over 391 with 256 threads: pair-sum then Hillis
  int a = (2 * t < NBUCKET) ? cnt[2 * t] : 0;
  int b2_ = (2 * t + 1 < NBUCKET) ? cnt[2 * t + 1] : 0;
  int s = a + b2_;
  sc[t] = s;
  __syncthreads();
  for (int off = 1; off < 256; off <<= 1) {
    int add = (t >= off) ? sc[t - off] : 0;
    __syncthreads();
    sc[t] += add;
    __syncthreads();
  }
  int pbase = sc[t] - s;  // exclusive prefix of my pair
  if (2 * t < NBUCKET) { excl[2 * t] = pbase; cursor[2 * t] = pbase; }
  if (2 * t + 1 < NBUCKET) {
    excl[2 * t + 1] = pbase + a;
    cursor[2 * t + 1] = pbase + a;
  }
  for (int i = t; i < NBUCKET; i += 256)
    bbase[i] = atomicAdd(&bcnt[i], cnt[i]);  // claim contiguous global range
  __syncthreads();
  for (int i = t; i < ne; i += 256) {
    int d = dst[e0 + i];
    int sv = src[e0 + i];
    int b = d >> 7;
    int pos = atomicAdd(&cursor[b], 1);
    stage[pos] = ((d & 127) << 16) | sv;  // src < 65536 fits 16 bits
    bkt[pos] = (unsigned short)b;
  }
  __syncthreads();
  for (int i = t; i < ne; i += 256) {
    int b = bkt[i];
    bins[(size_t)b * BUCKET_CAP + bbase[b] + (i - excl[b])] = stage[i];
  }
}

// ---------------------------------------------------------------------------
// Bucket-sort phase B: one block per bucket (128 nodes). Builds final CSR.
__global__ __launch_bounds__(256) void k_binB(
    const int* __restrict__ bcnt, const int* __restrict__ bins,
    int* __restrict__ rs, int* __restrict__ srcs,
    float* __restrict__ invdeg) {
  __shared__ int sc[256];
  __shared__ int hist[128];
  __shared__ int cursor[128];
  int b = blockIdx.x;
  int t = threadIdx.x;
  // base = sum(bcnt[0..b-1]); each thread covers t and t+256
  int v = 0;
  if (t < b) v += bcnt[t];
  if (t + 256 < b) v += bcnt[t + 256];
  sc[t] = v;
  __syncthreads();
  for (int off = 128; off; off >>= 1) {
    if (t < off) sc[t] += sc[t + off];
    __syncthreads();
  }
  int base = sc[0];
  int cnt = bcnt[b];
  const int* bb = bins + (size_t)b * BUCKET_CAP;
  if (t < 128) hist[t] = 0;
  __syncthreads();
  for (int i = t; i < cnt; i += 256) atomicAdd(&hist[bb[i] >> 16], 1);
  __syncthreads();
  int c = (t < 128) ? hist[t] : 0;
  sc[t] = c;
  __syncthreads();
  for (int off = 1; off < 128; off <<= 1) {
    int add = (t >= off) ? sc[t - off] : 0;
    __syncthreads();
    sc[t] += add;
    __syncthreads();
  }
  int lexcl = sc[t] - c;
  int node = b * 128 + t;
  if (t < 128 && node < N_NODES) {
    rs[node] = base + lexcl;
    invdeg[node] = 1.0f / (float)(c > 1 ? c : 1);
  }
  if (b == 0 && t == 0) rs[N_NODES] = N_EDGES;
  if (t < 128) cursor[t] = lexcl;
  __syncthreads();
  for (int i = t; i < cnt; i += 256) {
    int v2 = bb[i];
    int pos = atomicAdd(&cursor[v2 >> 16], 1);
    srcs[base + pos] = v2 & 0xFFFF;
  }
}

// ---------------------------------------------------------------------------
// Layer-1 mean-aggregation: wave per node, 8 edge-slots x 8 lanes x 2x16B.
__global__ __launch_bounds__(256) void k_gather1(
    const int* __restrict__ rs, const int* __restrict__ srcs,
    const float* __restrict__ invdeg, unsigned short* __restrict__ Ab) {
  int node = blockIdx.x * 4 + (threadIdx.x >> 6);
  int lane = threadIdx.x & 63;
  int slot = lane >> 3, li = lane & 7;
  if (node >= N_NODES) return;
  int beg = rs[node], end = rs[node + 1];
  float acc[16];
#pragma unroll
  for (int j = 0; j < 16; j++) acc[j] = 0.f;
  for (int i = beg + slot; i < end; i += 8) {
    int s = srcs[i];
    const unsigned short* rp = Ab + (size_t)s * 256 + 128 + li * 8;
    u16x8 v0 = *(const u16x8*)rp;
    u16x8 v1 = *(const u16x8*)(rp + 64);
#pragma unroll
    for (int j = 0; j < 8; j++) {
      acc[j] += bf2f(v0[j]);
      acc[8 + j] += bf2f(v1[j]);
    }
  }
#pragma unroll
  for (int off = 8; off <= 32; off <<= 1)
#pragma unroll
    for (int j = 0; j < 16; j++) acc[j] += __shfl_xor(acc[j], off, 64);
  if (slot == 0) {  // lanes 0..7 cover cols li*8 and 64+li*8
    float inv = invdeg[node];
    u16x8 o0, o1;
#pragma unroll
    for (int j = 0; j < 8; j++) {
      o0[j] = f2bf(acc[j] * inv);
      o1[j] = f2bf(acc[8 + j] * inv);
    }
    *(u16x8*)(Ab + (size_t)node * 256 + li * 8) = o0;
    *(u16x8*)(Ab + (size_t)node * 256 + 64 + li * 8) = o1;
  }
}

// ---------------------------------------------------------------------------
// Fused MLP, occupancy-restructured: block = 32 rows (grid 1563). Phase 1:
// wave w owns n-tiles {2w,2w+1} x BOTH 16-row tiles — each B-fragment load
// feeds 2 independent MFMA chains. h round-trips through LDS (stride 132:
// 2-way bank alias = free). Phase 2: wave w covers row-tile (w&1), n-group
// (w>>1): {0,1,2} or {3,4}. Writes pb/q in the dead-bins region (disjoint
// from Ab — see RACE FIX note at the offset table).
__global__ __launch_bounds__(256) void k_mlp(
    const unsigned short* __restrict__ Ab, const unsigned short* __restrict__ Wt1,
    const unsigned short* __restrict__ Wt2, const float* __restrict__ b1,
    const float* __restrict__ b2, unsigned short* __restrict__ pb,
    float* __restrict__ q) {
  __shared__ unsigned short hs[32 * 132];  // 8.4 KB
  int w = threadIdx.x >> 6, lane = threadIdx.x & 63;
  int r = lane & 15, quad = lane >> 4;
  int row0 = blockIdx.x * 32;
  int ar0 = row0 + r;
  int ar1 = row0 + 16 + r;
  if (ar0 >= N_NODES) ar0 = N_NODES - 1;  // clamp load, guard store
  if (ar1 >= N_NODES) ar1 = N_NODES - 1;
  const unsigned short* Ap0 = Ab + (size_t)ar0 * 256 + quad * 8;
  const unsigned short* Ap1 = Ab + (size_t)ar1 * 256 + quad * 8;
  const unsigned short* Bp = Wt1 + (size_t)(w * 32 + r) * 256 + quad * 8;
  f32x4 acc[2][2];
#pragma unroll
  for (int nn = 0; nn < 2; nn++)
#pragma unroll
    for (int rt = 0; rt < 2; rt++) acc[nn][rt] = (f32x4){0.f, 0.f, 0.f, 0.f};
#pragma unroll
  for (int k0 = 0; k0 < 256; k0 += 32) {
    bf16x8 a0 = *(const bf16x8*)(Ap0 + k0);
    bf16x8 a1 = *(const bf16x8*)(Ap1 + k0);
#pragma unroll
    for (int nn = 0; nn < 2; nn++) {
      bf16x8 bv = *(const bf16x8*)(Bp + (size_t)nn * 16 * 256 + k0);
      acc[nn][0] = __builtin_amdgcn_mfma_f32_16x16x32_bf16(a0, bv, acc[nn][0], 0, 0, 0);
      acc[nn][1] = __builtin_amdgcn_mfma_f32_16x16x32_bf16(a1, bv, acc[nn][1], 0, 0, 0);
    }
  }
  // h (bias + relu + bf16) -> LDS
#pragma unroll
  for (int nn = 0; nn < 2; nn++) {
    int col = (w * 2 + nn) * 16 + r;
    float bias = b1[col];
#pragma unroll
    for (int rt = 0; rt < 2; rt++)
#pragma unroll
      for (int reg = 0; reg < 4; reg++)
        hs[(rt * 16 + quad * 4 + reg) * 132 + col] =
            f2bf(fmaxf(acc[nn][rt][reg] + bias, 0.f));
  }
  __syncthreads();
  // phase 2: [p|q] = h @ Wt2
  int rt2 = w & 1, ng = w >> 1;
  int nbeg = ng ? 3 : 0;
  int ncnt = ng ? 2 : 3;
  const unsigned short* hrow = hs + (rt2 * 16 + r) * 132 + quad * 8;
  const unsigned short* Bp2 = Wt2 + (size_t)(nbeg * 16 + r) * 128 + quad * 8;
  f32x4 acc2[3];
#pragma unroll
  for (int j = 0; j < 3; j++) acc2[j] = (f32x4){0.f, 0.f, 0.f, 0.f};
#pragma unroll
  for (int k0 = 0; k0 < 128; k0 += 32) {
    ushort4 h0 = *(const ushort4*)(hrow + k0);       // 8B-aligned ds_read_b64
    ushort4 h1 = *(const ushort4*)(hrow + k0 + 4);
    bf16x8 af;
    af[0] = (short)h0.x; af[1] = (short)h0.y; af[2] = (short)h0.z; af[3] = (short)h0.w;
    af[4] = (short)h1.x; af[5] = (short)h1.y; af[6] = (short)h1.z; af[7] = (short)h1.w;
#pragma unroll
    for (int j = 0; j < 3; j++) {
      if (j < ncnt) {
        bf16x8 bv = *(const bf16x8*)(Bp2 + (size_t)j * 16 * 128 + k0);
        acc2[j] = __builtin_amdgcn_mfma_f32_16x16x32_bf16(af, bv, acc2[j], 0, 0, 0);
      }
    }
  }
  int crow0 = row0 + rt2 * 16 + quad * 4;
#pragma unroll
  for (int j = 0; j < 3; j++) {
    if (j < ncnt) {
      int col = (nbeg + j) * 16 + r;
#pragma unroll
      for (int reg = 0; reg < 4; reg++) {
        int row = crow0 + reg;
        if (row < N_NODES) {
          float v = acc2[j][reg];
          if (col < N_CLASSES)
            pb[(size_t)row * 40 + col] = f2bf(v);
          else
            q[(size_t)row * N_CLASSES + (col - N_CLASSES)] = v + b2[col - N_CLASSES];
        }
      }
    }
  }
}

// ---------------------------------------------------------------------------
// Fused: layer-2 gather-mean (bf16 p, stride 40) + root + ReLU + log_softmax.
// Wave per node, 8 edge-slots x (5 active lanes x 16B = 80B/edge).
__global__ __launch_bounds__(256) void k_final(
    const unsigned short* __restrict__ pb, const float* __restrict__ q,
    const int* __restrict__ rs, const int* __restrict__ srcs,
    const float* __restrict__ invdeg, float* __restrict__ out) {
  int node = blockIdx.x * 4 + (threadIdx.x >> 6);
  int lane = threadIdx.x & 63;
  int slot = lane >> 3, li = lane & 7;
  if (node >= N_NODES) return;
  bool valid = li < 5;  // lane li covers cols li*8..li*8+7 (<40)
  int beg = rs[node], end = rs[node + 1];
  float acc[8];
#pragma unroll
  for (int j = 0; j < 8; j++) acc[j] = 0.f;
  for (int i = beg + slot; i < end; i += 8) {
    int s = srcs[i];
    if (valid) {
      u16x8 v = *(const u16x8*)(pb + (size_t)s * 40 + li * 8);
#pragma unroll
      for (int j = 0; j < 8; j++) acc[j] += bf2f(v[j]);
    }
  }
#pragma unroll
  for (int off = 8; off <= 32; off <<= 1)
#pragma unroll
    for (int j = 0; j < 8; j++) acc[j] += __shfl_xor(acc[j], off, 64);
  float inv = invdeg[node];
  float v[8];
  float m = -1e30f;
  if (valid) {
    const float* qr = q + (size_t)node * N_CLASSES + li * 8;
    float4 q0 = *(const float4*)qr;
    float4 q1 = *(const float4*)(qr + 4);
    v[0] = fmaxf(acc[0] * inv + q0.x, 0.f);
    v[1] = fmaxf(acc[1] * inv + q0.y, 0.f);
    v[2] = fmaxf(acc[2] * inv + q0.z, 0.f);
    v[3] = fmaxf(acc[3] * inv + q0.w, 0.f);
    v[4] = fmaxf(acc[4] * inv + q1.x, 0.f);
    v[5] = fmaxf(acc[5] * inv + q1.y, 0.f);
    v[6] = fmaxf(acc[6] * inv + q1.z, 0.f);
    v[7] = fmaxf(acc[7] * inv + q1.w, 0.f);
#pragma unroll
    for (int j = 0; j < 8; j++) m = fmaxf(m, v[j]);
  }
#pragma unroll
  for (int off = 1; off <= 4; off <<= 1) m = fmaxf(m, __shfl_xor(m, off, 8));
  float ssum = 0.f;
  if (valid) {
#pragma unroll
    for (int j = 0; j < 8; j++) ssum += __expf(v[j] - m);
  }
#pragma unroll
  for (int off = 1; off <= 4; off <<= 1) ssum += __shfl_xor(ssum, off, 8);
  float lse = __logf(ssum) + m;
  if (slot == 0 && valid) {
    float* orow = out + (size_t)node * N_CLASSES + li * 8;
    *(float4*)orow = make_float4(v[0] - lse, v[1] - lse, v[2] - lse, v[3] - lse);
    *(float4*)(orow + 4) =
        make_float4(v[4] - lse, v[5] - lse, v[6] - lse, v[7] - lse);
  }
}

// ---------------------------------------------------------------------------
extern "C" void kernel_launch(void* const* d_in, const int* in_sizes, int n_in,
                              void* d_out, int out_size, void* d_ws,
                              size_t ws_size, hipStream_t stream) {
  const float* x   = (const float*)d_in[0];
  const int*   ei  = (const int*)d_in[1];
  const int*   src = ei;
  const int*   dst = ei + N_EDGES;
  const float* W1l = (const float*)d_in[2];
  const float* W1r = (const float*)d_in[3];
  const float* b1  = (const float*)d_in[4];
  const float* W2l = (const float*)d_in[5];
  const float* W2r = (const float*)d_in[6];
  const float* b2  = (const float*)d_in[7];
  float* out = (float*)d_out;

  float* wsf = (float*)d_ws;
  int*   rs     = (int*)wsf + OFF_RS;
  int*   bcnt   = (int*)wsf + OFF_BCNT;
  float* invdeg = wsf + OFF_INVDEG;
  int*   srcs   = (int*)wsf + OFF_SRCS;
  unsigned short* Ab  = (unsigned short*)(wsf + OFF_AB);
  unsigned short* pb  = (unsigned short*)(wsf + OFF_PB);  // dead-bins region
  unsigned short* Wt1 = (unsigned short*)(wsf + OFF_WT1);
  unsigned short* Wt2 = (unsigned short*)(wsf + OFF_WT2);
  int*   bins   = (int*)wsf + OFF_BINS;
  float* q = wsf + OFF_Q;  // dead-bins region

  hipMemsetAsync(bcnt, 0, NBUCKET * sizeof(int), stream);

  k_binA_prep<<<BINA_NBLK + PREP_NBLK, 256, 0, stream>>>(
      src, dst, bcnt, bins, x, W1l, W1r, W2l, W2r, Ab, Wt1, Wt2);
  k_binB<<<NBUCKET, 256, 0, stream>>>(bcnt, bins, rs, srcs, invdeg);
  k_gather1<<<(N_NODES + 3) / 4, 256, 0, stream>>>(rs, srcs, invdeg, Ab);
  k_mlp<<<(N_NODES + 31) / 32, 256, 0, stream>>>(Ab, Wt1, Wt2, b1, b2, pb, q);
  k_final<<<(N_NODES + 3) / 4, 256, 0, stream>>>(pb, q, rs, srcs, invdeg, out);
}

// Round 12
// 212.702 us; speedup vs baseline: 11.3019x; 1.0494x over previous
//
#include <hip/hip_runtime.h>

#define N_NODES 50000
#define N_EDGES 800000
#define F_IN 128
#define HIDDEN 128
#define N_CLASSES 40

#define NBUCKET 391      // buckets of 128 nodes (dst>>7); 391*128 = 50048
#define BUCKET_CAP 4096  // per-bucket capacity (mean fill 2048, sd ~45)
#define BINA_CHUNK 2048
#define BINA_NBLK 391    // ceil(800000/2048)
#define PREP_ITEMS (N_NODES * 32 + 128 * 256 + 80 * 128)  // 1,643,008
#define PREP_NBLK (PREP_ITEMS / 256)                       // 6418 (exact)

// workspace element offsets (4B units)
// Overlay audit (R10 lesson): xb LIVE through k_fused; bins dead after
// k_binB; pb/q overlay dead bins only; nothing overlays live xb.
#define OFF_RS     0          // int[N+1]
#define OFF_BCNT   50004      // int[391] global bucket counts
#define OFF_INVDEG 100004     // float[N]
#define OFF_SRCS   150004     // int[E] -> ends 950,004
#define OFF_XB     950004     // ushort[N*128] bf16 x -> ends 4,150,004; LIVE through k_fused
#define OFF_BINS   7350004    // int[391*4096] -> ends 8,951,540; dead after k_binB
#define OFF_PB     7350004    // ushort[N*40] bf16 p (overlays dead bins) -> ends 8,350,004
#define OFF_Q      8350004    // float[N*40] (overlays dead bins tail) -> ends 10,350,004
#define OFF_WT1    10550004   // ushort[128*256] -> ends 10,566,388
#define OFF_WT2    10566388   // ushort[80*128]  -> ends 10,571,508
// total 10,571,508 float-units = 42.3 MB (proven available)

typedef short bf16x8 __attribute__((ext_vector_type(8)));
typedef float f32x4 __attribute__((ext_vector_type(4)));
typedef unsigned short u16x8 __attribute__((ext_vector_type(8)));

static __device__ __forceinline__ unsigned short f2bf(float f) {
  unsigned int u = __builtin_bit_cast(unsigned int, f);
  u = (u + 0x7fffu + ((u >> 16) & 1u)) >> 16;  // RNE; inputs are finite
  return (unsigned short)u;
}
static __device__ __forceinline__ float bf2f(unsigned short s) {
  unsigned int u = ((unsigned int)s) << 16;
  return __builtin_bit_cast(float, u);
}

// ---------------------------------------------------------------------------
// Fused: bucket-sort phase A (blocks 0..390) + weight/x prep (blocks 391+).
__global__ __launch_bounds__(256) void k_binA_prep(
    const int* __restrict__ src, const int* __restrict__ dst,
    int* __restrict__ bcnt, int* __restrict__ bins,
    const float* __restrict__ x, const float* __restrict__ W1l,
    const float* __restrict__ W1r, const float* __restrict__ W2l,
    const float* __restrict__ W2r, unsigned short* __restrict__ xb,
    unsigned short* __restrict__ Wt1, unsigned short* __restrict__ Wt2) {
  if (blockIdx.x >= BINA_NBLK) {
    // ---- prep path (independent of CSR build) ----
    int idx = (blockIdx.x - BINA_NBLK) * 256 + threadIdx.x;
    if (idx < N_NODES * 32) {  // x fp32 -> bf16, one thread per 4 elems
      int row = idx >> 5, c4 = (idx & 31) << 2;
      const float4 v = *(const float4*)(x + (size_t)row * F_IN + c4);
      ushort4 o;
      o.x = f2bf(v.x); o.y = f2bf(v.y); o.z = f2bf(v.z); o.w = f2bf(v.w);
      *(ushort4*)(xb + (size_t)row * 128 + c4) = o;
      return;
    }
    idx -= N_NODES * 32;
    if (idx < 128 * 256) {
      int n = idx >> 8, k = idx & 255;
      float v = (k < 128) ? W1l[(size_t)k * 128 + n]
                          : W1r[(size_t)(k - 128) * 128 + n];
      Wt1[(size_t)n * 256 + k] = f2bf(v);
    } else if (idx < 128 * 256 + 80 * 128) {
      int j = idx - 128 * 256;
      int n = j >> 7, k = j & 127;
      float v = (n < 40) ? W2l[(size_t)k * 40 + n]
                         : W2r[(size_t)k * 40 + (n - 40)];
      Wt2[(size_t)n * 128 + k] = f2bf(v);
    }
    return;
  }
  // ---- binA path: LDS counting sort of 2048 edges into 391 dst-buckets ----
  __shared__ int cnt[NBUCKET];
  __shared__ int excl[NBUCKET];
  __shared__ int cursor[NBUCKET];
  __shared__ int bbase[NBUCKET];
  __shared__ int sc[256];
  __shared__ int stage[BINA_CHUNK];
  __shared__ unsigned short bkt[BINA_CHUNK];
  int t = threadIdx.x;
  int e0 = blockIdx.x * BINA_CHUNK;
  int ne = N_EDGES - e0;
  if (ne > BINA_CHUNK) ne = BINA_CHUNK;
  for (int i = t; i < NBUCKET; i += 256) cnt[i] = 0;
  __syncthreads();
  for (int i = t; i < ne; i += 256) atomicAdd(&cnt[dst[e0 + i] >> 7], 1);
  __syncthreads();
  // exclusive scan over 391 with 256 threads: pair-sum then Hillis
  int a = (2 * t < NBUCKET) ? cnt[2 * t] : 0;
  int b2_ = (2 * t + 1 < NBUCKET) ? cnt[2 * t + 1] : 0;
  int s = a + b2_;
  sc[t] = s;
  __syncthreads();
  for (int off = 1; off < 256; off <<= 1) {
    int add = (t >= off) ? sc[t - off] : 0;
    __syncthreads();
    sc[t] += add;
    __syncthreads();
  }
  int pbase = sc[t] - s;  // exclusive prefix of my pair
  if (2 * t < NBUCKET) { excl[2 * t] = pbase; cursor[2 * t] = pbase; }
  if (2 * t + 1 < NBUCKET) {
    excl[2 * t + 1] = pbase + a;
    cursor[2 * t + 1] = pbase + a;
  }
  for (int i = t; i < NBUCKET; i += 256)
    bbase[i] = atomicAdd(&bcnt[i], cnt[i]);  // claim contiguous global range
  __syncthreads();
  for (int i = t; i < ne; i += 256) {
    int d = dst[e0 + i];
    int sv = src[e0 + i];
    int b = d >> 7;
    int pos = atomicAdd(&cursor[b], 1);
    stage[pos] = ((d & 127) << 16) | sv;  // src < 65536 fits 16 bits
    bkt[pos] = (unsigned short)b;
  }
  __syncthreads();
  for (int i = t; i < ne; i += 256) {
    int b = bkt[i];
    bins[(size_t)b * BUCKET_CAP + bbase[b] + (i - excl[b])] = stage[i];
  }
}

// ---------------------------------------------------------------------------
// Bucket-sort phase B: one block per bucket (128 nodes). Builds final CSR.
__global__ __launch_bounds__(256) void k_binB(
    const int* __restrict__ bcnt, const int* __restrict__ bins,
    int* __restrict__ rs, int* __restrict__ srcs,
    float* __restrict__ invdeg) {
  __shared__ int sc[256];
  __shared__ int hist[128];
  __shared__ int cursor[128];
  int b = blockIdx.x;
  int t = threadIdx.x;
  // base = sum(bcnt[0..b-1]); each thread covers t and t+256
  int v = 0;
  if (t < b) v += bcnt[t];
  if (t + 256 < b) v += bcnt[t + 256];
  sc[t] = v;
  __syncthreads();
  for (int off = 128; off; off >>= 1) {
    if (t < off) sc[t] += sc[t + off];
    __syncthreads();
  }
  int base = sc[0];
  int cnt = bcnt[b];
  const int* bb = bins + (size_t)b * BUCKET_CAP;
  if (t < 128) hist[t] = 0;
  __syncthreads();
  for (int i = t; i < cnt; i += 256) atomicAdd(&hist[bb[i] >> 16], 1);
  __syncthreads();
  int c = (t < 128) ? hist[t] : 0;
  sc[t] = c;
  __syncthreads();
  for (int off = 1; off < 128; off <<= 1) {
    int add = (t >= off) ? sc[t - off] : 0;
    __syncthreads();
    sc[t] += add;
    __syncthreads();
  }
  int lexcl = sc[t] - c;
  int node = b * 128 + t;
  if (t < 128 && node < N_NODES) {
    rs[node] = base + lexcl;
    invdeg[node] = 1.0f / (float)(c > 1 ? c : 1);
  }
  if (b == 0 && t == 0) rs[N_NODES] = N_EDGES;
  if (t < 128) cursor[t] = lexcl;
  __syncthreads();
  for (int i = t; i < cnt; i += 256) {
    int v2 = bb[i];
    int pos = atomicAdd(&cursor[v2 >> 16], 1);
    srcs[base + pos] = v2 & 0xFFFF;
  }
}

// ---------------------------------------------------------------------------
// FUSED gather + 2-layer MLP. Block = 32 rows, 4 waves.
// Stage 1: wave w gathers agg for rows w*8..w*8+7 (8 edge-slots x 8 lanes x
// 2x16B from xb) -> LDS as[., 0:128]; all threads also stage own-row x-half
// (coalesced 16KB) -> as[., 128:256]. Stride 264 ushorts: ds_read_b128 at
// row r, col quad*16 is 2-way bank-aliased (free, m136).
// Stage 2: phase-1 MFMA (A from LDS, B=Wt1 from L2), h->hs LDS.
// Stage 3: phase-2 MFMA ([p|q] = h @ Wt2), store pb/q (dead-bins region).
__global__ __launch_bounds__(256) void k_fused(
    const unsigned short* __restrict__ xb, const int* __restrict__ rs,
    const int* __restrict__ srcs, const float* __restrict__ invdeg,
    const unsigned short* __restrict__ Wt1, const unsigned short* __restrict__ Wt2,
    const float* __restrict__ b1, const float* __restrict__ b2,
    unsigned short* __restrict__ pb, float* __restrict__ q) {
  __shared__ unsigned short as[32 * 264];  // 16.9 KB  A = [agg|x]
  __shared__ unsigned short hs[32 * 132];  //  8.4 KB  h
  int w = threadIdx.x >> 6, lane = threadIdx.x & 63;
  int t = threadIdx.x;
  int row0 = blockIdx.x * 32;

  // ---- stage own-row x-half into as[., 128:256] (coalesced) ----
  for (int chunk = t; chunk < 32 * 16; chunk += 256) {  // 16 x 16B per row
    int lrow = chunk >> 4, c8 = (chunk & 15) * 8;
    int grow = row0 + lrow;
    if (grow >= N_NODES) grow = N_NODES - 1;
    u16x8 v = *(const u16x8*)(xb + (size_t)grow * 128 + c8);
    *(u16x8*)(as + lrow * 264 + 128 + c8) = v;
  }

  // ---- gather agg for this wave's 8 rows ----
  int slot = lane >> 3, li = lane & 7;
  for (int j = 0; j < 8; j++) {
    int lrow = w * 8 + j;
    int node = row0 + lrow;
    int beg = 0, end = 0;
    if (node < N_NODES) { beg = rs[node]; end = rs[node + 1]; }
    float acc[16];
#pragma unroll
    for (int k = 0; k < 16; k++) acc[k] = 0.f;
    for (int i = beg + slot; i < end; i += 8) {
      int s = srcs[i];
      const unsigned short* rp = xb + (size_t)s * 128 + li * 8;
      u16x8 v0 = *(const u16x8*)rp;
      u16x8 v1 = *(const u16x8*)(rp + 64);
#pragma unroll
      for (int k = 0; k < 8; k++) {
        acc[k] += bf2f(v0[k]);
        acc[8 + k] += bf2f(v1[k]);
      }
    }
#pragma unroll
    for (int off = 8; off <= 32; off <<= 1)
#pragma unroll
      for (int k = 0; k < 16; k++) acc[k] += __shfl_xor(acc[k], off, 64);
    if (slot == 0) {
      int nidx = (node < N_NODES) ? node : 0;
      float inv = invdeg[nidx];
      u16x8 o0, o1;
#pragma unroll
      for (int k = 0; k < 8; k++) {
        o0[k] = f2bf(acc[k] * inv);
        o1[k] = f2bf(acc[8 + k] * inv);
      }
      *(u16x8*)(as + lrow * 264 + li * 8) = o0;
      *(u16x8*)(as + lrow * 264 + 64 + li * 8) = o1;
    }
  }
  __syncthreads();

  // ---- phase 1: h = relu(A @ Wt1 + b1), A from LDS ----
  int r = lane & 15, quad = lane >> 4;
  const unsigned short* Bp = Wt1 + (size_t)(w * 32 + r) * 256 + quad * 8;
  const unsigned short* A0 = as + r * 264 + quad * 8;
  const unsigned short* A1 = as + (16 + r) * 264 + quad * 8;
  f32x4 acc1[2][2];
#pragma unroll
  for (int nn = 0; nn < 2; nn++)
#pragma unroll
    for (int rt = 0; rt < 2; rt++) acc1[nn][rt] = (f32x4){0.f, 0.f, 0.f, 0.f};
#pragma unroll
  for (int k0 = 0; k0 < 256; k0 += 32) {
    bf16x8 a0 = *(const bf16x8*)(A0 + k0);
    bf16x8 a1 = *(const bf16x8*)(A1 + k0);
#pragma unroll
    for (int nn = 0; nn < 2; nn++) {
      bf16x8 bv = *(const bf16x8*)(Bp + (size_t)nn * 16 * 256 + k0);
      acc1[nn][0] = __builtin_amdgcn_mfma_f32_16x16x32_bf16(a0, bv, acc1[nn][0], 0, 0, 0);
      acc1[nn][1] = __builtin_amdgcn_mfma_f32_16x16x32_bf16(a1, bv, acc1[nn][1], 0, 0, 0);
    }
  }
  __syncthreads();  // as reads done before hs writes (hs disjoint, but keep
                    // ordering cheap and explicit for the next barrier anyway)
  // h (bias + relu + bf16) -> LDS
#pragma unroll
  for (int nn = 0; nn < 2; nn++) {
    int col = (w * 2 + nn) * 16 + r;
    float bias = b1[col];
#pragma unroll
    for (int rt = 0; rt < 2; rt++)
#pragma unroll
      for (int reg = 0; reg < 4; reg++)
        hs[(rt * 16 + quad * 4 + reg) * 132 + col] =
            f2bf(fmaxf(acc1[nn][rt][reg] + bias, 0.f));
  }
  __syncthreads();

  // ---- phase 2: [p|q] = h @ Wt2 ----
  int rt2 = w & 1, ng = w >> 1;
  int nbeg = ng ? 3 : 0;
  int ncnt = ng ? 2 : 3;
  const unsigned short* hrow = hs + (rt2 * 16 + r) * 132 + quad * 8;
  const unsigned short* Bp2 = Wt2 + (size_t)(nbeg * 16 + r) * 128 + quad * 8;
  f32x4 acc2[3];
#pragma unroll
  for (int j = 0; j < 3; j++) acc2[j] = (f32x4){0.f, 0.f, 0.f, 0.f};
#pragma unroll
  for (int k0 = 0; k0 < 128; k0 += 32) {
    ushort4 h0 = *(const ushort4*)(hrow + k0);       // 8B-aligned ds_read_b64
    ushort4 h1 = *(const ushort4*)(hrow + k0 + 4);
    bf16x8 af;
    af[0] = (short)h0.x; af[1] = (short)h0.y; af[2] = (short)h0.z; af[3] = (short)h0.w;
    af[4] = (short)h1.x; af[5] = (short)h1.y; af[6] = (short)h1.z; af[7] = (short)h1.w;
#pragma unroll
    for (int j = 0; j < 3; j++) {
      if (j < ncnt) {
        bf16x8 bv = *(const bf16x8*)(Bp2 + (size_t)j * 16 * 128 + k0);
        acc2[j] = __builtin_amdgcn_mfma_f32_16x16x32_bf16(af, bv, acc2[j], 0, 0, 0);
      }
    }
  }
  int crow0 = row0 + rt2 * 16 + quad * 4;
#pragma unroll
  for (int j = 0; j < 3; j++) {
    if (j < ncnt) {
      int col = (nbeg + j) * 16 + r;
#pragma unroll
      for (int reg = 0; reg < 4; reg++) {
        int row = crow0 + reg;
        if (row < N_NODES) {
          float v = acc2[j][reg];
          if (col < N_CLASSES)
            pb[(size_t)row * 40 + col] = f2bf(v);
          else
            q[(size_t)row * N_CLASSES + (col - N_CLASSES)] = v + b2[col - N_CLASSES];
        }
      }
    }
  }
}

// ---------------------------------------------------------------------------
// Fused: layer-2 gather-mean (bf16 p, stride 40) + root + ReLU + log_softmax.
// Wave per node, 8 edge-slots x (5 active lanes x 16B = 80B/edge).
__global__ __launch_bounds__(256) void k_final(
    const unsigned short* __restrict__ pb, const float* __restrict__ q,
    const int* __restrict__ rs, const int* __restrict__ srcs,
    const float* __restrict__ invdeg, float* __restrict__ out) {
  int node = blockIdx.x * 4 + (threadIdx.x >> 6);
  int lane = threadIdx.x & 63;
  int slot = lane >> 3, li = lane & 7;
  if (node >= N_NODES) return;
  bool valid = li < 5;  // lane li covers cols li*8..li*8+7 (<40)
  int beg = rs[node], end = rs[node + 1];
  float acc[8];
#pragma unroll
  for (int j = 0; j < 8; j++) acc[j] = 0.f;
  for (int i = beg + slot; i < end; i += 8) {
    int s = srcs[i];
    if (valid) {
      u16x8 v = *(const u16x8*)(pb + (size_t)s * 40 + li * 8);
#pragma unroll
      for (int j = 0; j < 8; j++) acc[j] += bf2f(v[j]);
    }
  }
#pragma unroll
  for (int off = 8; off <= 32; off <<= 1)
#pragma unroll
    for (int j = 0; j < 8; j++) acc[j] += __shfl_xor(acc[j], off, 64);
  float inv = invdeg[node];
  float v[8];
  float m = -1e30f;
  if (valid) {
    const float* qr = q + (size_t)node * N_CLASSES + li * 8;
    float4 q0 = *(const float4*)qr;
    float4 q1 = *(const float4*)(qr + 4);
    v[0] = fmaxf(acc[0] * inv + q0.x, 0.f);
    v[1] = fmaxf(acc[1] * inv + q0.y, 0.f);
    v[2] = fmaxf(acc[2] * inv + q0.z, 0.f);
    v[3] = fmaxf(acc[3] * inv + q0.w, 0.f);
    v[4] = fmaxf(acc[4] * inv + q1.x, 0.f);
    v[5] = fmaxf(acc[5] * inv + q1.y, 0.f);
    v[6] = fmaxf(acc[6] * inv + q1.z, 0.f);
    v[7] = fmaxf(acc[7] * inv + q1.w, 0.f);
#pragma unroll
    for (int j = 0; j < 8; j++) m = fmaxf(m, v[j]);
  }
#pragma unroll
  for (int off = 1; off <= 4; off <<= 1) m = fmaxf(m, __shfl_xor(m, off, 8));
  float ssum = 0.f;
  if (valid) {
#pragma unroll
    for (int j = 0; j < 8; j++) ssum += __expf(v[j] - m);
  }
#pragma unroll
  for (int off = 1; off <= 4; off <<= 1) ssum += __shfl_xor(ssum, off, 8);
  float lse = __logf(ssum) + m;
  if (slot == 0 && valid) {
    float* orow = out + (size_t)node * N_CLASSES + li * 8;
    *(float4*)orow = make_float4(v[0] - lse, v[1] - lse, v[2] - lse, v[3] - lse);
    *(float4*)(orow + 4) =
        make_float4(v[4] - lse, v[5] - lse, v[6] - lse, v[7] - lse);
  }
}

// ---------------------------------------------------------------------------
extern "C" void kernel_launch(void* const* d_in, const int* in_sizes, int n_in,
                              void* d_out, int out_size, void* d_ws,
                              size_t ws_size, hipStream_t stream) {
  const float* x   = (const float*)d_in[0];
  const int*   ei  = (const int*)d_in[1];
  const int*   src = ei;
  const int*   dst = ei + N_EDGES;
  const float* W1l = (const float*)d_in[2];
  const float* W1r = (const float*)d_in[3];
  const float* b1  = (const float*)d_in[4];
  const float* W2l = (const float*)d_in[5];
  const float* W2r = (const float*)d_in[6];
  const float* b2  = (const float*)d_in[7];
  float* out = (float*)d_out;

  float* wsf = (float*)d_ws;
  int*   rs     = (int*)wsf + OFF_RS;
  int*   bcnt   = (int*)wsf + OFF_BCNT;
  float* invdeg = wsf + OFF_INVDEG;
  int*   srcs   = (int*)wsf + OFF_SRCS;
  unsigned short* xb  = (unsigned short*)(wsf + OFF_XB);
  unsigned short* pb  = (unsigned short*)(wsf + OFF_PB);  // dead-bins region
  unsigned short* Wt1 = (unsigned short*)(wsf + OFF_WT1);
  unsigned short* Wt2 = (unsigned short*)(wsf + OFF_WT2);
  int*   bins   = (int*)wsf + OFF_BINS;
  float* q = wsf + OFF_Q;  // dead-bins region

  hipMemsetAsync(bcnt, 0, NBUCKET * sizeof(int), stream);

  k_binA_prep<<<BINA_NBLK + PREP_NBLK, 256, 0, stream>>>(
      src, dst, bcnt, bins, x, W1l, W1r, W2l, W2r, xb, Wt1, Wt2);
  k_binB<<<NBUCKET, 256, 0, stream>>>(bcnt, bins, rs, srcs, invdeg);
  k_fused<<<(N_NODES + 31) / 32, 256, 0, stream>>>(
      xb, rs, srcs, invdeg, Wt1, Wt2, b1, b2, pb, q);
  k_final<<<(N_NODES + 3) / 4, 256, 0, stream>>>(pb, q, rs, srcs, invdeg, out);
}

// Round 13
// 208.101 us; speedup vs baseline: 11.5518x; 1.0221x over previous
//
#include <hip/hip_runtime.h>

#define N_NODES 50000
#define N_EDGES 800000
#define F_IN 128
#define HIDDEN 128
#define N_CLASSES 40

#define NBUCKET 391      // buckets of 128 nodes (dst>>7); 391*128 = 50048
#define BUCKET_CAP 4096  // per-bucket capacity (mean fill 2048, sd ~45)
#define BINA_CHUNK 2048
#define BINA_NBLK 391    // ceil(800000/2048)
#define PREP_ITEMS (N_NODES * 32 + 128 * 256 + 80 * 128)  // 1,643,008
#define PREP_NBLK (PREP_ITEMS / 256)                       // 6418 (exact)

// workspace element offsets (4B units)
// Overlay audit (R10 lesson): xb LIVE through k_fused; bins dead after
// k_binB; pb/q overlay dead bins only; nothing overlays live xb.
#define OFF_RS     0          // int[N+1]
#define OFF_BCNT   50004      // int[391] global bucket counts
#define OFF_INVDEG 100004     // float[N]
#define OFF_SRCS   150004     // int[E] -> ends 950,004
#define OFF_XB     950004     // ushort[N*128] bf16 x -> ends 4,150,004; LIVE through k_fused
#define OFF_BINS   7350004    // int[391*4096] -> ends 8,951,540; dead after k_binB
#define OFF_PB     7350004    // ushort[N*40] bf16 p (overlays dead bins) -> ends 8,350,004
#define OFF_Q      8350004    // float[N*40] (overlays dead bins tail) -> ends 10,350,004
#define OFF_WT1    10550004   // ushort[128*256] -> ends 10,566,388
#define OFF_WT2    10566388   // ushort[80*128]  -> ends 10,571,508
// total 10,571,508 float-units = 42.3 MB (proven available)

typedef short bf16x8 __attribute__((ext_vector_type(8)));
typedef float f32x4 __attribute__((ext_vector_type(4)));
typedef unsigned short u16x8 __attribute__((ext_vector_type(8)));

static __device__ __forceinline__ unsigned short f2bf(float f) {
  unsigned int u = __builtin_bit_cast(unsigned int, f);
  u = (u + 0x7fffu + ((u >> 16) & 1u)) >> 16;  // RNE; inputs are finite
  return (unsigned short)u;
}
static __device__ __forceinline__ float bf2f(unsigned short s) {
  unsigned int u = ((unsigned int)s) << 16;
  return __builtin_bit_cast(float, u);
}

// ---------------------------------------------------------------------------
// Fused: bucket-sort phase A (blocks 0..390) + weight/x prep (blocks 391+).
__global__ __launch_bounds__(256) void k_binA_prep(
    const int* __restrict__ src, const int* __restrict__ dst,
    int* __restrict__ bcnt, int* __restrict__ bins,
    const float* __restrict__ x, const float* __restrict__ W1l,
    const float* __restrict__ W1r, const float* __restrict__ W2l,
    const float* __restrict__ W2r, unsigned short* __restrict__ xb,
    unsigned short* __restrict__ Wt1, unsigned short* __restrict__ Wt2) {
  if (blockIdx.x >= BINA_NBLK) {
    // ---- prep path (independent of CSR build) ----
    int idx = (blockIdx.x - BINA_NBLK) * 256 + threadIdx.x;
    if (idx < N_NODES * 32) {  // x fp32 -> bf16, one thread per 4 elems
      int row = idx >> 5, c4 = (idx & 31) << 2;
      const float4 v = *(const float4*)(x + (size_t)row * F_IN + c4);
      ushort4 o;
      o.x = f2bf(v.x); o.y = f2bf(v.y); o.z = f2bf(v.z); o.w = f2bf(v.w);
      *(ushort4*)(xb + (size_t)row * 128 + c4) = o;
      return;
    }
    idx -= N_NODES * 32;
    if (idx < 128 * 256) {
      int n = idx >> 8, k = idx & 255;
      float v = (k < 128) ? W1l[(size_t)k * 128 + n]
                          : W1r[(size_t)(k - 128) * 128 + n];
      Wt1[(size_t)n * 256 + k] = f2bf(v);
    } else if (idx < 128 * 256 + 80 * 128) {
      int j = idx - 128 * 256;
      int n = j >> 7, k = j & 127;
      float v = (n < 40) ? W2l[(size_t)k * 40 + n]
                         : W2r[(size_t)k * 40 + (n - 40)];
      Wt2[(size_t)n * 128 + k] = f2bf(v);
    }
    return;
  }
  // ---- binA path: LDS counting sort of 2048 edges into 391 dst-buckets ----
  __shared__ int cnt[NBUCKET];
  __shared__ int excl[NBUCKET];
  __shared__ int cursor[NBUCKET];
  __shared__ int bbase[NBUCKET];
  __shared__ int sc[256];
  __shared__ int stage[BINA_CHUNK];
  __shared__ unsigned short bkt[BINA_CHUNK];
  int t = threadIdx.x;
  int e0 = blockIdx.x * BINA_CHUNK;
  int ne = N_EDGES - e0;
  if (ne > BINA_CHUNK) ne = BINA_CHUNK;
  for (int i = t; i < NBUCKET; i += 256) cnt[i] = 0;
  __syncthreads();
  for (int i = t; i < ne; i += 256) atomicAdd(&cnt[dst[e0 + i] >> 7], 1);
  __syncthreads();
  // exclusive scan over 391 with 256 threads: pair-sum then Hillis
  int a = (2 * t < NBUCKET) ? cnt[2 * t] : 0;
  int b2_ = (2 * t + 1 < NBUCKET) ? cnt[2 * t + 1] : 0;
  int s = a + b2_;
  sc[t] = s;
  __syncthreads();
  for (int off = 1; off < 256; off <<= 1) {
    int add = (t >= off) ? sc[t - off] : 0;
    __syncthreads();
    sc[t] += add;
    __syncthreads();
  }
  int pbase = sc[t] - s;  // exclusive prefix of my pair
  if (2 * t < NBUCKET) { excl[2 * t] = pbase; cursor[2 * t] = pbase; }
  if (2 * t + 1 < NBUCKET) {
    excl[2 * t + 1] = pbase + a;
    cursor[2 * t + 1] = pbase + a;
  }
  for (int i = t; i < NBUCKET; i += 256)
    bbase[i] = atomicAdd(&bcnt[i], cnt[i]);  // claim contiguous global range
  __syncthreads();
  for (int i = t; i < ne; i += 256) {
    int d = dst[e0 + i];
    int sv = src[e0 + i];
    int b = d >> 7;
    int pos = atomicAdd(&cursor[b], 1);
    stage[pos] = ((d & 127) << 16) | sv;  // src < 65536 fits 16 bits
    bkt[pos] = (unsigned short)b;
  }
  __syncthreads();
  for (int i = t; i < ne; i += 256) {
    int b = bkt[i];
    bins[(size_t)b * BUCKET_CAP + bbase[b] + (i - excl[b])] = stage[i];
  }
}

// ---------------------------------------------------------------------------
// Bucket-sort phase B: one block per bucket (128 nodes). Builds final CSR.
__global__ __launch_bounds__(256) void k_binB(
    const int* __restrict__ bcnt, const int* __restrict__ bins,
    int* __restrict__ rs, int* __restrict__ srcs,
    float* __restrict__ invdeg) {
  __shared__ int sc[256];
  __shared__ int hist[128];
  __shared__ int cursor[128];
  int b = blockIdx.x;
  int t = threadIdx.x;
  // base = sum(bcnt[0..b-1]); each thread covers t and t+256
  int v = 0;
  if (t < b) v += bcnt[t];
  if (t + 256 < b) v += bcnt[t + 256];
  sc[t] = v;
  __syncthreads();
  for (int off = 128; off; off >>= 1) {
    if (t < off) sc[t] += sc[t + off];
    __syncthreads();
  }
  int base = sc[0];
  int cnt = bcnt[b];
  const int* bb = bins + (size_t)b * BUCKET_CAP;
  if (t < 128) hist[t] = 0;
  __syncthreads();
  for (int i = t; i < cnt; i += 256) atomicAdd(&hist[bb[i] >> 16], 1);
  __syncthreads();
  int c = (t < 128) ? hist[t] : 0;
  sc[t] = c;
  __syncthreads();
  for (int off = 1; off < 128; off <<= 1) {
    int add = (t >= off) ? sc[t - off] : 0;
    __syncthreads();
    sc[t] += add;
    __syncthreads();
  }
  int lexcl = sc[t] - c;
  int node = b * 128 + t;
  if (t < 128 && node < N_NODES) {
    rs[node] = base + lexcl;
    invdeg[node] = 1.0f / (float)(c > 1 ? c : 1);
  }
  if (b == 0 && t == 0) rs[N_NODES] = N_EDGES;
  if (t < 128) cursor[t] = lexcl;
  __syncthreads();
  for (int i = t; i < cnt; i += 256) {
    int v2 = bb[i];
    int pos = atomicAdd(&cursor[v2 >> 16], 1);
    srcs[base + pos] = v2 & 0xFFFF;
  }
}

// ---------------------------------------------------------------------------
// FUSED gather + 2-layer MLP. Block = 64 rows, 8 waves (512 threads).
// Stage 1: wave w gathers agg for rows w*8..w*8+7 (8 edge-slots, unrolled x2
// -> 32 cache lines in flight/wave) -> as[., 0:128]; all threads stage
// own-row x-half (coalesced) -> as[., 128:256].
// Stage 2: phase-1 MFMA — wave w owns n-tile w across ALL FOUR 16-row tiles:
// each B-fragment load feeds 4 independent MFMA chains (1 KB B-traffic/row,
// half of R12). h -> hs LDS.
// Stage 3: phase-2 MFMA — wave w: row-tile w>>1, n-group w&1 ({0,1,2}|{3,4}).
__global__ __launch_bounds__(512) void k_fused(
    const unsigned short* __restrict__ xb, const int* __restrict__ rs,
    const int* __restrict__ srcs, const float* __restrict__ invdeg,
    const unsigned short* __restrict__ Wt1, const unsigned short* __restrict__ Wt2,
    const float* __restrict__ b1, const float* __restrict__ b2,
    unsigned short* __restrict__ pb, float* __restrict__ q) {
  __shared__ unsigned short as[64 * 264];  // 33.0 KB  A = [agg|x]
  __shared__ unsigned short hs[64 * 132];  // 16.5 KB  h
  int w = threadIdx.x >> 6, lane = threadIdx.x & 63;
  int t = threadIdx.x;
  int row0 = blockIdx.x * 64;

  // ---- stage own-row x-half into as[., 128:256] (coalesced) ----
  for (int chunk = t; chunk < 64 * 16; chunk += 512) {  // 16 x 16B per row
    int lrow = chunk >> 4, c8 = (chunk & 15) * 8;
    int grow = row0 + lrow;
    if (grow >= N_NODES) grow = N_NODES - 1;
    u16x8 v = *(const u16x8*)(xb + (size_t)grow * 128 + c8);
    *(u16x8*)(as + lrow * 264 + 128 + c8) = v;
  }

  // ---- gather agg for this wave's 8 rows (edge loop unrolled x2) ----
  int slot = lane >> 3, li = lane & 7;
  for (int j = 0; j < 8; j++) {
    int lrow = w * 8 + j;
    int node = row0 + lrow;
    int beg = 0, end = 0;
    if (node < N_NODES) { beg = rs[node]; end = rs[node + 1]; }
    float acc[16];
#pragma unroll
    for (int k = 0; k < 16; k++) acc[k] = 0.f;
    int i = beg + slot;
    for (; i + 8 < end; i += 16) {  // two edges per slot per iter
      int s0 = srcs[i], s1 = srcs[i + 8];
      const unsigned short* rp0 = xb + (size_t)s0 * 128 + li * 8;
      const unsigned short* rp1 = xb + (size_t)s1 * 128 + li * 8;
      u16x8 a0 = *(const u16x8*)rp0;
      u16x8 a1 = *(const u16x8*)(rp0 + 64);
      u16x8 c0 = *(const u16x8*)rp1;
      u16x8 c1 = *(const u16x8*)(rp1 + 64);
#pragma unroll
      for (int k = 0; k < 8; k++) {
        acc[k] += bf2f(a0[k]) + bf2f(c0[k]);
        acc[8 + k] += bf2f(a1[k]) + bf2f(c1[k]);
      }
    }
    if (i < end) {  // tail edge
      int s0 = srcs[i];
      const unsigned short* rp0 = xb + (size_t)s0 * 128 + li * 8;
      u16x8 a0 = *(const u16x8*)rp0;
      u16x8 a1 = *(const u16x8*)(rp0 + 64);
#pragma unroll
      for (int k = 0; k < 8; k++) {
        acc[k] += bf2f(a0[k]);
        acc[8 + k] += bf2f(a1[k]);
      }
    }
#pragma unroll
    for (int off = 8; off <= 32; off <<= 1)
#pragma unroll
      for (int k = 0; k < 16; k++) acc[k] += __shfl_xor(acc[k], off, 64);
    if (slot == 0) {
      int nidx = (node < N_NODES) ? node : 0;
      float inv = invdeg[nidx];
      u16x8 o0, o1;
#pragma unroll
      for (int k = 0; k < 8; k++) {
        o0[k] = f2bf(acc[k] * inv);
        o1[k] = f2bf(acc[8 + k] * inv);
      }
      *(u16x8*)(as + lrow * 264 + li * 8) = o0;
      *(u16x8*)(as + lrow * 264 + 64 + li * 8) = o1;
    }
  }
  __syncthreads();

  // ---- phase 1: h = relu(A @ Wt1 + b1); wave w = n-tile w, 4 row-tiles ----
  int r = lane & 15, quad = lane >> 4;
  const unsigned short* Bp = Wt1 + (size_t)(w * 16 + r) * 256 + quad * 8;
  f32x4 acc1[4];
#pragma unroll
  for (int rt = 0; rt < 4; rt++) acc1[rt] = (f32x4){0.f, 0.f, 0.f, 0.f};
#pragma unroll
  for (int k0 = 0; k0 < 256; k0 += 32) {
    bf16x8 bv = *(const bf16x8*)(Bp + k0);
#pragma unroll
    for (int rt = 0; rt < 4; rt++) {
      bf16x8 av = *(const bf16x8*)(as + (rt * 16 + r) * 264 + quad * 8 + k0);
      acc1[rt] = __builtin_amdgcn_mfma_f32_16x16x32_bf16(av, bv, acc1[rt], 0, 0, 0);
    }
  }
  // h (bias + relu + bf16) -> LDS (hs disjoint from as; no barrier needed yet)
  {
    int col = w * 16 + r;
    float bias = b1[col];
#pragma unroll
    for (int rt = 0; rt < 4; rt++)
#pragma unroll
      for (int reg = 0; reg < 4; reg++)
        hs[(rt * 16 + quad * 4 + reg) * 132 + col] =
            f2bf(fmaxf(acc1[rt][reg] + bias, 0.f));
  }
  __syncthreads();

  // ---- phase 2: [p|q] = h @ Wt2 ----
  int rt2 = w >> 1, ng = w & 1;
  int nbeg = ng ? 3 : 0;
  int ncnt = ng ? 2 : 3;
  const unsigned short* hrow = hs + (rt2 * 16 + r) * 132 + quad * 8;
  const unsigned short* Bp2 = Wt2 + (size_t)(nbeg * 16 + r) * 128 + quad * 8;
  f32x4 acc2[3];
#pragma unroll
  for (int j = 0; j < 3; j++) acc2[j] = (f32x4){0.f, 0.f, 0.f, 0.f};
#pragma unroll
  for (int k0 = 0; k0 < 128; k0 += 32) {
    ushort4 h0 = *(const ushort4*)(hrow + k0);       // 8B-aligned ds_read_b64
    ushort4 h1 = *(const ushort4*)(hrow + k0 + 4);
    bf16x8 af;
    af[0] = (short)h0.x; af[1] = (short)h0.y; af[2] = (short)h0.z; af[3] = (short)h0.w;
    af[4] = (short)h1.x; af[5] = (short)h1.y; af[6] = (short)h1.z; af[7] = (short)h1.w;
#pragma unroll
    for (int j = 0; j < 3; j++) {
      if (j < ncnt) {
        bf16x8 bv = *(const bf16x8*)(Bp2 + (size_t)j * 16 * 128 + k0);
        acc2[j] = __builtin_amdgcn_mfma_f32_16x16x32_bf16(af, bv, acc2[j], 0, 0, 0);
      }
    }
  }
  int crow0 = row0 + rt2 * 16 + quad * 4;
#pragma unroll
  for (int j = 0; j < 3; j++) {
    if (j < ncnt) {
      int col = (nbeg + j) * 16 + r;
#pragma unroll
      for (int reg = 0; reg < 4; reg++) {
        int row = crow0 + reg;
        if (row < N_NODES) {
          float v = acc2[j][reg];
          if (col < N_CLASSES)
            pb[(size_t)row * 40 + col] = f2bf(v);
          else
            q[(size_t)row * N_CLASSES + (col - N_CLASSES)] = v + b2[col - N_CLASSES];
        }
      }
    }
  }
}

// ---------------------------------------------------------------------------
// Fused: layer-2 gather-mean (bf16 p, stride 40) + root + ReLU + log_softmax.
// Wave per node, 8 edge-slots (unrolled x2) x (5 active lanes x 16B).
__global__ __launch_bounds__(256) void k_final(
    const unsigned short* __restrict__ pb, const float* __restrict__ q,
    const int* __restrict__ rs, const int* __restrict__ srcs,
    const float* __restrict__ invdeg, float* __restrict__ out) {
  int node = blockIdx.x * 4 + (threadIdx.x >> 6);
  int lane = threadIdx.x & 63;
  int slot = lane >> 3, li = lane & 7;
  if (node >= N_NODES) return;
  bool valid = li < 5;  // lane li covers cols li*8..li*8+7 (<40)
  int beg = rs[node], end = rs[node + 1];
  float acc[8];
#pragma unroll
  for (int j = 0; j < 8; j++) acc[j] = 0.f;
  int i = beg + slot;
  for (; i + 8 < end; i += 16) {
    int s0 = srcs[i], s1 = srcs[i + 8];
    if (valid) {
      u16x8 v0 = *(const u16x8*)(pb + (size_t)s0 * 40 + li * 8);
      u16x8 v1 = *(const u16x8*)(pb + (size_t)s1 * 40 + li * 8);
#pragma unroll
      for (int j = 0; j < 8; j++) acc[j] += bf2f(v0[j]) + bf2f(v1[j]);
    }
  }
  if (i < end) {
    int s0 = srcs[i];
    if (valid) {
      u16x8 v0 = *(const u16x8*)(pb + (size_t)s0 * 40 + li * 8);
#pragma unroll
      for (int j = 0; j < 8; j++) acc[j] += bf2f(v0[j]);
    }
  }
#pragma unroll
  for (int off = 8; off <= 32; off <<= 1)
#pragma unroll
    for (int j = 0; j < 8; j++) acc[j] += __shfl_xor(acc[j], off, 64);
  float inv = invdeg[node];
  float v[8];
  float m = -1e30f;
  if (valid) {
    const float* qr = q + (size_t)node * N_CLASSES + li * 8;
    float4 q0 = *(const float4*)qr;
    float4 q1 = *(const float4*)(qr + 4);
    v[0] = fmaxf(acc[0] * inv + q0.x, 0.f);
    v[1] = fmaxf(acc[1] * inv + q0.y, 0.f);
    v[2] = fmaxf(acc[2] * inv + q0.z, 0.f);
    v[3] = fmaxf(acc[3] * inv + q0.w, 0.f);
    v[4] = fmaxf(acc[4] * inv + q1.x, 0.f);
    v[5] = fmaxf(acc[5] * inv + q1.y, 0.f);
    v[6] = fmaxf(acc[6] * inv + q1.z, 0.f);
    v[7] = fmaxf(acc[7] * inv + q1.w, 0.f);
#pragma unroll
    for (int j = 0; j < 8; j++) m = fmaxf(m, v[j]);
  }
#pragma unroll
  for (int off = 1; off <= 4; off <<= 1) m = fmaxf(m, __shfl_xor(m, off, 8));
  float ssum = 0.f;
  if (valid) {
#pragma unroll
    for (int j = 0; j < 8; j++) ssum += __expf(v[j] - m);
  }
#pragma unroll
  for (int off = 1; off <= 4; off <<= 1) ssum += __shfl_xor(ssum, off, 8);
  float lse = __logf(ssum) + m;
  if (slot == 0 && valid) {
    float* orow = out + (size_t)node * N_CLASSES + li * 8;
    *(float4*)orow = make_float4(v[0] - lse, v[1] - lse, v[2] - lse, v[3] - lse);
    *(float4*)(orow + 4) =
        make_float4(v[4] - lse, v[5] - lse, v[6] - lse, v[7] - lse);
  }
}

// ---------------------------------------------------------------------------
extern "C" void kernel_launch(void* const* d_in, const int* in_sizes, int n_in,
                              void* d_out, int out_size, void* d_ws,
                              size_t ws_size, hipStream_t stream) {
  const float* x   = (const float*)d_in[0];
  const int*   ei  = (const int*)d_in[1];
  const int*   src = ei;
  const int*   dst = ei + N_EDGES;
  const float* W1l = (const float*)d_in[2];
  const float* W1r = (const float*)d_in[3];
  const float* b1  = (const float*)d_in[4];
  const float* W2l = (const float*)d_in[5];
  const float* W2r = (const float*)d_in[6];
  const float* b2  = (const float*)d_in[7];
  float* out = (float*)d_out;

  float* wsf = (float*)d_ws;
  int*   rs     = (int*)wsf + OFF_RS;
  int*   bcnt   = (int*)wsf + OFF_BCNT;
  float* invdeg = wsf + OFF_INVDEG;
  int*   srcs   = (int*)wsf + OFF_SRCS;
  unsigned short* xb  = (unsigned short*)(wsf + OFF_XB);
  unsigned short* pb  = (unsigned short*)(wsf + OFF_PB);  // dead-bins region
  unsigned short* Wt1 = (unsigned short*)(wsf + OFF_WT1);
  unsigned short* Wt2 = (unsigned short*)(wsf + OFF_WT2);
  int*   bins   = (int*)wsf + OFF_BINS;
  float* q = wsf + OFF_Q;  // dead-bins region

  hipMemsetAsync(bcnt, 0, NBUCKET * sizeof(int), stream);

  k_binA_prep<<<BINA_NBLK + PREP_NBLK, 256, 0, stream>>>(
      src, dst, bcnt, bins, x, W1l, W1r, W2l, W2r, xb, Wt1, Wt2);
  k_binB<<<NBUCKET, 256, 0, stream>>>(bcnt, bins, rs, srcs, invdeg);
  k_fused<<<(N_NODES + 63) / 64, 512, 0, stream>>>(
      xb, rs, srcs, invdeg, Wt1, Wt2, b1, b2, pb, q);
  k_final<<<(N_NODES + 3) / 4, 256, 0, stream>>>(pb, q, rs, srcs, invdeg, out);
}

// Round 14
// 207.455 us; speedup vs baseline: 11.5878x; 1.0031x over previous
//
#include <hip/hip_runtime.h>

#define N_NODES 50000
#define N_EDGES 800000
#define F_IN 128
#define HIDDEN 128
#define N_CLASSES 40

#define NBUCKET 391      // buckets of 128 nodes (dst>>7); 391*128 = 50048
#define BUCKET_CAP 4096  // per-bucket capacity (mean fill 2048, sd ~45)
#define BINA_CHUNK 2048
#define BINA_NBLK 391    // ceil(800000/2048)
#define PREP_ITEMS (N_NODES * 32 + 128 * 256 + 80 * 128)  // 1,643,008
#define PREP_NBLK (PREP_ITEMS / 256)                       // 6418 (exact)

// workspace element offsets (4B units)
// Overlay audit (R10 lesson): xb LIVE through k_fused; bins dead after
// k_binB; pb/q overlay dead bins only; nothing overlays live xb.
#define OFF_RS     0          // int[N+1]
#define OFF_BCNT   50004      // int[391] global bucket counts
#define OFF_INVDEG 100004     // float[N]
#define OFF_SRCS   150004     // int[E] -> ends 950,004
#define OFF_XB     950004     // ushort[N*128] bf16 x -> ends 4,150,004; LIVE through k_fused
#define OFF_BINS   7350004    // int[391*4096] -> ends 8,951,540; dead after k_binB
#define OFF_PB     7350004    // ushort[N*40] bf16 p (overlays dead bins) -> ends 8,350,004
#define OFF_Q      8350004    // float[N*40] (overlays dead bins tail) -> ends 10,350,004
#define OFF_WT1    10550004   // ushort[128*256] -> ends 10,566,388
#define OFF_WT2    10566388   // ushort[80*128]  -> ends 10,571,508
// total 10,571,508 float-units = 42.3 MB (proven available)

typedef short bf16x8 __attribute__((ext_vector_type(8)));
typedef float f32x4 __attribute__((ext_vector_type(4)));
typedef unsigned short u16x8 __attribute__((ext_vector_type(8)));

static __device__ __forceinline__ unsigned short f2bf(float f) {
  unsigned int u = __builtin_bit_cast(unsigned int, f);
  u = (u + 0x7fffu + ((u >> 16) & 1u)) >> 16;  // RNE; inputs are finite
  return (unsigned short)u;
}
static __device__ __forceinline__ float bf2f(unsigned short s) {
  unsigned int u = ((unsigned int)s) << 16;
  return __builtin_bit_cast(float, u);
}

// ---------------------------------------------------------------------------
// Fused: bucket-sort phase A (blocks 0..390) + weight/x prep (blocks 391+).
__global__ __launch_bounds__(256) void k_binA_prep(
    const int* __restrict__ src, const int* __restrict__ dst,
    int* __restrict__ bcnt, int* __restrict__ bins,
    const float* __restrict__ x, const float* __restrict__ W1l,
    const float* __restrict__ W1r, const float* __restrict__ W2l,
    const float* __restrict__ W2r, unsigned short* __restrict__ xb,
    unsigned short* __restrict__ Wt1, unsigned short* __restrict__ Wt2) {
  if (blockIdx.x >= BINA_NBLK) {
    // ---- prep path (independent of CSR build) ----
    int idx = (blockIdx.x - BINA_NBLK) * 256 + threadIdx.x;
    if (idx < N_NODES * 32) {  // x fp32 -> bf16, one thread per 4 elems
      int row = idx >> 5, c4 = (idx & 31) << 2;
      const float4 v = *(const float4*)(x + (size_t)row * F_IN + c4);
      ushort4 o;
      o.x = f2bf(v.x); o.y = f2bf(v.y); o.z = f2bf(v.z); o.w = f2bf(v.w);
      *(ushort4*)(xb + (size_t)row * 128 + c4) = o;
      return;
    }
    idx -= N_NODES * 32;
    if (idx < 128 * 256) {
      int n = idx >> 8, k = idx & 255;
      float v = (k < 128) ? W1l[(size_t)k * 128 + n]
                          : W1r[(size_t)(k - 128) * 128 + n];
      Wt1[(size_t)n * 256 + k] = f2bf(v);
    } else if (idx < 128 * 256 + 80 * 128) {
      int j = idx - 128 * 256;
      int n = j >> 7, k = j & 127;
      float v = (n < 40) ? W2l[(size_t)k * 40 + n]
                         : W2r[(size_t)k * 40 + (n - 40)];
      Wt2[(size_t)n * 128 + k] = f2bf(v);
    }
    return;
  }
  // ---- binA path: LDS counting sort of 2048 edges into 391 dst-buckets ----
  __shared__ int cnt[NBUCKET];
  __shared__ int excl[NBUCKET];
  __shared__ int cursor[NBUCKET];
  __shared__ int bbase[NBUCKET];
  __shared__ int sc[256];
  __shared__ int stage[BINA_CHUNK];
  __shared__ unsigned short bkt[BINA_CHUNK];
  int t = threadIdx.x;
  int e0 = blockIdx.x * BINA_CHUNK;
  int ne = N_EDGES - e0;
  if (ne > BINA_CHUNK) ne = BINA_CHUNK;
  for (int i = t; i < NBUCKET; i += 256) cnt[i] = 0;
  __syncthreads();
  for (int i = t; i < ne; i += 256) atomicAdd(&cnt[dst[e0 + i] >> 7], 1);
  __syncthreads();
  // exclusive scan over 391 with 256 threads: pair-sum then Hillis
  int a = (2 * t < NBUCKET) ? cnt[2 * t] : 0;
  int b2_ = (2 * t + 1 < NBUCKET) ? cnt[2 * t + 1] : 0;
  int s = a + b2_;
  sc[t] = s;
  __syncthreads();
  for (int off = 1; off < 256; off <<= 1) {
    int add = (t >= off) ? sc[t - off] : 0;
    __syncthreads();
    sc[t] += add;
    __syncthreads();
  }
  int pbase = sc[t] - s;  // exclusive prefix of my pair
  if (2 * t < NBUCKET) { excl[2 * t] = pbase; cursor[2 * t] = pbase; }
  if (2 * t + 1 < NBUCKET) {
    excl[2 * t + 1] = pbase + a;
    cursor[2 * t + 1] = pbase + a;
  }
  for (int i = t; i < NBUCKET; i += 256)
    bbase[i] = atomicAdd(&bcnt[i], cnt[i]);  // claim contiguous global range
  __syncthreads();
  for (int i = t; i < ne; i += 256) {
    int d = dst[e0 + i];
    int sv = src[e0 + i];
    int b = d >> 7;
    int pos = atomicAdd(&cursor[b], 1);
    stage[pos] = ((d & 127) << 16) | sv;  // src < 65536 fits 16 bits
    bkt[pos] = (unsigned short)b;
  }
  __syncthreads();
  for (int i = t; i < ne; i += 256) {
    int b = bkt[i];
    bins[(size_t)b * BUCKET_CAP + bbase[b] + (i - excl[b])] = stage[i];
  }
}

// ---------------------------------------------------------------------------
// Bucket-sort phase B: one block per bucket (128 nodes). Builds final CSR.
__global__ __launch_bounds__(256) void k_binB(
    const int* __restrict__ bcnt, const int* __restrict__ bins,
    int* __restrict__ rs, int* __restrict__ srcs,
    float* __restrict__ invdeg) {
  __shared__ int sc[256];
  __shared__ int hist[128];
  __shared__ int cursor[128];
  int b = blockIdx.x;
  int t = threadIdx.x;
  // base = sum(bcnt[0..b-1]); each thread covers t and t+256
  int v = 0;
  if (t < b) v += bcnt[t];
  if (t + 256 < b) v += bcnt[t + 256];
  sc[t] = v;
  __syncthreads();
  for (int off = 128; off; off >>= 1) {
    if (t < off) sc[t] += sc[t + off];
    __syncthreads();
  }
  int base = sc[0];
  int cnt = bcnt[b];
  const int* bb = bins + (size_t)b * BUCKET_CAP;
  if (t < 128) hist[t] = 0;
  __syncthreads();
  for (int i = t; i < cnt; i += 256) atomicAdd(&hist[bb[i] >> 16], 1);
  __syncthreads();
  int c = (t < 128) ? hist[t] : 0;
  sc[t] = c;
  __syncthreads();
  for (int off = 1; off < 128; off <<= 1) {
    int add = (t >= off) ? sc[t - off] : 0;
    __syncthreads();
    sc[t] += add;
    __syncthreads();
  }
  int lexcl = sc[t] - c;
  int node = b * 128 + t;
  if (t < 128 && node < N_NODES) {
    rs[node] = base + lexcl;
    invdeg[node] = 1.0f / (float)(c > 1 ? c : 1);
  }
  if (b == 0 && t == 0) rs[N_NODES] = N_EDGES;
  if (t < 128) cursor[t] = lexcl;
  __syncthreads();
  for (int i = t; i < cnt; i += 256) {
    int v2 = bb[i];
    int pos = atomicAdd(&cursor[v2 >> 16], 1);
    srcs[base + pos] = v2 & 0xFFFF;
  }
}

// ---------------------------------------------------------------------------
// FUSED gather + 2-layer MLP. Block = 64 rows, 8 waves (512 threads).
// LDS: single 33 KB buffer `as`; h ALIASES into it after phase-1 (extra
// barrier separates last as-read from first h-write). 33 KB -> 4 blocks/CU
// -> 32 waves/CU (hardware cap), vs 3 blocks at R13's 49.5 KB.
__global__ __launch_bounds__(512) void k_fused(
    const unsigned short* __restrict__ xb, const int* __restrict__ rs,
    const int* __restrict__ srcs, const float* __restrict__ invdeg,
    const unsigned short* __restrict__ Wt1, const unsigned short* __restrict__ Wt2,
    const float* __restrict__ b1, const float* __restrict__ b2,
    unsigned short* __restrict__ pb, float* __restrict__ q) {
  __shared__ unsigned short as[64 * 264];  // 33.0 KB; A=[agg|x], then h alias
  unsigned short* hs = as;                 // h: 64 x 132 = 16.9 KB, fits
  int w = threadIdx.x >> 6, lane = threadIdx.x & 63;
  int t = threadIdx.x;
  int row0 = blockIdx.x * 64;

  // ---- stage own-row x-half into as[., 128:256] (coalesced) ----
  for (int chunk = t; chunk < 64 * 16; chunk += 512) {  // 16 x 16B per row
    int lrow = chunk >> 4, c8 = (chunk & 15) * 8;
    int grow = row0 + lrow;
    if (grow >= N_NODES) grow = N_NODES - 1;
    u16x8 v = *(const u16x8*)(xb + (size_t)grow * 128 + c8);
    *(u16x8*)(as + lrow * 264 + 128 + c8) = v;
  }

  // ---- gather agg for this wave's 8 rows (edge loop unrolled x2) ----
  int slot = lane >> 3, li = lane & 7;
  for (int j = 0; j < 8; j++) {
    int lrow = w * 8 + j;
    int node = row0 + lrow;
    int beg = 0, end = 0;
    if (node < N_NODES) { beg = rs[node]; end = rs[node + 1]; }
    float acc[16];
#pragma unroll
    for (int k = 0; k < 16; k++) acc[k] = 0.f;
    int i = beg + slot;
    for (; i + 8 < end; i += 16) {  // two edges per slot per iter
      int s0 = srcs[i], s1 = srcs[i + 8];
      const unsigned short* rp0 = xb + (size_t)s0 * 128 + li * 8;
      const unsigned short* rp1 = xb + (size_t)s1 * 128 + li * 8;
      u16x8 a0 = *(const u16x8*)rp0;
      u16x8 a1 = *(const u16x8*)(rp0 + 64);
      u16x8 c0 = *(const u16x8*)rp1;
      u16x8 c1 = *(const u16x8*)(rp1 + 64);
#pragma unroll
      for (int k = 0; k < 8; k++) {
        acc[k] += bf2f(a0[k]) + bf2f(c0[k]);
        acc[8 + k] += bf2f(a1[k]) + bf2f(c1[k]);
      }
    }
    if (i < end) {  // tail edge
      int s0 = srcs[i];
      const unsigned short* rp0 = xb + (size_t)s0 * 128 + li * 8;
      u16x8 a0 = *(const u16x8*)rp0;
      u16x8 a1 = *(const u16x8*)(rp0 + 64);
#pragma unroll
      for (int k = 0; k < 8; k++) {
        acc[k] += bf2f(a0[k]);
        acc[8 + k] += bf2f(a1[k]);
      }
    }
#pragma unroll
    for (int off = 8; off <= 32; off <<= 1)
#pragma unroll
      for (int k = 0; k < 16; k++) acc[k] += __shfl_xor(acc[k], off, 64);
    if (slot == 0) {
      int nidx = (node < N_NODES) ? node : 0;
      float inv = invdeg[nidx];
      u16x8 o0, o1;
#pragma unroll
      for (int k = 0; k < 8; k++) {
        o0[k] = f2bf(acc[k] * inv);
        o1[k] = f2bf(acc[8 + k] * inv);
      }
      *(u16x8*)(as + lrow * 264 + li * 8) = o0;
      *(u16x8*)(as + lrow * 264 + 64 + li * 8) = o1;
    }
  }
  __syncthreads();

  // ---- phase 1: h = relu(A @ Wt1 + b1); wave w = n-tile w, 4 row-tiles ----
  int r = lane & 15, quad = lane >> 4;
  const unsigned short* Bp = Wt1 + (size_t)(w * 16 + r) * 256 + quad * 8;
  f32x4 acc1[4];
#pragma unroll
  for (int rt = 0; rt < 4; rt++) acc1[rt] = (f32x4){0.f, 0.f, 0.f, 0.f};
#pragma unroll
  for (int k0 = 0; k0 < 256; k0 += 32) {
    bf16x8 bv = *(const bf16x8*)(Bp + k0);
#pragma unroll
    for (int rt = 0; rt < 4; rt++) {
      bf16x8 av = *(const bf16x8*)(as + (rt * 16 + r) * 264 + quad * 8 + k0);
      acc1[rt] = __builtin_amdgcn_mfma_f32_16x16x32_bf16(av, bv, acc1[rt], 0, 0, 0);
    }
  }
  __syncthreads();  // REQUIRED: all as reads done before h aliases over it
  // h (bias + relu + bf16) -> LDS (aliased into as, stride 132)
  {
    int col = w * 16 + r;
    float bias = b1[col];
#pragma unroll
    for (int rt = 0; rt < 4; rt++)
#pragma unroll
      for (int reg = 0; reg < 4; reg++)
        hs[(rt * 16 + quad * 4 + reg) * 132 + col] =
            f2bf(fmaxf(acc1[rt][reg] + bias, 0.f));
  }
  __syncthreads();

  // ---- phase 2: [p|q] = h @ Wt2 ----
  int rt2 = w >> 1, ng = w & 1;
  int nbeg = ng ? 3 : 0;
  int ncnt = ng ? 2 : 3;
  const unsigned short* hrow = hs + (rt2 * 16 + r) * 132 + quad * 8;
  const unsigned short* Bp2 = Wt2 + (size_t)(nbeg * 16 + r) * 128 + quad * 8;
  f32x4 acc2[3];
#pragma unroll
  for (int j = 0; j < 3; j++) acc2[j] = (f32x4){0.f, 0.f, 0.f, 0.f};
#pragma unroll
  for (int k0 = 0; k0 < 128; k0 += 32) {
    ushort4 h0 = *(const ushort4*)(hrow + k0);       // 8B-aligned ds_read_b64
    ushort4 h1 = *(const ushort4*)(hrow + k0 + 4);
    bf16x8 af;
    af[0] = (short)h0.x; af[1] = (short)h0.y; af[2] = (short)h0.z; af[3] = (short)h0.w;
    af[4] = (short)h1.x; af[5] = (short)h1.y; af[6] = (short)h1.z; af[7] = (short)h1.w;
#pragma unroll
    for (int j = 0; j < 3; j++) {
      if (j < ncnt) {
        bf16x8 bv = *(const bf16x8*)(Bp2 + (size_t)j * 16 * 128 + k0);
        acc2[j] = __builtin_amdgcn_mfma_f32_16x16x32_bf16(af, bv, acc2[j], 0, 0, 0);
      }
    }
  }
  int crow0 = row0 + rt2 * 16 + quad * 4;
#pragma unroll
  for (int j = 0; j < 3; j++) {
    if (j < ncnt) {
      int col = (nbeg + j) * 16 + r;
#pragma unroll
      for (int reg = 0; reg < 4; reg++) {
        int row = crow0 + reg;
        if (row < N_NODES) {
          float v = acc2[j][reg];
          if (col < N_CLASSES)
            pb[(size_t)row * 40 + col] = f2bf(v);
          else
            q[(size_t)row * N_CLASSES + (col - N_CLASSES)] = v + b2[col - N_CLASSES];
        }
      }
    }
  }
}

// ---------------------------------------------------------------------------
// Fused: layer-2 gather-mean (bf16 p, stride 40) + root + ReLU + log_softmax.
// Wave per node, 8 edge-slots (unrolled x2) x (5 active lanes x 16B).
__global__ __launch_bounds__(256) void k_final(
    const unsigned short* __restrict__ pb, const float* __restrict__ q,
    const int* __restrict__ rs, const int* __restrict__ srcs,
    const float* __restrict__ invdeg, float* __restrict__ out) {
  int node = blockIdx.x * 4 + (threadIdx.x >> 6);
  int lane = threadIdx.x & 63;
  int slot = lane >> 3, li = lane & 7;
  if (node >= N_NODES) return;
  bool valid = li < 5;  // lane li covers cols li*8..li*8+7 (<40)
  int beg = rs[node], end = rs[node + 1];
  float acc[8];
#pragma unroll
  for (int j = 0; j < 8; j++) acc[j] = 0.f;
  int i = beg + slot;
  for (; i + 8 < end; i += 16) {
    int s0 = srcs[i], s1 = srcs[i + 8];
    if (valid) {
      u16x8 v0 = *(const u16x8*)(pb + (size_t)s0 * 40 + li * 8);
      u16x8 v1 = *(const u16x8*)(pb + (size_t)s1 * 40 + li * 8);
#pragma unroll
      for (int j = 0; j < 8; j++) acc[j] += bf2f(v0[j]) + bf2f(v1[j]);
    }
  }
  if (i < end) {
    int s0 = srcs[i];
    if (valid) {
      u16x8 v0 = *(const u16x8*)(pb + (size_t)s0 * 40 + li * 8);
#pragma unroll
      for (int j = 0; j < 8; j++) acc[j] += bf2f(v0[j]);
    }
  }
#pragma unroll
  for (int off = 8; off <= 32; off <<= 1)
#pragma unroll
    for (int j = 0; j < 8; j++) acc[j] += __shfl_xor(acc[j], off, 64);
  float inv = invdeg[node];
  float v[8];
  float m = -1e30f;
  if (valid) {
    const float* qr = q + (size_t)node * N_CLASSES + li * 8;
    float4 q0 = *(const float4*)qr;
    float4 q1 = *(const float4*)(qr + 4);
    v[0] = fmaxf(acc[0] * inv + q0.x, 0.f);
    v[1] = fmaxf(acc[1] * inv + q0.y, 0.f);
    v[2] = fmaxf(acc[2] * inv + q0.z, 0.f);
    v[3] = fmaxf(acc[3] * inv + q0.w, 0.f);
    v[4] = fmaxf(acc[4] * inv + q1.x, 0.f);
    v[5] = fmaxf(acc[5] * inv + q1.y, 0.f);
    v[6] = fmaxf(acc[6] * inv + q1.z, 0.f);
    v[7] = fmaxf(acc[7] * inv + q1.w, 0.f);
#pragma unroll
    for (int j = 0; j < 8; j++) m = fmaxf(m, v[j]);
  }
#pragma unroll
  for (int off = 1; off <= 4; off <<= 1) m = fmaxf(m, __shfl_xor(m, off, 8));
  float ssum = 0.f;
  if (valid) {
#pragma unroll
    for (int j = 0; j < 8; j++) ssum += __expf(v[j] - m);
  }
#pragma unroll
  for (int off = 1; off <= 4; off <<= 1) ssum += __shfl_xor(ssum, off, 8);
  float lse = __logf(ssum) + m;
  if (slot == 0 && valid) {
    float* orow = out + (size_t)node * N_CLASSES + li * 8;
    *(float4*)orow = make_float4(v[0] - lse, v[1] - lse, v[2] - lse, v[3] - lse);
    *(float4*)(orow + 4) =
        make_float4(v[4] - lse, v[5] - lse, v[6] - lse, v[7] - lse);
  }
}

// ---------------------------------------------------------------------------
extern "C" void kernel_launch(void* const* d_in, const int* in_sizes, int n_in,
                              void* d_out, int out_size, void* d_ws,
                              size_t ws_size, hipStream_t stream) {
  const float* x   = (const float*)d_in[0];
  const int*   ei  = (const int*)d_in[1];
  const int*   src = ei;
  const int*   dst = ei + N_EDGES;
  const float* W1l = (const float*)d_in[2];
  const float* W1r = (const float*)d_in[3];
  const float* b1  = (const float*)d_in[4];
  const float* W2l = (const float*)d_in[5];
  const float* W2r = (const float*)d_in[6];
  const float* b2  = (const float*)d_in[7];
  float* out = (float*)d_out;

  float* wsf = (float*)d_ws;
  int*   rs     = (int*)wsf + OFF_RS;
  int*   bcnt   = (int*)wsf + OFF_BCNT;
  float* invdeg = wsf + OFF_INVDEG;
  int*   srcs   = (int*)wsf + OFF_SRCS;
  unsigned short* xb  = (unsigned short*)(wsf + OFF_XB);
  unsigned short* pb  = (unsigned short*)(wsf + OFF_PB);  // dead-bins region
  unsigned short* Wt1 = (unsigned short*)(wsf + OFF_WT1);
  unsigned short* Wt2 = (unsigned short*)(wsf + OFF_WT2);
  int*   bins   = (int*)wsf + OFF_BINS;
  float* q = wsf + OFF_Q;  // dead-bins region

  hipMemsetAsync(bcnt, 0, NBUCKET * sizeof(int), stream);

  k_binA_prep<<<BINA_NBLK + PREP_NBLK, 256, 0, stream>>>(
      src, dst, bcnt, bins, x, W1l, W1r, W2l, W2r, xb, Wt1, Wt2);
  k_binB<<<NBUCKET, 256, 0, stream>>>(bcnt, bins, rs, srcs, invdeg);
  k_fused<<<(N_NODES + 63) / 64, 512, 0, stream>>>(
      xb, rs, srcs, invdeg, Wt1, Wt2, b1, b2, pb, q);
  k_final<<<(N_NODES + 3) / 4, 256, 0, stream>>>(pb, q, rs, srcs, invdeg, out);
}